// Round 1
// baseline (86306.079 us; speedup 1.0000x reference)
//
#include <hip/hip_runtime.h>
#include <hip/hip_bf16.h>
#include <math.h>

// Problem constants
static constexpr int B_ = 8, S_ = 1024, E_ = 256, D_ = 1024, H_ = 16, DH_ = 64,
                     FF_ = 4096, L_ = 12, TDIM_ = 4096;
static constexpr int BS_ = B_ * S_;                    // 8192 rows
static constexpr int PROJN_ = 3 * H_ * DH_ + 2 * FF_;  // 11264

__device__ __forceinline__ float gelu_exact(float x) {
    return 0.5f * x * (1.f + erff(x * 0.70710678118654752440f));
}
__device__ __forceinline__ float gelu_tanh(float x) {
    float x3 = x * x * x;
    return 0.5f * x * (1.f + tanhf(0.79788456080286535588f * (x + 0.044715f * x3)));
}

// ---------------- time embedding base: temb0[b] = [sin(ts), cos(ts)] -----------
__global__ void temb0_kernel(const float* __restrict__ time, float* __restrict__ temb0) {
    int b = blockIdx.x;
    int i = threadIdx.x;  // 0..511
    float inv_ts = expf((float)i * (-logf(10000.f) / 511.f));  // half-1 = 511
    float ts = time[b] * inv_ts;
    temb0[b * D_ + i] = sinf(ts);
    temb0[b * D_ + 512 + i] = cosf(ts);
}

// ---------------- fixed positional embedding ----------------------------------
__global__ void pos_kernel(float* __restrict__ pos) {
    int s = blockIdx.x;
    int j = threadIdx.x;  // 0..511
    float inv_freq = expf((float)j * (-logf(10000.f) / 512.f));  // 2j/D = j/512
    float arg = (float)s * inv_freq;
    pos[s * D_ + j] = sinf(arg);
    pos[s * D_ + 512 + j] = cosf(arg);
}

// ---------------- h += pos[s] + temb[b] ---------------------------------------
__global__ void addpe_kernel(float* __restrict__ h, const float* __restrict__ pos,
                             const float* __restrict__ temb) {
    size_t idx = (size_t)blockIdx.x * 256 + threadIdx.x;  // over BS_*D_
    int d = (int)(idx & 1023);
    int s = (int)((idx >> 10) & 1023);
    int b = (int)(idx >> 20);
    h[idx] += pos[s * D_ + d] + temb[b * D_ + d];
}

// ---------------- LayerNorm: u = (h-m)*rsqrt(v+eps)*g + b ---------------------
__global__ void ln_kernel(const float* __restrict__ h, const float* __restrict__ g,
                          const float* __restrict__ bb, float* __restrict__ u) {
    int row = blockIdx.x;
    int t = threadIdx.x;  // 256 threads, 4 elems each
    const float4 v = reinterpret_cast<const float4*>(h + (size_t)row * D_)[t];
    __shared__ float red[8];
    float s = v.x + v.y + v.z + v.w;
    for (int m8 = 1; m8 < 64; m8 <<= 1) s += __shfl_xor(s, m8, 64);
    if ((t & 63) == 0) red[t >> 6] = s;
    __syncthreads();
    float mean = (red[0] + red[1] + red[2] + red[3]) * (1.f / 1024.f);
    float dx = v.x - mean, dy = v.y - mean, dz = v.z - mean, dw = v.w - mean;
    float sq = dx * dx + dy * dy + dz * dz + dw * dw;
    for (int m8 = 1; m8 < 64; m8 <<= 1) sq += __shfl_xor(sq, m8, 64);
    if ((t & 63) == 0) red[4 + (t >> 6)] = sq;
    __syncthreads();
    float var = (red[4] + red[5] + red[6] + red[7]) * (1.f / 1024.f);
    float inv = rsqrtf(var + 1e-5f);
    int c = t * 4;
    float4 o;
    o.x = dx * inv * g[c + 0] + bb[c + 0];
    o.y = dy * inv * g[c + 1] + bb[c + 1];
    o.z = dz * inv * g[c + 2] + bb[c + 2];
    o.w = dw * inv * g[c + 3] + bb[c + 3];
    reinterpret_cast<float4*>(u + (size_t)row * D_)[t] = o;
}

// ---------------- generic tiled fp32 GEMM: C = A[MxK] * B[KxN] (+bias)(+act) ---
// 64x64 tile, BK=16, 256 threads, 4x4 per thread. M guarded; N,K must be mult of 64/16.
template <int ACT, int BIAS, int ACCUM, int OUTBF16>
__global__ void gemm_kernel(const float* __restrict__ A, const float* __restrict__ Bm,
                            const float* __restrict__ bias, float* __restrict__ Cf,
                            __hip_bfloat16* __restrict__ Cb, int M, int N, int K) {
    __shared__ float As[16][65];  // +1 pad: transposed store would be 16-way conflicted
    __shared__ float Bs[16][64];
    int t = threadIdx.x;
    int tx = t & 15, ty = t >> 4;
    int n0 = blockIdx.x * 64, m0 = blockIdx.y * 64;
    float acc[4][4] = {};
    int nkt = K >> 4;
    for (int kt = 0; kt < nkt; ++kt) {
        int k0 = kt << 4;
#pragma unroll
        for (int it = 0; it < 4; ++it) {
            int idx = t + it * 256;
            int r = idx >> 4, c = idx & 15;
            int row = m0 + r;
            As[c][r] = (row < M) ? A[(size_t)row * K + k0 + c] : 0.f;
        }
#pragma unroll
        for (int it = 0; it < 4; ++it) {
            int idx = t + it * 256;
            int r = idx >> 6, c = idx & 63;
            Bs[r][c] = Bm[(size_t)(k0 + r) * N + n0 + c];
        }
        __syncthreads();
#pragma unroll
        for (int kk = 0; kk < 16; ++kk) {
            float av[4], bv[4];
#pragma unroll
            for (int i = 0; i < 4; ++i) av[i] = As[kk][ty * 4 + i];
#pragma unroll
            for (int j = 0; j < 4; ++j) bv[j] = Bs[kk][tx * 4 + j];
#pragma unroll
            for (int i = 0; i < 4; ++i)
#pragma unroll
                for (int j = 0; j < 4; ++j) acc[i][j] = fmaf(av[i], bv[j], acc[i][j]);
        }
        __syncthreads();
    }
#pragma unroll
    for (int i = 0; i < 4; ++i) {
        int row = m0 + ty * 4 + i;
        if (row >= M) continue;
#pragma unroll
        for (int j = 0; j < 4; ++j) {
            int col = n0 + tx * 4 + j;
            float v = acc[i][j];
            if (BIAS) v += bias[col];
            if (ACT == 1) v = gelu_exact(v);
            if (ACT == 2) v = gelu_tanh(v);
            size_t o = (size_t)row * N + col;
            if (ACCUM) Cf[o] += v;
            else if (OUTBF16) Cb[o] = __float2bfloat16(v);
            else Cf[o] = v;
        }
    }
}

// ---------------- flash attention (fp32 compute, bf16 proj input) -------------
// grid (S/32, H, B), 256 threads. Each thread: row = t>>3 (0..31), jg = t&7.
__global__ void attn_kernel(const __hip_bfloat16* __restrict__ proj, float* __restrict__ a) {
    int qt = blockIdx.x, head = blockIdx.y, b = blockIdx.z;
    int t = threadIdx.x;
    __shared__ float qs[32][64];
    __shared__ float ks[64][64];
    __shared__ float vs[64][64];
    __shared__ float sc[32][64];
    const __hip_bfloat16* pb = proj + (size_t)b * S_ * PROJN_;
    int q0 = qt * 32;
    int qcol = head * 64;
    for (int idx = t; idx < 32 * 64; idx += 256) {
        int i = idx >> 6, k = idx & 63;
        qs[i][k] = __bfloat162float(pb[(size_t)(q0 + i) * PROJN_ + qcol + k]);
    }
    int row = t >> 3;
    int jg = t & 7;
    float m = -1e30f, l = 0.f;
    float oacc[8];
#pragma unroll
    for (int dd = 0; dd < 8; ++dd) oacc[dd] = 0.f;
    __syncthreads();
    for (int kt = 0; kt < 16; ++kt) {
        int k0 = kt * 64;
        for (int idx = t; idx < 64 * 64; idx += 256) {
            int i = idx >> 6, d = idx & 63;
            size_t r = (size_t)(k0 + i) * PROJN_;
            ks[i][d] = __bfloat162float(pb[r + 1024 + qcol + d]);
            vs[i][d] = __bfloat162float(pb[r + 2048 + qcol + d]);
        }
        __syncthreads();
        float s8[8];
#pragma unroll
        for (int j = 0; j < 8; ++j) s8[j] = 0.f;
        for (int k = 0; k < 64; ++k) {
            float qv = qs[row][k];
#pragma unroll
            for (int j = 0; j < 8; ++j) s8[j] = fmaf(qv, ks[jg * 8 + j][k], s8[j]);
        }
        float tmax = -1e30f;
#pragma unroll
        for (int j = 0; j < 8; ++j) {
            s8[j] *= 0.125f;  // 1/sqrt(64)
            tmax = fmaxf(tmax, s8[j]);
        }
        for (int m8 = 1; m8 < 8; m8 <<= 1) tmax = fmaxf(tmax, __shfl_xor(tmax, m8, 64));
        float mnew = fmaxf(m, tmax);
        float rsum = 0.f;
        float p8[8];
#pragma unroll
        for (int j = 0; j < 8; ++j) {
            p8[j] = expf(s8[j] - mnew);
            rsum += p8[j];
        }
        for (int m8 = 1; m8 < 8; m8 <<= 1) rsum += __shfl_xor(rsum, m8, 64);
        float alpha = expf(m - mnew);
        l = l * alpha + rsum;
        m = mnew;
#pragma unroll
        for (int j = 0; j < 8; ++j) sc[row][jg * 8 + j] = p8[j];
        __syncthreads();
        int d0 = jg * 8;
#pragma unroll
        for (int dd = 0; dd < 8; ++dd) oacc[dd] *= alpha;
        for (int j = 0; j < 64; ++j) {
            float pv = sc[row][j];
#pragma unroll
            for (int dd = 0; dd < 8; ++dd) oacc[dd] = fmaf(pv, vs[j][d0 + dd], oacc[dd]);
        }
        __syncthreads();
    }
    float inv = 1.f / l;
    float* ap = a + ((size_t)b * S_ + q0 + row) * (size_t)(H_ * DH_) + head * 64 + jg * 8;
#pragma unroll
    for (int dd = 0; dd < 8; ++dd) ap[dd] = oacc[dd] * inv;
}

// ---------------- ffg = ff * gelu_tanh(gate) ----------------------------------
__global__ void ffg_kernel(const __hip_bfloat16* __restrict__ proj, float* __restrict__ ffg) {
    size_t idx = (size_t)blockIdx.x * 256 + threadIdx.x;  // over BS_*FF_
    int row = (int)(idx >> 12);
    int j = (int)(idx & 4095);
    const __hip_bfloat16* pr = proj + (size_t)row * PROJN_;
    float ff = __bfloat162float(pr[3072 + j]);
    float gt = __bfloat162float(pr[7168 + j]);
    ffg[idx] = ff * gelu_tanh(gt);
}

extern "C" void kernel_launch(void* const* d_in, const int* in_sizes, int n_in,
                              void* d_out, int out_size, void* d_ws, size_t ws_size,
                              hipStream_t stream) {
    const float* inputs = (const float*)d_in[0];
    const float* time = (const float*)d_in[1];
    const float* in_W = (const float*)d_in[2];
    const float* in_b = (const float*)d_in[3];
    const float* out_W = (const float*)d_in[4];
    const float* out_b = (const float*)d_in[5];
    const float* t_W1 = (const float*)d_in[6];
    const float* t_b1 = (const float*)d_in[7];
    const float* t_W2 = (const float*)d_in[8];
    const float* t_b2 = (const float*)d_in[9];
    const float* ln_scale = (const float*)d_in[10];
    const float* ln_bias = (const float*)d_in[11];
    const float* proj_W = (const float*)d_in[12];
    const float* attn_W = (const float*)d_in[13];
    const float* ff_W = (const float*)d_in[14];
    float* out = (float*)d_out;

    // workspace layout (floats)
    float* ws = (float*)d_ws;
    size_t off = 0;
    float* temb0 = ws + off; off += (size_t)B_ * D_;      // 8K
    float* tact = ws + off;  off += (size_t)B_ * TDIM_;   // 32K
    float* temb = ws + off;  off += (size_t)B_ * D_;      // 8K
    float* pos = ws + off;   off += (size_t)S_ * D_;      // 1M
    float* h = ws + off;     off += (size_t)BS_ * D_;     // 8M
    float* u = ws + off;     off += (size_t)BS_ * D_;     // 8M
    float* a = ws + off;     off += (size_t)BS_ * D_;     // 8M
    float* ffg = ws + off;   off += (size_t)BS_ * FF_;    // 32M
    __hip_bfloat16* proj = (__hip_bfloat16*)(ws + off);   // BS_*11264 bf16

    dim3 blk(256);

    // time embedding
    temb0_kernel<<<B_, 512, 0, stream>>>(time, temb0);
    gemm_kernel<1, 1, 0, 0><<<dim3(TDIM_ / 64, 1), blk, 0, stream>>>(
        temb0, t_W1, t_b1, tact, nullptr, B_, TDIM_, D_);
    gemm_kernel<1, 1, 0, 0><<<dim3(D_ / 64, 1), blk, 0, stream>>>(
        tact, t_W2, t_b2, temb, nullptr, B_, D_, TDIM_);
    // positional embedding
    pos_kernel<<<S_, 512, 0, stream>>>(pos);
    // input projection + embeddings
    gemm_kernel<0, 1, 0, 0><<<dim3(D_ / 64, BS_ / 64), blk, 0, stream>>>(
        inputs, in_W, in_b, h, nullptr, BS_, D_, 2 * E_);
    addpe_kernel<<<(BS_ * D_) / 256, blk, 0, stream>>>(h, pos, temb);

    for (int l = 0; l < L_; ++l) {
        const float* Wp = proj_W + (size_t)l * D_ * PROJN_;
        const float* Wa = attn_W + (size_t)l * (H_ * DH_) * D_;
        const float* Wf = ff_W + (size_t)l * FF_ * D_;
        ln_kernel<<<BS_, blk, 0, stream>>>(h, ln_scale + l * D_, ln_bias + l * D_, u);
        gemm_kernel<0, 0, 0, 1><<<dim3(PROJN_ / 64, BS_ / 64), blk, 0, stream>>>(
            u, Wp, nullptr, nullptr, proj, BS_, PROJN_, D_);
        attn_kernel<<<dim3(S_ / 32, H_, B_), blk, 0, stream>>>(proj, a);
        gemm_kernel<0, 0, 1, 0><<<dim3(D_ / 64, BS_ / 64), blk, 0, stream>>>(
            a, Wa, nullptr, h, nullptr, BS_, D_, H_ * DH_);  // h += a@Wa
        ffg_kernel<<<(size_t)(BS_ * (size_t)FF_) / 256, blk, 0, stream>>>(proj, ffg);
        gemm_kernel<0, 0, 1, 0><<<dim3(D_ / 64, BS_ / 64), blk, 0, stream>>>(
            ffg, Wf, nullptr, h, nullptr, BS_, D_, FF_);  // h += ffg@Wf
    }
    // output projection
    gemm_kernel<0, 1, 0, 0><<<dim3(E_ / 64, BS_ / 64), blk, 0, stream>>>(
        h, out_W, out_b, out, nullptr, BS_, E_, D_);
}

// Round 2
// 26414.316 us; speedup vs baseline: 3.2674x; 3.2674x over previous
//
#include <hip/hip_runtime.h>
#include <hip/hip_bf16.h>
#include <math.h>

// Problem constants
static constexpr int B_ = 8, S_ = 1024, E_ = 256, D_ = 1024, H_ = 16, DH_ = 64,
                     FF_ = 4096, L_ = 12, TDIM_ = 4096;
static constexpr int BS_ = B_ * S_;                    // 8192 rows
static constexpr int PROJN_ = 3 * H_ * DH_ + 2 * FF_;  // 11264

typedef __attribute__((ext_vector_type(8))) short bf16x8;
typedef __attribute__((ext_vector_type(4))) short bf16x4;
typedef __attribute__((ext_vector_type(4))) float f32x4;

__device__ __forceinline__ float b2f(short b) {
    return __uint_as_float(((unsigned)(unsigned short)b) << 16);
}
__device__ __forceinline__ short f2b(float f) {
    __hip_bfloat16 h = __float2bfloat16(f);
    return *reinterpret_cast<short*>(&h);
}
__device__ __forceinline__ float gelu_exact(float x) {
    return 0.5f * x * (1.f + erff(x * 0.70710678118654752440f));
}
__device__ __forceinline__ float gelu_tanh(float x) {
    float x3 = x * x * x;
    return 0.5f * x * (1.f + tanhf(0.79788456080286535588f * (x + 0.044715f * x3)));
}

#define GLOAD16(g, l)                                                     \
    __builtin_amdgcn_global_load_lds(                                     \
        (const __attribute__((address_space(1))) void*)(g),               \
        (__attribute__((address_space(3))) void*)(l), 16, 0, 0)

// ---------------- time embedding base: temb0[b] = [sin(ts), cos(ts)] -----------
__global__ void temb0_kernel(const float* __restrict__ time, float* __restrict__ temb0) {
    int b = blockIdx.x;
    int i = threadIdx.x;  // 0..511
    float inv_ts = expf((float)i * (-logf(10000.f) / 511.f));  // half-1 = 511
    float ts = time[b] * inv_ts;
    temb0[b * D_ + i] = sinf(ts);
    temb0[b * D_ + 512 + i] = cosf(ts);
}

// ---------------- fixed positional embedding ----------------------------------
__global__ void pos_kernel(float* __restrict__ pos) {
    int s = blockIdx.x;
    int j = threadIdx.x;  // 0..511
    float inv_freq = expf((float)j * (-logf(10000.f) / 512.f));  // 2j/D = j/512
    float arg = (float)s * inv_freq;
    pos[s * D_ + j] = sinf(arg);
    pos[s * D_ + 512 + j] = cosf(arg);
}

// ---------------- tiny-M GEMM + exact GELU: C[8][N] = gelu(A[8][K]@B + bias) ---
// grid N/64 blocks, 256 threads: col = t&63, kslice = t>>6 (4 slices).
__global__ void tmlp_kernel(const float* __restrict__ A, const float* __restrict__ Bw,
                            const float* __restrict__ bias, float* __restrict__ C,
                            int K, int N) {
    __shared__ float Ast[8][256];
    __shared__ float red2[4][64][8];
    int t = threadIdx.x;
    int col = t & 63, ks = t >> 6;
    int n = blockIdx.x * 64 + col;
    float acc[8];
#pragma unroll
    for (int b = 0; b < 8; ++b) acc[b] = 0.f;
    for (int c0 = 0; c0 < K; c0 += 256) {
#pragma unroll
        for (int i = 0; i < 8; ++i) {
            int idx = t + i * 256;
            Ast[idx >> 8][idx & 255] = A[(idx >> 8) * K + c0 + (idx & 255)];
        }
        __syncthreads();
        for (int k = ks * 64; k < ks * 64 + 64; ++k) {
            float w = Bw[(size_t)(c0 + k) * N + n];
#pragma unroll
            for (int b = 0; b < 8; ++b) acc[b] = fmaf(Ast[b][k], w, acc[b]);
        }
        __syncthreads();
    }
#pragma unroll
    for (int b = 0; b < 8; ++b) red2[ks][col][b] = acc[b];
    __syncthreads();
    if (ks == 0) {
#pragma unroll
        for (int b = 0; b < 8; ++b) {
            float s = red2[0][col][b] + red2[1][col][b] + red2[2][col][b] + red2[3][col][b];
            C[(size_t)b * N + n] = gelu_exact(s + bias[n]);
        }
    }
}

// ---------------- h += pos[s] + temb[b] ---------------------------------------
__global__ void addpe_kernel(float* __restrict__ h, const float* __restrict__ pos,
                             const float* __restrict__ temb) {
    size_t idx = (size_t)blockIdx.x * 256 + threadIdx.x;  // over BS_*D_
    int d = (int)(idx & 1023);
    int s = (int)((idx >> 10) & 1023);
    int b = (int)(idx >> 20);
    h[idx] += pos[s * D_ + d] + temb[b * D_ + d];
}

// ---------------- fp32 -> bf16 elementwise (n multiple of 1024) ---------------
__global__ void f2b4_kernel(const float* __restrict__ in, __hip_bfloat16* __restrict__ out) {
    size_t i = ((size_t)blockIdx.x * 256 + threadIdx.x) * 4;
    float4 v = *reinterpret_cast<const float4*>(in + i);
    bf16x4 o;
    o[0] = f2b(v.x); o[1] = f2b(v.y); o[2] = f2b(v.z); o[3] = f2b(v.w);
    *reinterpret_cast<bf16x4*>(reinterpret_cast<short*>(out) + i) = o;
}

// ---------------- transpose + convert: W[K][N] fp32 -> Wt[N][K] bf16 ----------
// grid (N/32, K/32), 256 threads (tx=t&31, ty=t>>5 in 0..7)
__global__ void convT_kernel(const float* __restrict__ W, __hip_bfloat16* __restrict__ Wt,
                             int K, int N) {
    __shared__ float tile[32][33];
    int t = threadIdx.x;
    int tx = t & 31, ty = t >> 5;
    int n0 = blockIdx.x * 32, k0 = blockIdx.y * 32;
#pragma unroll
    for (int r = 0; r < 4; ++r) {
        int k = ty + r * 8;
        tile[k][tx] = W[(size_t)(k0 + k) * N + n0 + tx];
    }
    __syncthreads();
#pragma unroll
    for (int r = 0; r < 4; ++r) {
        int n = ty + r * 8;
        Wt[(size_t)(n0 + n) * K + k0 + tx] = __float2bfloat16(tile[tx][n]);
    }
}

// ---------------- LayerNorm: u = bf16((h-m)*rsqrt(v+eps)*g + b) ---------------
__global__ void ln_kernel(const float* __restrict__ h, const float* __restrict__ g,
                          const float* __restrict__ bb, __hip_bfloat16* __restrict__ u) {
    int row = blockIdx.x;
    int t = threadIdx.x;  // 256 threads, 4 elems each
    const float4 v = reinterpret_cast<const float4*>(h + (size_t)row * D_)[t];
    __shared__ float red[8];
    float s = v.x + v.y + v.z + v.w;
    for (int m8 = 1; m8 < 64; m8 <<= 1) s += __shfl_xor(s, m8, 64);
    if ((t & 63) == 0) red[t >> 6] = s;
    __syncthreads();
    float mean = (red[0] + red[1] + red[2] + red[3]) * (1.f / 1024.f);
    float dx = v.x - mean, dy = v.y - mean, dz = v.z - mean, dw = v.w - mean;
    float sq = dx * dx + dy * dy + dz * dz + dw * dw;
    for (int m8 = 1; m8 < 64; m8 <<= 1) sq += __shfl_xor(sq, m8, 64);
    if ((t & 63) == 0) red[4 + (t >> 6)] = sq;
    __syncthreads();
    float var = (red[4] + red[5] + red[6] + red[7]) * (1.f / 1024.f);
    float inv = rsqrtf(var + 1e-5f);
    int c = t * 4;
    bf16x4 o;
    o[0] = f2b(dx * inv * g[c + 0] + bb[c + 0]);
    o[1] = f2b(dy * inv * g[c + 1] + bb[c + 1]);
    o[2] = f2b(dz * inv * g[c + 2] + bb[c + 2]);
    o[3] = f2b(dw * inv * g[c + 3] + bb[c + 3]);
    *reinterpret_cast<bf16x4*>(reinterpret_cast<short*>(u) + (size_t)row * D_ + c) = o;
}

// ---------------- MFMA bf16 GEMM, m97 structure -------------------------------
// C[M][N] = A[M][K] @ Bt[N][K]^T.  128x128 tile, BK=32, 256 thr (4 waves 2x2).
// MODE 0: Cf = acc (+bias); MODE 1: Cb = bf16(acc); MODE 2: Cf += acc.
template <int MODE, int BIAS>
__global__ __launch_bounds__(256) void mfma_gemm(
    const __hip_bfloat16* __restrict__ A, const __hip_bfloat16* __restrict__ Bt,
    const float* __restrict__ bias, float* __restrict__ Cf,
    __hip_bfloat16* __restrict__ Cb, int M, int N, int K) {
    __shared__ __align__(16) char As[128 * 64];  // [128 rows][32 bf16]
    __shared__ __align__(16) char Bs[128 * 64];
    int t = threadIdx.x;
    int lane = t & 63, wid = t >> 6;
    int m0 = blockIdx.y * 128, n0 = blockIdx.x * 128;
    size_t rowb = (size_t)K * 2;
    // staging: wave w call c covers tile rows [w*32+c*16, +16), lane: row +=(l>>2), col (l&3)*16B
    int srow = wid * 32 + (lane >> 2);
    int scol = (lane & 3) * 16;
    const char* ag0 = (const char*)A + (size_t)(m0 + srow) * rowb + scol;
    const char* ag1 = (const char*)A + (size_t)(m0 + srow + 16) * rowb + scol;
    const char* bg0 = (const char*)Bt + (size_t)(n0 + srow) * rowb + scol;
    const char* bg1 = (const char*)Bt + (size_t)(n0 + srow + 16) * rowb + scol;
    int lb0 = wid * 32 * 64;          // LDS byte base, call 0
    int lb1 = lb0 + 16 * 64;          // call 1
    // compute-side indices
    int wr = (wid >> 1) * 64, wc = (wid & 1) * 64;
    int lr = lane & 15;
    int a_base = (wr + lr) * 64 + (lane >> 4) * 16;  // byte offset into As
    int b_base = (wc + lr) * 64 + (lane >> 4) * 16;
    f32x4 acc[4][4] = {};
    int nkt = K >> 5;
    for (int kt = 0; kt < nkt; ++kt) {
        GLOAD16(ag0, As + lb0);
        GLOAD16(ag1, As + lb1);
        GLOAD16(bg0, Bs + lb0);
        GLOAD16(bg1, Bs + lb1);
        ag0 += 64; ag1 += 64; bg0 += 64; bg1 += 64;  // advance BK=32 bf16
        __syncthreads();  // drains vmcnt: LDS tile ready
        bf16x8 af[4], bf[4];
#pragma unroll
        for (int f = 0; f < 4; ++f) {
            af[f] = *reinterpret_cast<const bf16x8*>(As + a_base + f * 1024);
            bf[f] = *reinterpret_cast<const bf16x8*>(Bs + b_base + f * 1024);
        }
#pragma unroll
        for (int i = 0; i < 4; ++i)
#pragma unroll
            for (int j = 0; j < 4; ++j)
                acc[i][j] = __builtin_amdgcn_mfma_f32_16x16x32_bf16(af[i], bf[j], acc[i][j], 0, 0, 0);
        __syncthreads();  // all waves done reading before next stage overwrites
    }
    // epilogue: C/D map col=lane&15, row=(lane>>4)*4+reg (m89/m91 verified)
    int crow0 = m0 + wr + (lane >> 4) * 4;
    int ccol0 = n0 + wc + lr;
#pragma unroll
    for (int i = 0; i < 4; ++i) {
#pragma unroll
        for (int j = 0; j < 4; ++j) {
            int col = ccol0 + j * 16;
            float bv = BIAS ? bias[col] : 0.f;
            f32x4 v = acc[i][j];
#pragma unroll
            for (int r = 0; r < 4; ++r) {
                size_t o = (size_t)(crow0 + i * 16 + r) * N + col;
                float val = v[r] + bv;
                if (MODE == 0) Cf[o] = val;
                else if (MODE == 1) Cb[o] = __float2bfloat16(val);
                else Cf[o] += val;
            }
        }
    }
}

// ---------------- flash attention (fp32 compute, bf16 proj input) -------------
// grid (S/32, H, B), 256 threads. row = t>>3 (0..31), jg = t&7.
// LDS leading dim 65 (= 1 mod 32) kills the 8-way row-bank conflicts.
__global__ void attn_kernel(const __hip_bfloat16* __restrict__ proj,
                            __hip_bfloat16* __restrict__ a) {
    int qt = blockIdx.x, head = blockIdx.y, b = blockIdx.z;
    int t = threadIdx.x;
    __shared__ float qs[32][65];
    __shared__ float ks[64][65];
    __shared__ float vs[64][65];
    __shared__ float sc[32][65];
    const __hip_bfloat16* pb = proj + (size_t)b * S_ * PROJN_;
    int q0 = qt * 32;
    int qcol = head * 64;
    {
        int i = t >> 3, k8 = (t & 7) * 8;
        bf16x8 v = *reinterpret_cast<const bf16x8*>(pb + (size_t)(q0 + i) * PROJN_ + qcol + k8);
#pragma unroll
        for (int d = 0; d < 8; ++d) qs[i][k8 + d] = b2f(v[d]);
    }
    int row = t >> 3;
    int jg = t & 7;
    float m = -1e30f, l = 0.f;
    float oacc[8];
#pragma unroll
    for (int dd = 0; dd < 8; ++dd) oacc[dd] = 0.f;
    __syncthreads();
    for (int kt = 0; kt < 16; ++kt) {
        int k0 = kt * 64;
        for (int idx = t; idx < 512; idx += 256) {
            int i = idx >> 3, k8 = (idx & 7) * 8;
            size_t r = (size_t)(k0 + i) * PROJN_ + qcol;
            bf16x8 kv = *reinterpret_cast<const bf16x8*>(pb + r + 1024 + k8);
            bf16x8 vv = *reinterpret_cast<const bf16x8*>(pb + r + 2048 + k8);
#pragma unroll
            for (int d = 0; d < 8; ++d) {
                ks[i][k8 + d] = b2f(kv[d]);
                vs[i][k8 + d] = b2f(vv[d]);
            }
        }
        __syncthreads();
        float s8[8];
#pragma unroll
        for (int j = 0; j < 8; ++j) s8[j] = 0.f;
        for (int k = 0; k < 64; ++k) {
            float qv = qs[row][k];
#pragma unroll
            for (int j = 0; j < 8; ++j) s8[j] = fmaf(qv, ks[jg * 8 + j][k], s8[j]);
        }
        float tmax = -1e30f;
#pragma unroll
        for (int j = 0; j < 8; ++j) {
            s8[j] *= 0.125f;  // 1/sqrt(64)
            tmax = fmaxf(tmax, s8[j]);
        }
        for (int m8 = 1; m8 < 8; m8 <<= 1) tmax = fmaxf(tmax, __shfl_xor(tmax, m8, 64));
        float mnew = fmaxf(m, tmax);
        float rsum = 0.f;
        float p8[8];
#pragma unroll
        for (int j = 0; j < 8; ++j) {
            p8[j] = expf(s8[j] - mnew);
            rsum += p8[j];
        }
        for (int m8 = 1; m8 < 8; m8 <<= 1) rsum += __shfl_xor(rsum, m8, 64);
        float alpha = expf(m - mnew);
        l = l * alpha + rsum;
        m = mnew;
#pragma unroll
        for (int j = 0; j < 8; ++j) sc[row][jg * 8 + j] = p8[j];
        __syncthreads();
        int d0 = jg * 8;
#pragma unroll
        for (int dd = 0; dd < 8; ++dd) oacc[dd] *= alpha;
        for (int j = 0; j < 64; ++j) {
            float pv = sc[row][j];
#pragma unroll
            for (int dd = 0; dd < 8; ++dd) oacc[dd] = fmaf(pv, vs[j][d0 + dd], oacc[dd]);
        }
        __syncthreads();
    }
    float inv = 1.f / l;
    bf16x8 ov;
#pragma unroll
    for (int dd = 0; dd < 8; ++dd) ov[dd] = f2b(oacc[dd] * inv);
    short* ap = reinterpret_cast<short*>(a) +
                ((size_t)b * S_ + q0 + row) * (size_t)(H_ * DH_) + head * 64 + jg * 8;
    *reinterpret_cast<bf16x8*>(ap) = ov;
}

// ---------------- ffg = bf16(ff * gelu_tanh(gate)) ----------------------------
__global__ void ffg_kernel(const __hip_bfloat16* __restrict__ proj,
                           __hip_bfloat16* __restrict__ ffg) {
    size_t idx = (size_t)blockIdx.x * 256 + threadIdx.x;  // over BS_*FF_/8
    int row = (int)(idx >> 9);
    int j8 = (int)(idx & 511) * 8;
    const __hip_bfloat16* pr = proj + (size_t)row * PROJN_;
    bf16x8 fv = *reinterpret_cast<const bf16x8*>(pr + 3072 + j8);
    bf16x8 gv = *reinterpret_cast<const bf16x8*>(pr + 7168 + j8);
    bf16x8 o;
#pragma unroll
    for (int d = 0; d < 8; ++d) o[d] = f2b(b2f(fv[d]) * gelu_tanh(b2f(gv[d])));
    *reinterpret_cast<bf16x8*>(reinterpret_cast<short*>(ffg) + (size_t)row * FF_ + j8) = o;
}

extern "C" void kernel_launch(void* const* d_in, const int* in_sizes, int n_in,
                              void* d_out, int out_size, void* d_ws, size_t ws_size,
                              hipStream_t stream) {
    const float* inputs = (const float*)d_in[0];
    const float* time = (const float*)d_in[1];
    const float* in_W = (const float*)d_in[2];
    const float* in_b = (const float*)d_in[3];
    const float* out_W = (const float*)d_in[4];
    const float* out_b = (const float*)d_in[5];
    const float* t_W1 = (const float*)d_in[6];
    const float* t_b1 = (const float*)d_in[7];
    const float* t_W2 = (const float*)d_in[8];
    const float* t_b2 = (const float*)d_in[9];
    const float* ln_scale = (const float*)d_in[10];
    const float* ln_bias = (const float*)d_in[11];
    const float* proj_W = (const float*)d_in[12];
    const float* attn_W = (const float*)d_in[13];
    const float* ff_W = (const float*)d_in[14];
    float* out = (float*)d_out;

    // workspace layout (float units; bf16 buffers carved as 2 per float)
    float* ws = (float*)d_ws;
    size_t off = 0;
    float* temb0 = ws + off; off += 8 * 1024;
    float* tact = ws + off;  off += 8 * 4096;
    float* temb = ws + off;  off += 8 * 1024;
    float* pos = ws + off;   off += (size_t)S_ * D_;
    float* h = ws + off;     off += (size_t)BS_ * D_;
    __hip_bfloat16* u = (__hip_bfloat16*)(ws + off);      off += (size_t)BS_ * D_ / 2;
    __hip_bfloat16* a = (__hip_bfloat16*)(ws + off);      off += (size_t)BS_ * D_ / 2;
    __hip_bfloat16* ffg = (__hip_bfloat16*)(ws + off);    off += (size_t)BS_ * FF_ / 2;
    __hip_bfloat16* proj = (__hip_bfloat16*)(ws + off);   off += (size_t)BS_ * PROJN_ / 2;
    __hip_bfloat16* hb = (__hip_bfloat16*)(ws + off);     off += (size_t)BS_ * D_ / 2;
    __hip_bfloat16* inbf = (__hip_bfloat16*)(ws + off);   off += (size_t)BS_ * (2 * E_) / 2;
    __hip_bfloat16* in_Wt = (__hip_bfloat16*)(ws + off);  off += (size_t)(2 * E_) * D_ / 2;
    __hip_bfloat16* out_Wt = (__hip_bfloat16*)(ws + off); off += (size_t)D_ * E_ / 2;
    __hip_bfloat16* Wpt = (__hip_bfloat16*)(ws + off);    off += (size_t)D_ * PROJN_ / 2;
    __hip_bfloat16* Wat = (__hip_bfloat16*)(ws + off);    off += (size_t)D_ * D_ / 2;
    __hip_bfloat16* Wft = (__hip_bfloat16*)(ws + off);    off += (size_t)FF_ * D_ / 2;

    dim3 blk(256);

    // time embedding MLP (K-parallel small-M kernels)
    temb0_kernel<<<B_, 512, 0, stream>>>(time, temb0);
    tmlp_kernel<<<TDIM_ / 64, blk, 0, stream>>>(temb0, t_W1, t_b1, tact, D_, TDIM_);
    tmlp_kernel<<<D_ / 64, blk, 0, stream>>>(tact, t_W2, t_b2, temb, TDIM_, D_);
    // positional embedding
    pos_kernel<<<S_, 512, 0, stream>>>(pos);
    // one-time conversions
    f2b4_kernel<<<(BS_ * 2 * E_) / 1024, blk, 0, stream>>>(inputs, inbf);
    convT_kernel<<<dim3(D_ / 32, (2 * E_) / 32), blk, 0, stream>>>(in_W, in_Wt, 2 * E_, D_);
    convT_kernel<<<dim3(E_ / 32, D_ / 32), blk, 0, stream>>>(out_W, out_Wt, D_, E_);
    // input projection + embeddings
    mfma_gemm<0, 1><<<dim3(D_ / 128, BS_ / 128), blk, 0, stream>>>(
        inbf, in_Wt, in_b, h, nullptr, BS_, D_, 2 * E_);
    addpe_kernel<<<(BS_ * D_) / 256, blk, 0, stream>>>(h, pos, temb);

    for (int l = 0; l < L_; ++l) {
        const float* Wp = proj_W + (size_t)l * D_ * PROJN_;
        const float* Wa = attn_W + (size_t)l * (H_ * DH_) * D_;
        const float* Wf = ff_W + (size_t)l * FF_ * D_;
        convT_kernel<<<dim3(PROJN_ / 32, D_ / 32), blk, 0, stream>>>(Wp, Wpt, D_, PROJN_);
        convT_kernel<<<dim3(D_ / 32, D_ / 32), blk, 0, stream>>>(Wa, Wat, D_, D_);
        convT_kernel<<<dim3(D_ / 32, FF_ / 32), blk, 0, stream>>>(Wf, Wft, FF_, D_);
        ln_kernel<<<BS_, blk, 0, stream>>>(h, ln_scale + l * D_, ln_bias + l * D_, u);
        mfma_gemm<1, 0><<<dim3(PROJN_ / 128, BS_ / 128), blk, 0, stream>>>(
            u, Wpt, nullptr, nullptr, proj, BS_, PROJN_, D_);
        attn_kernel<<<dim3(S_ / 32, H_, B_), blk, 0, stream>>>(proj, a);
        mfma_gemm<2, 0><<<dim3(D_ / 128, BS_ / 128), blk, 0, stream>>>(
            a, Wat, nullptr, h, nullptr, BS_, D_, H_ * DH_);  // h += a@Wa
        ffg_kernel<<<(BS_ * (FF_ / 8)) / 256, blk, 0, stream>>>(proj, ffg);
        mfma_gemm<2, 0><<<dim3(D_ / 128, BS_ / 128), blk, 0, stream>>>(
            ffg, Wft, nullptr, h, nullptr, BS_, D_, FF_);  // h += ffg@Wf
    }
    // output projection
    f2b4_kernel<<<(BS_ * D_) / 1024, blk, 0, stream>>>(h, hb);
    mfma_gemm<0, 1><<<dim3(E_ / 128, BS_ / 128), blk, 0, stream>>>(
        hb, out_Wt, out_b, out, nullptr, BS_, E_, D_);
}

// Round 3
// 7845.339 us; speedup vs baseline: 11.0009x; 3.3669x over previous
//
#include <hip/hip_runtime.h>
#include <hip/hip_bf16.h>
#include <math.h>

// Problem constants
static constexpr int B_ = 8, S_ = 1024, E_ = 256, D_ = 1024, H_ = 16, DH_ = 64,
                     FF_ = 4096, L_ = 12, TDIM_ = 4096;
static constexpr int BS_ = B_ * S_;                    // 8192 rows
static constexpr int PROJN_ = 3 * H_ * DH_ + 2 * FF_;  // 11264

typedef __attribute__((ext_vector_type(8))) short bf16x8;
typedef __attribute__((ext_vector_type(4))) short bf16x4;
typedef __attribute__((ext_vector_type(4))) float f32x4;

__device__ __forceinline__ float b2f(short b) {
    return __uint_as_float(((unsigned)(unsigned short)b) << 16);
}
__device__ __forceinline__ short f2b(float f) {
    __hip_bfloat16 h = __float2bfloat16(f);
    return *reinterpret_cast<short*>(&h);
}
__device__ __forceinline__ float gelu_exact(float x) {
    return 0.5f * x * (1.f + erff(x * 0.70710678118654752440f));
}
__device__ __forceinline__ float gelu_tanh(float x) {
    float x3 = x * x * x;
    return 0.5f * x * (1.f + tanhf(0.79788456080286535588f * (x + 0.044715f * x3)));
}

#define GLOAD16(g, l)                                                     \
    __builtin_amdgcn_global_load_lds(                                     \
        (const __attribute__((address_space(1))) void*)(g),               \
        (__attribute__((address_space(3))) void*)(l), 16, 0, 0)

// ---------------- time embedding base: temb0[b] = [sin(ts), cos(ts)] -----------
__global__ void temb0_kernel(const float* __restrict__ time, float* __restrict__ temb0) {
    int b = blockIdx.x;
    int i = threadIdx.x;  // 0..511
    float inv_ts = expf((float)i * (-logf(10000.f) / 511.f));  // half-1 = 511
    float ts = time[b] * inv_ts;
    temb0[b * D_ + i] = sinf(ts);
    temb0[b * D_ + 512 + i] = cosf(ts);
}

// ---------------- fixed positional embedding ----------------------------------
__global__ void pos_kernel(float* __restrict__ pos) {
    int s = blockIdx.x;
    int j = threadIdx.x;  // 0..511
    float inv_freq = expf((float)j * (-logf(10000.f) / 512.f));  // 2j/D = j/512
    float arg = (float)s * inv_freq;
    pos[s * D_ + j] = sinf(arg);
    pos[s * D_ + 512 + j] = cosf(arg);
}

// ---------------- tiny-M GEMM + exact GELU: C[8][N] = gelu(A[8][K]@B + bias) ---
__global__ void tmlp_kernel(const float* __restrict__ A, const float* __restrict__ Bw,
                            const float* __restrict__ bias, float* __restrict__ C,
                            int K, int N) {
    __shared__ float Ast[8][256];
    __shared__ float red2[4][64][8];
    int t = threadIdx.x;
    int col = t & 63, ks = t >> 6;
    int n = blockIdx.x * 64 + col;
    float acc[8];
#pragma unroll
    for (int b = 0; b < 8; ++b) acc[b] = 0.f;
    for (int c0 = 0; c0 < K; c0 += 256) {
#pragma unroll
        for (int i = 0; i < 8; ++i) {
            int idx = t + i * 256;
            Ast[idx >> 8][idx & 255] = A[(idx >> 8) * K + c0 + (idx & 255)];
        }
        __syncthreads();
        for (int k = ks * 64; k < ks * 64 + 64; ++k) {
            float w = Bw[(size_t)(c0 + k) * N + n];
#pragma unroll
            for (int b = 0; b < 8; ++b) acc[b] = fmaf(Ast[b][k], w, acc[b]);
        }
        __syncthreads();
    }
#pragma unroll
    for (int b = 0; b < 8; ++b) red2[ks][col][b] = acc[b];
    __syncthreads();
    if (ks == 0) {
#pragma unroll
        for (int b = 0; b < 8; ++b) {
            float s = red2[0][col][b] + red2[1][col][b] + red2[2][col][b] + red2[3][col][b];
            C[(size_t)b * N + n] = gelu_exact(s + bias[n]);
        }
    }
}

// ---------------- h += pos[s] + temb[b] ---------------------------------------
__global__ void addpe_kernel(float* __restrict__ h, const float* __restrict__ pos,
                             const float* __restrict__ temb) {
    size_t idx = (size_t)blockIdx.x * 256 + threadIdx.x;  // over BS_*D_
    int d = (int)(idx & 1023);
    int s = (int)((idx >> 10) & 1023);
    int b = (int)(idx >> 20);
    h[idx] += pos[s * D_ + d] + temb[b * D_ + d];
}

// ---------------- fp32 -> bf16 elementwise (n multiple of 1024) ---------------
__global__ void f2b4_kernel(const float* __restrict__ in, __hip_bfloat16* __restrict__ out) {
    size_t i = ((size_t)blockIdx.x * 256 + threadIdx.x) * 4;
    float4 v = *reinterpret_cast<const float4*>(in + i);
    bf16x4 o;
    o[0] = f2b(v.x); o[1] = f2b(v.y); o[2] = f2b(v.z); o[3] = f2b(v.w);
    *reinterpret_cast<bf16x4*>(reinterpret_cast<short*>(out) + i) = o;
}

// ---------------- transpose + convert: W[K][N] fp32 -> Wt[N][K] bf16 ----------
__global__ void convT_kernel(const float* __restrict__ W, __hip_bfloat16* __restrict__ Wt,
                             int K, int N) {
    __shared__ float tile[32][33];
    int t = threadIdx.x;
    int tx = t & 31, ty = t >> 5;
    int n0 = blockIdx.x * 32, k0 = blockIdx.y * 32;
#pragma unroll
    for (int r = 0; r < 4; ++r) {
        int k = ty + r * 8;
        tile[k][tx] = W[(size_t)(k0 + k) * N + n0 + tx];
    }
    __syncthreads();
#pragma unroll
    for (int r = 0; r < 4; ++r) {
        int n = ty + r * 8;
        Wt[(size_t)(n0 + n) * K + k0 + tx] = __float2bfloat16(tile[tx][n]);
    }
}

// ---------------- LayerNorm: u = bf16((h-m)*rsqrt(v+eps)*g + b) ---------------
__global__ void ln_kernel(const float* __restrict__ h, const float* __restrict__ g,
                          const float* __restrict__ bb, __hip_bfloat16* __restrict__ u) {
    int row = blockIdx.x;
    int t = threadIdx.x;  // 256 threads, 4 elems each
    const float4 v = reinterpret_cast<const float4*>(h + (size_t)row * D_)[t];
    __shared__ float red[8];
    float s = v.x + v.y + v.z + v.w;
    for (int m8 = 1; m8 < 64; m8 <<= 1) s += __shfl_xor(s, m8, 64);
    if ((t & 63) == 0) red[t >> 6] = s;
    __syncthreads();
    float mean = (red[0] + red[1] + red[2] + red[3]) * (1.f / 1024.f);
    float dx = v.x - mean, dy = v.y - mean, dz = v.z - mean, dw = v.w - mean;
    float sq = dx * dx + dy * dy + dz * dz + dw * dw;
    for (int m8 = 1; m8 < 64; m8 <<= 1) sq += __shfl_xor(sq, m8, 64);
    if ((t & 63) == 0) red[4 + (t >> 6)] = sq;
    __syncthreads();
    float var = (red[4] + red[5] + red[6] + red[7]) * (1.f / 1024.f);
    float inv = rsqrtf(var + 1e-5f);
    int c = t * 4;
    bf16x4 o;
    o[0] = f2b(dx * inv * g[c + 0] + bb[c + 0]);
    o[1] = f2b(dy * inv * g[c + 1] + bb[c + 1]);
    o[2] = f2b(dz * inv * g[c + 2] + bb[c + 2]);
    o[3] = f2b(dw * inv * g[c + 3] + bb[c + 3]);
    *reinterpret_cast<bf16x4*>(reinterpret_cast<short*>(u) + (size_t)row * D_ + c) = o;
}

// ---------------- MFMA bf16 GEMM, m97 structure -------------------------------
// C[M][N] = A[M][K] @ Bt[N][K]^T.  128x128 tile, BK=32, 256 thr (4 waves 2x2).
template <int MODE, int BIAS>
__global__ __launch_bounds__(256) void mfma_gemm(
    const __hip_bfloat16* __restrict__ A, const __hip_bfloat16* __restrict__ Bt,
    const float* __restrict__ bias, float* __restrict__ Cf,
    __hip_bfloat16* __restrict__ Cb, int M, int N, int K) {
    __shared__ __align__(16) char As[128 * 64];  // [128 rows][32 bf16]
    __shared__ __align__(16) char Bs[128 * 64];
    int t = threadIdx.x;
    int lane = t & 63, wid = t >> 6;
    int m0 = blockIdx.y * 128, n0 = blockIdx.x * 128;
    size_t rowb = (size_t)K * 2;
    int srow = wid * 32 + (lane >> 2);
    int scol = (lane & 3) * 16;
    const char* ag0 = (const char*)A + (size_t)(m0 + srow) * rowb + scol;
    const char* ag1 = (const char*)A + (size_t)(m0 + srow + 16) * rowb + scol;
    const char* bg0 = (const char*)Bt + (size_t)(n0 + srow) * rowb + scol;
    const char* bg1 = (const char*)Bt + (size_t)(n0 + srow + 16) * rowb + scol;
    int lb0 = wid * 32 * 64;
    int lb1 = lb0 + 16 * 64;
    int wr = (wid >> 1) * 64, wc = (wid & 1) * 64;
    int lr = lane & 15;
    int a_base = (wr + lr) * 64 + (lane >> 4) * 16;
    int b_base = (wc + lr) * 64 + (lane >> 4) * 16;
    f32x4 acc[4][4] = {};
    int nkt = K >> 5;
    for (int kt = 0; kt < nkt; ++kt) {
        GLOAD16(ag0, As + lb0);
        GLOAD16(ag1, As + lb1);
        GLOAD16(bg0, Bs + lb0);
        GLOAD16(bg1, Bs + lb1);
        ag0 += 64; ag1 += 64; bg0 += 64; bg1 += 64;
        __syncthreads();
        bf16x8 af[4], bf[4];
#pragma unroll
        for (int f = 0; f < 4; ++f) {
            af[f] = *reinterpret_cast<const bf16x8*>(As + a_base + f * 1024);
            bf[f] = *reinterpret_cast<const bf16x8*>(Bs + b_base + f * 1024);
        }
#pragma unroll
        for (int i = 0; i < 4; ++i)
#pragma unroll
            for (int j = 0; j < 4; ++j)
                acc[i][j] = __builtin_amdgcn_mfma_f32_16x16x32_bf16(af[i], bf[j], acc[i][j], 0, 0, 0);
        __syncthreads();
    }
    int crow0 = m0 + wr + (lane >> 4) * 4;
    int ccol0 = n0 + wc + lr;
#pragma unroll
    for (int i = 0; i < 4; ++i) {
#pragma unroll
        for (int j = 0; j < 4; ++j) {
            int col = ccol0 + j * 16;
            float bv = BIAS ? bias[col] : 0.f;
            f32x4 v = acc[i][j];
#pragma unroll
            for (int r = 0; r < 4; ++r) {
                size_t o = (size_t)(crow0 + i * 16 + r) * N + col;
                float val = v[r] + bv;
                if (MODE == 0) Cf[o] = val;
                else if (MODE == 1) Cb[o] = __float2bfloat16(val);
                else Cf[o] += val;
            }
        }
    }
}

// ---------------- MFMA flash attention ----------------------------------------
// grid (S/64, H, B), 256 thr = 4 waves; wave w owns q rows q0+w*16..+15.
// S^T = mfma(K, Q): lane's softmax state is scalar for q = lane&15.
// K: global_load_lds, linear LDS + pre-swizzled global src (XOR 16B groups).
// V: reg-staged transposed vsT[d][kv], rotated scalar writes, same XOR swizzle.
// P: per-wave LDS roundtrip (16 b16 writes -> b128 A-frag reads).
__global__ __launch_bounds__(256, 2) void attn_kernel(
    const __hip_bfloat16* __restrict__ proj, __hip_bfloat16* __restrict__ a) {
    __shared__ __align__(16) char ksm[64 * 128];       // K [kv][64 bf16], swizzled cols
    __shared__ __align__(16) char vsm[64 * 128];       // V^T [d][kv], swizzled cols
    __shared__ __align__(16) char psm[4 * 16 * 128];   // per-wave P [q][kv]
    int qt = blockIdx.x, head = blockIdx.y, b = blockIdx.z;
    int t = threadIdx.x;
    int lane = t & 63, w = t >> 6;
    int r = lane & 15, g = lane >> 4;
    int r7s = (r & 7) << 4;  // read-side swizzle for rows r, byte units
    int q0 = qt * 64;
    int qcol = head * 64;
    const __hip_bfloat16* pb = proj + (size_t)b * S_ * PROJN_;
    // Q B-frags in registers (col=q=w*16+r, k = kk*32 + g*8)
    bf16x8 qf[2];
#pragma unroll
    for (int kk = 0; kk < 2; ++kk)
        qf[kk] = *reinterpret_cast<const bf16x8*>(
            pb + (size_t)(q0 + w * 16 + r) * PROJN_ + qcol + kk * 32 + g * 8);
    // K staging: lane -> row (lane>>3), LDS col group lane&7 holds global group (lane&7)^(row&7)
    int krow = lane >> 3;
    int kcolswz = ((lane & 7) ^ krow) * 8;  // element offset in row
    int vdg = lane & 7;
    float m = -1e30f, l = 0.f;
    f32x4 o_acc[4] = {};
    char* pw = psm + w * 2048;
    for (int kt = 0; kt < 16; ++kt) {
        int k0 = kt * 64;
        // ---- stage K (global_load_lds, 2 instrs/wave, 8 rows each) ----
#pragma unroll
        for (int c = 0; c < 2; ++c) {
            const __hip_bfloat16* src =
                pb + (size_t)(k0 + w * 16 + c * 8 + krow) * PROJN_ + 1024 + qcol + kcolswz;
            GLOAD16(src, ksm + (w * 16 + c * 8) * 128);
        }
        // ---- stage V transposed (reg, rotated scalar writes) ----
#pragma unroll
        for (int it = 0; it < 2; ++it) {
            int kv = it * 32 + w * 8 + krow;
            bf16x8 vv = *reinterpret_cast<const bf16x8*>(
                pb + (size_t)(k0 + kv) * PROJN_ + 2048 + qcol + vdg * 8);
            int kv2 = kv * 2;
#pragma unroll
            for (int i = 0; i < 8; ++i) {
                int j = (i + vdg) & 7;
                int d = vdg * 8 + j;
                *reinterpret_cast<short*>(vsm + d * 128 + (kv2 ^ ((d & 7) << 4))) = vv[j];
            }
        }
        __syncthreads();
        // ---- QK^T -> S^T tile [64 kv][16 q] ----
        f32x4 st[4] = {};
#pragma unroll
        for (int j = 0; j < 4; ++j) {
#pragma unroll
            for (int kk = 0; kk < 2; ++kk) {
                bf16x8 kf = *reinterpret_cast<const bf16x8*>(
                    ksm + (j * 16 + r) * 128 + ((((kk * 4 + g) << 4) ^ r7s)));
                st[j] = __builtin_amdgcn_mfma_f32_16x16x32_bf16(kf, qf[kk], st[j], 0, 0, 0);
            }
        }
        // ---- online softmax: lane owns q = w*16 + r, kv = j*16 + g*4 + rr ----
        float tmax = -1e30f;
#pragma unroll
        for (int j = 0; j < 4; ++j)
#pragma unroll
            for (int rr = 0; rr < 4; ++rr) {
                st[j][rr] *= 0.125f;
                tmax = fmaxf(tmax, st[j][rr]);
            }
        tmax = fmaxf(tmax, __shfl_xor(tmax, 16, 64));
        tmax = fmaxf(tmax, __shfl_xor(tmax, 32, 64));
        float mnew = fmaxf(m, tmax);
        float rsum = 0.f;
#pragma unroll
        for (int j = 0; j < 4; ++j)
#pragma unroll
            for (int rr = 0; rr < 4; ++rr) {
                float p = __expf(st[j][rr] - mnew);
                st[j][rr] = p;
                rsum += p;
            }
        rsum += __shfl_xor(rsum, 16, 64);
        rsum += __shfl_xor(rsum, 32, 64);
        float alpha = __expf(m - mnew);
        l = l * alpha + rsum;
        m = mnew;
        // ---- write P [q=r][kv] bf16 swizzled (per-wave tile) ----
#pragma unroll
        for (int j = 0; j < 4; ++j)
#pragma unroll
            for (int rr = 0; rr < 4; ++rr) {
                int kv2 = j * 32 + g * 8 + rr * 2;
                *reinterpret_cast<short*>(pw + r * 128 + (kv2 ^ r7s)) = f2b(st[j][rr]);
            }
        asm volatile("s_waitcnt lgkmcnt(0)" ::: "memory");
        __builtin_amdgcn_sched_barrier(0);
        // ---- rescale o_acc (alpha for row q' = g*4+rr lives in lane q') ----
        float ar[4];
#pragma unroll
        for (int rr = 0; rr < 4; ++rr) ar[rr] = __shfl(alpha, g * 4 + rr, 64);
#pragma unroll
        for (int dt = 0; dt < 4; ++dt)
#pragma unroll
            for (int rr = 0; rr < 4; ++rr) o_acc[dt][rr] *= ar[rr];
        // ---- PV: O[q][d] += P[q][kv] V^T[d][kv] ----
#pragma unroll
        for (int kk = 0; kk < 2; ++kk) {
            bf16x8 pf = *reinterpret_cast<const bf16x8*>(
                pw + r * 128 + ((((kk * 4 + g) << 4) ^ r7s)));
#pragma unroll
            for (int dt = 0; dt < 4; ++dt) {
                bf16x8 vf = *reinterpret_cast<const bf16x8*>(
                    vsm + (dt * 16 + r) * 128 + ((((kk * 4 + g) << 4) ^ r7s)));
                o_acc[dt] = __builtin_amdgcn_mfma_f32_16x16x32_bf16(pf, vf, o_acc[dt], 0, 0, 0);
            }
        }
        __syncthreads();
    }
    float linv = 1.f / l;
    float lr[4];
#pragma unroll
    for (int rr = 0; rr < 4; ++rr) lr[rr] = __shfl(linv, g * 4 + rr, 64);
    short* ap = reinterpret_cast<short*>(a);
#pragma unroll
    for (int dt = 0; dt < 4; ++dt)
#pragma unroll
        for (int rr = 0; rr < 4; ++rr) {
            size_t o = ((size_t)b * S_ + q0 + w * 16 + g * 4 + rr) * (size_t)(H_ * DH_) +
                       qcol + dt * 16 + r;
            ap[o] = f2b(o_acc[dt][rr] * lr[rr]);
        }
}

// ---------------- ffg = bf16(ff * gelu_tanh(gate)) ----------------------------
__global__ void ffg_kernel(const __hip_bfloat16* __restrict__ proj,
                           __hip_bfloat16* __restrict__ ffg) {
    size_t idx = (size_t)blockIdx.x * 256 + threadIdx.x;  // over BS_*FF_/8
    int row = (int)(idx >> 9);
    int j8 = (int)(idx & 511) * 8;
    const __hip_bfloat16* pr = proj + (size_t)row * PROJN_;
    bf16x8 fv = *reinterpret_cast<const bf16x8*>(pr + 3072 + j8);
    bf16x8 gv = *reinterpret_cast<const bf16x8*>(pr + 7168 + j8);
    bf16x8 o;
#pragma unroll
    for (int d = 0; d < 8; ++d) o[d] = f2b(b2f(fv[d]) * gelu_tanh(b2f(gv[d])));
    *reinterpret_cast<bf16x8*>(reinterpret_cast<short*>(ffg) + (size_t)row * FF_ + j8) = o;
}

extern "C" void kernel_launch(void* const* d_in, const int* in_sizes, int n_in,
                              void* d_out, int out_size, void* d_ws, size_t ws_size,
                              hipStream_t stream) {
    const float* inputs = (const float*)d_in[0];
    const float* time = (const float*)d_in[1];
    const float* in_W = (const float*)d_in[2];
    const float* in_b = (const float*)d_in[3];
    const float* out_W = (const float*)d_in[4];
    const float* out_b = (const float*)d_in[5];
    const float* t_W1 = (const float*)d_in[6];
    const float* t_b1 = (const float*)d_in[7];
    const float* t_W2 = (const float*)d_in[8];
    const float* t_b2 = (const float*)d_in[9];
    const float* ln_scale = (const float*)d_in[10];
    const float* ln_bias = (const float*)d_in[11];
    const float* proj_W = (const float*)d_in[12];
    const float* attn_W = (const float*)d_in[13];
    const float* ff_W = (const float*)d_in[14];
    float* out = (float*)d_out;

    float* ws = (float*)d_ws;
    size_t off = 0;
    float* temb0 = ws + off; off += 8 * 1024;
    float* tact = ws + off;  off += 8 * 4096;
    float* temb = ws + off;  off += 8 * 1024;
    float* pos = ws + off;   off += (size_t)S_ * D_;
    float* h = ws + off;     off += (size_t)BS_ * D_;
    __hip_bfloat16* u = (__hip_bfloat16*)(ws + off);      off += (size_t)BS_ * D_ / 2;
    __hip_bfloat16* a = (__hip_bfloat16*)(ws + off);      off += (size_t)BS_ * D_ / 2;
    __hip_bfloat16* ffg = (__hip_bfloat16*)(ws + off);    off += (size_t)BS_ * FF_ / 2;
    __hip_bfloat16* proj = (__hip_bfloat16*)(ws + off);   off += (size_t)BS_ * PROJN_ / 2;
    __hip_bfloat16* hb = (__hip_bfloat16*)(ws + off);     off += (size_t)BS_ * D_ / 2;
    __hip_bfloat16* inbf = (__hip_bfloat16*)(ws + off);   off += (size_t)BS_ * (2 * E_) / 2;
    __hip_bfloat16* in_Wt = (__hip_bfloat16*)(ws + off);  off += (size_t)(2 * E_) * D_ / 2;
    __hip_bfloat16* out_Wt = (__hip_bfloat16*)(ws + off); off += (size_t)D_ * E_ / 2;
    __hip_bfloat16* Wpt = (__hip_bfloat16*)(ws + off);    off += (size_t)D_ * PROJN_ / 2;
    __hip_bfloat16* Wat = (__hip_bfloat16*)(ws + off);    off += (size_t)D_ * D_ / 2;
    __hip_bfloat16* Wft = (__hip_bfloat16*)(ws + off);    off += (size_t)FF_ * D_ / 2;

    dim3 blk(256);

    temb0_kernel<<<B_, 512, 0, stream>>>(time, temb0);
    tmlp_kernel<<<TDIM_ / 64, blk, 0, stream>>>(temb0, t_W1, t_b1, tact, D_, TDIM_);
    tmlp_kernel<<<D_ / 64, blk, 0, stream>>>(tact, t_W2, t_b2, temb, TDIM_, D_);
    pos_kernel<<<S_, 512, 0, stream>>>(pos);
    f2b4_kernel<<<(BS_ * 2 * E_) / 1024, blk, 0, stream>>>(inputs, inbf);
    convT_kernel<<<dim3(D_ / 32, (2 * E_) / 32), blk, 0, stream>>>(in_W, in_Wt, 2 * E_, D_);
    convT_kernel<<<dim3(E_ / 32, D_ / 32), blk, 0, stream>>>(out_W, out_Wt, D_, E_);
    mfma_gemm<0, 1><<<dim3(D_ / 128, BS_ / 128), blk, 0, stream>>>(
        inbf, in_Wt, in_b, h, nullptr, BS_, D_, 2 * E_);
    addpe_kernel<<<(BS_ * D_) / 256, blk, 0, stream>>>(h, pos, temb);

    for (int l = 0; l < L_; ++l) {
        const float* Wp = proj_W + (size_t)l * D_ * PROJN_;
        const float* Wa = attn_W + (size_t)l * (H_ * DH_) * D_;
        const float* Wf = ff_W + (size_t)l * FF_ * D_;
        convT_kernel<<<dim3(PROJN_ / 32, D_ / 32), blk, 0, stream>>>(Wp, Wpt, D_, PROJN_);
        convT_kernel<<<dim3(D_ / 32, D_ / 32), blk, 0, stream>>>(Wa, Wat, D_, D_);
        convT_kernel<<<dim3(D_ / 32, FF_ / 32), blk, 0, stream>>>(Wf, Wft, FF_, D_);
        ln_kernel<<<BS_, blk, 0, stream>>>(h, ln_scale + l * D_, ln_bias + l * D_, u);
        mfma_gemm<1, 0><<<dim3(PROJN_ / 128, BS_ / 128), blk, 0, stream>>>(
            u, Wpt, nullptr, nullptr, proj, BS_, PROJN_, D_);
        attn_kernel<<<dim3(S_ / 64, H_, B_), blk, 0, stream>>>(proj, a);
        mfma_gemm<2, 0><<<dim3(D_ / 128, BS_ / 128), blk, 0, stream>>>(
            a, Wat, nullptr, h, nullptr, BS_, D_, H_ * DH_);
        ffg_kernel<<<(BS_ * (FF_ / 8)) / 256, blk, 0, stream>>>(proj, ffg);
        mfma_gemm<2, 0><<<dim3(D_ / 128, BS_ / 128), blk, 0, stream>>>(
            ffg, Wft, nullptr, h, nullptr, BS_, D_, FF_);
    }
    f2b4_kernel<<<(BS_ * D_) / 1024, blk, 0, stream>>>(h, hb);
    mfma_gemm<0, 1><<<dim3(E_ / 128, BS_ / 128), blk, 0, stream>>>(
        hb, out_Wt, out_b, out, nullptr, BS_, E_, D_);
}

// Round 4
// 7059.381 us; speedup vs baseline: 12.2257x; 1.1113x over previous
//
#include <hip/hip_runtime.h>
#include <hip/hip_bf16.h>
#include <math.h>

// Problem constants
static constexpr int B_ = 8, S_ = 1024, E_ = 256, D_ = 1024, H_ = 16, DH_ = 64,
                     FF_ = 4096, L_ = 12, TDIM_ = 4096;
static constexpr int BS_ = B_ * S_;                    // 8192 rows
static constexpr int PROJN_ = 3 * H_ * DH_ + 2 * FF_;  // 11264

typedef __attribute__((ext_vector_type(8))) short bf16x8;
typedef __attribute__((ext_vector_type(4))) short bf16x4;
typedef __attribute__((ext_vector_type(4))) float f32x4;

__device__ __forceinline__ float b2f(short b) {
    return __uint_as_float(((unsigned)(unsigned short)b) << 16);
}
__device__ __forceinline__ short f2b(float f) {
    __hip_bfloat16 h = __float2bfloat16(f);
    return *reinterpret_cast<short*>(&h);
}
__device__ __forceinline__ float gelu_exact(float x) {
    return 0.5f * x * (1.f + erff(x * 0.70710678118654752440f));
}
__device__ __forceinline__ float gelu_tanh(float x) {
    float x3 = x * x * x;
    return 0.5f * x * (1.f + tanhf(0.79788456080286535588f * (x + 0.044715f * x3)));
}

#define GLOAD16(g, l)                                                     \
    __builtin_amdgcn_global_load_lds(                                     \
        (const __attribute__((address_space(1))) void*)(g),               \
        (__attribute__((address_space(3))) void*)(l), 16, 0, 0)

// ---------------- time embedding base: temb0[b] = [sin(ts), cos(ts)] -----------
__global__ void temb0_kernel(const float* __restrict__ time, float* __restrict__ temb0) {
    int b = blockIdx.x;
    int i = threadIdx.x;  // 0..511
    float inv_ts = expf((float)i * (-logf(10000.f) / 511.f));  // half-1 = 511
    float ts = time[b] * inv_ts;
    temb0[b * D_ + i] = sinf(ts);
    temb0[b * D_ + 512 + i] = cosf(ts);
}

// ---------------- fixed positional embedding ----------------------------------
__global__ void pos_kernel(float* __restrict__ pos) {
    int s = blockIdx.x;
    int j = threadIdx.x;  // 0..511
    float inv_freq = expf((float)j * (-logf(10000.f) / 512.f));  // 2j/D = j/512
    float arg = (float)s * inv_freq;
    pos[s * D_ + j] = sinf(arg);
    pos[s * D_ + 512 + j] = cosf(arg);
}

// ---------------- tiny-M GEMM + exact GELU: C[8][N] = gelu(A[8][K]@B + bias) ---
// grid N/16 blocks, 256 threads: col = t&15 (16 cols), ks = t>>4 (16 K-slices).
// Deterministic in-block LDS reduction over the 16 K-slices.
__global__ void tmlp_kernel(const float* __restrict__ A, const float* __restrict__ Bw,
                            const float* __restrict__ bias, float* __restrict__ C,
                            int K, int N) {
    __shared__ float Ast[8][256];
    __shared__ float red2[16][16][9];  // [ks][col][b], padded to break banks
    int t = threadIdx.x;
    int col = t & 15, ks = t >> 4;
    int n = blockIdx.x * 16 + col;
    float acc[8];
#pragma unroll
    for (int b = 0; b < 8; ++b) acc[b] = 0.f;
    for (int c0 = 0; c0 < K; c0 += 256) {
#pragma unroll
        for (int i = 0; i < 8; ++i) {
            int idx = t + i * 256;
            Ast[idx >> 8][idx & 255] = A[(idx >> 8) * K + c0 + (idx & 255)];
        }
        __syncthreads();
#pragma unroll
        for (int i = 0; i < 16; ++i) {
            int k = ks * 16 + i;
            float w = Bw[(size_t)(c0 + k) * N + n];
#pragma unroll
            for (int b = 0; b < 8; ++b) acc[b] = fmaf(Ast[b][k], w, acc[b]);
        }
        __syncthreads();
    }
#pragma unroll
    for (int b = 0; b < 8; ++b) red2[ks][col][b] = acc[b];
    __syncthreads();
    if (t < 128) {
        int c2 = t >> 3, b = t & 7;
        float s = 0.f;
#pragma unroll
        for (int k2 = 0; k2 < 16; ++k2) s += red2[k2][c2][b];
        int nn = blockIdx.x * 16 + c2;
        C[(size_t)b * N + nn] = gelu_exact(s + bias[nn]);
    }
}

// ---------------- h += pos[s] + temb[b] ---------------------------------------
__global__ void addpe_kernel(float* __restrict__ h, const float* __restrict__ pos,
                             const float* __restrict__ temb) {
    size_t idx = (size_t)blockIdx.x * 256 + threadIdx.x;  // over BS_*D_
    int d = (int)(idx & 1023);
    int s = (int)((idx >> 10) & 1023);
    int b = (int)(idx >> 20);
    h[idx] += pos[s * D_ + d] + temb[b * D_ + d];
}

// ---------------- fp32 -> bf16 elementwise (n multiple of 1024) ---------------
__global__ void f2b4_kernel(const float* __restrict__ in, __hip_bfloat16* __restrict__ out) {
    size_t i = ((size_t)blockIdx.x * 256 + threadIdx.x) * 4;
    float4 v = *reinterpret_cast<const float4*>(in + i);
    bf16x4 o;
    o[0] = f2b(v.x); o[1] = f2b(v.y); o[2] = f2b(v.z); o[3] = f2b(v.w);
    *reinterpret_cast<bf16x4*>(reinterpret_cast<short*>(out) + i) = o;
}

// ---------------- transpose + convert: W[K][N] fp32 -> Wt[N][K] bf16 ----------
// 64x64 tile, float4 coalesced loads, bf16x4 coalesced stores. grid (N/64, K/64).
__global__ void convT_kernel(const float* __restrict__ W, __hip_bfloat16* __restrict__ Wt,
                             int K, int N) {
    __shared__ float tile[64][65];
    int t = threadIdx.x;
    int n0 = blockIdx.x * 64, k0 = blockIdx.y * 64;
#pragma unroll
    for (int i = 0; i < 4; ++i) {
        int idx = t + i * 256;  // 1024 float4 slots = 64x64
        int row = idx >> 4, c4 = (idx & 15) * 4;
        float4 v = *reinterpret_cast<const float4*>(W + (size_t)(k0 + row) * N + n0 + c4);
        tile[row][c4 + 0] = v.x; tile[row][c4 + 1] = v.y;
        tile[row][c4 + 2] = v.z; tile[row][c4 + 3] = v.w;
    }
    __syncthreads();
#pragma unroll
    for (int i = 0; i < 4; ++i) {
        int idx = t + i * 256;
        int n = idx >> 4, k4 = (idx & 15) * 4;
        bf16x4 o;
#pragma unroll
        for (int j = 0; j < 4; ++j) o[j] = f2b(tile[k4 + j][n]);
        *reinterpret_cast<bf16x4*>(reinterpret_cast<short*>(Wt) + (size_t)(n0 + n) * K + k0 + k4) = o;
    }
}

// ---------------- LayerNorm: u = bf16((h-m)*rsqrt(v+eps)*g + b) ---------------
__global__ void ln_kernel(const float* __restrict__ h, const float* __restrict__ g,
                          const float* __restrict__ bb, __hip_bfloat16* __restrict__ u) {
    int row = blockIdx.x;
    int t = threadIdx.x;  // 256 threads, 4 elems each
    const float4 v = reinterpret_cast<const float4*>(h + (size_t)row * D_)[t];
    __shared__ float red[8];
    float s = v.x + v.y + v.z + v.w;
    for (int m8 = 1; m8 < 64; m8 <<= 1) s += __shfl_xor(s, m8, 64);
    if ((t & 63) == 0) red[t >> 6] = s;
    __syncthreads();
    float mean = (red[0] + red[1] + red[2] + red[3]) * (1.f / 1024.f);
    float dx = v.x - mean, dy = v.y - mean, dz = v.z - mean, dw = v.w - mean;
    float sq = dx * dx + dy * dy + dz * dz + dw * dw;
    for (int m8 = 1; m8 < 64; m8 <<= 1) sq += __shfl_xor(sq, m8, 64);
    if ((t & 63) == 0) red[4 + (t >> 6)] = sq;
    __syncthreads();
    float var = (red[4] + red[5] + red[6] + red[7]) * (1.f / 1024.f);
    float inv = rsqrtf(var + 1e-5f);
    int c = t * 4;
    bf16x4 o;
    o[0] = f2b(dx * inv * g[c + 0] + bb[c + 0]);
    o[1] = f2b(dy * inv * g[c + 1] + bb[c + 1]);
    o[2] = f2b(dz * inv * g[c + 2] + bb[c + 2]);
    o[3] = f2b(dw * inv * g[c + 3] + bb[c + 3]);
    *reinterpret_cast<bf16x4*>(reinterpret_cast<short*>(u) + (size_t)row * D_ + c) = o;
}

// ---------------- MFMA bf16 GEMM, m97 structure -------------------------------
// C[M][N] = A[M][K] @ Bt[N][K]^T.  128x128 tile, BK=32, 256 thr (4 waves 2x2).
template <int MODE, int BIAS>
__global__ __launch_bounds__(256) void mfma_gemm(
    const __hip_bfloat16* __restrict__ A, const __hip_bfloat16* __restrict__ Bt,
    const float* __restrict__ bias, float* __restrict__ Cf,
    __hip_bfloat16* __restrict__ Cb, int M, int N, int K) {
    __shared__ __align__(16) char As[128 * 64];  // [128 rows][32 bf16]
    __shared__ __align__(16) char Bs[128 * 64];
    int t = threadIdx.x;
    int lane = t & 63, wid = t >> 6;
    int m0 = blockIdx.y * 128, n0 = blockIdx.x * 128;
    size_t rowb = (size_t)K * 2;
    int srow = wid * 32 + (lane >> 2);
    int scol = (lane & 3) * 16;
    const char* ag0 = (const char*)A + (size_t)(m0 + srow) * rowb + scol;
    const char* ag1 = (const char*)A + (size_t)(m0 + srow + 16) * rowb + scol;
    const char* bg0 = (const char*)Bt + (size_t)(n0 + srow) * rowb + scol;
    const char* bg1 = (const char*)Bt + (size_t)(n0 + srow + 16) * rowb + scol;
    int lb0 = wid * 32 * 64;
    int lb1 = lb0 + 16 * 64;
    int wr = (wid >> 1) * 64, wc = (wid & 1) * 64;
    int lr = lane & 15;
    int a_base = (wr + lr) * 64 + (lane >> 4) * 16;
    int b_base = (wc + lr) * 64 + (lane >> 4) * 16;
    f32x4 acc[4][4] = {};
    int nkt = K >> 5;
    for (int kt = 0; kt < nkt; ++kt) {
        GLOAD16(ag0, As + lb0);
        GLOAD16(ag1, As + lb1);
        GLOAD16(bg0, Bs + lb0);
        GLOAD16(bg1, Bs + lb1);
        ag0 += 64; ag1 += 64; bg0 += 64; bg1 += 64;
        __syncthreads();
        bf16x8 af[4], bf[4];
#pragma unroll
        for (int f = 0; f < 4; ++f) {
            af[f] = *reinterpret_cast<const bf16x8*>(As + a_base + f * 1024);
            bf[f] = *reinterpret_cast<const bf16x8*>(Bs + b_base + f * 1024);
        }
        __builtin_amdgcn_s_setprio(1);
#pragma unroll
        for (int i = 0; i < 4; ++i)
#pragma unroll
            for (int j = 0; j < 4; ++j)
                acc[i][j] = __builtin_amdgcn_mfma_f32_16x16x32_bf16(af[i], bf[j], acc[i][j], 0, 0, 0);
        __builtin_amdgcn_s_setprio(0);
        __syncthreads();
    }
    int crow0 = m0 + wr + (lane >> 4) * 4;
    int ccol0 = n0 + wc + lr;
#pragma unroll
    for (int i = 0; i < 4; ++i) {
#pragma unroll
        for (int j = 0; j < 4; ++j) {
            int col = ccol0 + j * 16;
            float bv = BIAS ? bias[col] : 0.f;
            f32x4 v = acc[i][j];
#pragma unroll
            for (int r = 0; r < 4; ++r) {
                size_t o = (size_t)(crow0 + i * 16 + r) * N + col;
                float val = v[r] + bv;
                if (MODE == 0) Cf[o] = val;
                else if (MODE == 1) Cb[o] = __float2bfloat16(val);
                else Cf[o] += val;
            }
        }
    }
}

// ---------------- MFMA flash attention ----------------------------------------
// grid (S/64, H, B), 256 thr = 4 waves; wave w owns q rows q0+w*16..+15.
__global__ __launch_bounds__(256, 2) void attn_kernel(
    const __hip_bfloat16* __restrict__ proj, __hip_bfloat16* __restrict__ a) {
    __shared__ __align__(16) char ksm[64 * 128];       // K [kv][64 bf16], swizzled cols
    __shared__ __align__(16) char vsm[64 * 128];       // V^T [d][kv], swizzled cols
    __shared__ __align__(16) char psm[4 * 16 * 128];   // per-wave P [q][kv]
    int qt = blockIdx.x, head = blockIdx.y, b = blockIdx.z;
    int t = threadIdx.x;
    int lane = t & 63, w = t >> 6;
    int r = lane & 15, g = lane >> 4;
    int r7s = (r & 7) << 4;  // read-side swizzle for rows r, byte units
    int q0 = qt * 64;
    int qcol = head * 64;
    const __hip_bfloat16* pb = proj + (size_t)b * S_ * PROJN_;
    bf16x8 qf[2];
#pragma unroll
    for (int kk = 0; kk < 2; ++kk)
        qf[kk] = *reinterpret_cast<const bf16x8*>(
            pb + (size_t)(q0 + w * 16 + r) * PROJN_ + qcol + kk * 32 + g * 8);
    int krow = lane >> 3;
    int kcolswz = ((lane & 7) ^ krow) * 8;  // element offset in row
    int vdg = lane & 7;
    float m = -1e30f, l = 0.f;
    f32x4 o_acc[4] = {};
    char* pw = psm + w * 2048;
    for (int kt = 0; kt < 16; ++kt) {
        int k0 = kt * 64;
#pragma unroll
        for (int c = 0; c < 2; ++c) {
            const __hip_bfloat16* src =
                pb + (size_t)(k0 + w * 16 + c * 8 + krow) * PROJN_ + 1024 + qcol + kcolswz;
            GLOAD16(src, ksm + (w * 16 + c * 8) * 128);
        }
#pragma unroll
        for (int it = 0; it < 2; ++it) {
            int kv = it * 32 + w * 8 + krow;
            bf16x8 vv = *reinterpret_cast<const bf16x8*>(
                pb + (size_t)(k0 + kv) * PROJN_ + 2048 + qcol + vdg * 8);
            int kv2 = kv * 2;
#pragma unroll
            for (int i = 0; i < 8; ++i) {
                int j = (i + vdg) & 7;
                int d = vdg * 8 + j;
                *reinterpret_cast<short*>(vsm + d * 128 + (kv2 ^ ((d & 7) << 4))) = vv[j];
            }
        }
        __syncthreads();
        // ---- QK^T -> S^T tile [64 kv][16 q] ----
        f32x4 st[4] = {};
        __builtin_amdgcn_s_setprio(1);
#pragma unroll
        for (int j = 0; j < 4; ++j) {
#pragma unroll
            for (int kk = 0; kk < 2; ++kk) {
                bf16x8 kf = *reinterpret_cast<const bf16x8*>(
                    ksm + (j * 16 + r) * 128 + ((((kk * 4 + g) << 4) ^ r7s)));
                st[j] = __builtin_amdgcn_mfma_f32_16x16x32_bf16(kf, qf[kk], st[j], 0, 0, 0);
            }
        }
        __builtin_amdgcn_s_setprio(0);
        // ---- online softmax: lane owns q = w*16 + r, kv = j*16 + g*4 + rr ----
        float tmax = -1e30f;
#pragma unroll
        for (int j = 0; j < 4; ++j)
#pragma unroll
            for (int rr = 0; rr < 4; ++rr) {
                st[j][rr] *= 0.125f;
                tmax = fmaxf(tmax, st[j][rr]);
            }
        tmax = fmaxf(tmax, __shfl_xor(tmax, 16, 64));
        tmax = fmaxf(tmax, __shfl_xor(tmax, 32, 64));
        float mnew = fmaxf(m, tmax);
        float rsum = 0.f;
#pragma unroll
        for (int j = 0; j < 4; ++j)
#pragma unroll
            for (int rr = 0; rr < 4; ++rr) {
                float p = __expf(st[j][rr] - mnew);
                st[j][rr] = p;
                rsum += p;
            }
        rsum += __shfl_xor(rsum, 16, 64);
        rsum += __shfl_xor(rsum, 32, 64);
        float alpha = __expf(m - mnew);
        l = l * alpha + rsum;
        m = mnew;
#pragma unroll
        for (int j = 0; j < 4; ++j)
#pragma unroll
            for (int rr = 0; rr < 4; ++rr) {
                int kv2 = j * 32 + g * 8 + rr * 2;
                *reinterpret_cast<short*>(pw + r * 128 + (kv2 ^ r7s)) = f2b(st[j][rr]);
            }
        asm volatile("s_waitcnt lgkmcnt(0)" ::: "memory");
        __builtin_amdgcn_sched_barrier(0);
        float ar[4];
#pragma unroll
        for (int rr = 0; rr < 4; ++rr) ar[rr] = __shfl(alpha, g * 4 + rr, 64);
#pragma unroll
        for (int dt = 0; dt < 4; ++dt)
#pragma unroll
            for (int rr = 0; rr < 4; ++rr) o_acc[dt][rr] *= ar[rr];
        // ---- PV: O[q][d] += P[q][kv] V^T[d][kv] ----
        __builtin_amdgcn_s_setprio(1);
#pragma unroll
        for (int kk = 0; kk < 2; ++kk) {
            bf16x8 pf = *reinterpret_cast<const bf16x8*>(
                pw + r * 128 + ((((kk * 4 + g) << 4) ^ r7s)));
#pragma unroll
            for (int dt = 0; dt < 4; ++dt) {
                bf16x8 vf = *reinterpret_cast<const bf16x8*>(
                    vsm + (dt * 16 + r) * 128 + ((((kk * 4 + g) << 4) ^ r7s)));
                o_acc[dt] = __builtin_amdgcn_mfma_f32_16x16x32_bf16(pf, vf, o_acc[dt], 0, 0, 0);
            }
        }
        __builtin_amdgcn_s_setprio(0);
        __syncthreads();
    }
    float linv = 1.f / l;
    float lr[4];
#pragma unroll
    for (int rr = 0; rr < 4; ++rr) lr[rr] = __shfl(linv, g * 4 + rr, 64);
    short* ap = reinterpret_cast<short*>(a);
#pragma unroll
    for (int dt = 0; dt < 4; ++dt)
#pragma unroll
        for (int rr = 0; rr < 4; ++rr) {
            size_t o = ((size_t)b * S_ + q0 + w * 16 + g * 4 + rr) * (size_t)(H_ * DH_) +
                       qcol + dt * 16 + r;
            ap[o] = f2b(o_acc[dt][rr] * lr[rr]);
        }
}

// ---------------- ffg = bf16(ff * gelu_tanh(gate)) ----------------------------
__global__ void ffg_kernel(const __hip_bfloat16* __restrict__ proj,
                           __hip_bfloat16* __restrict__ ffg) {
    size_t idx = (size_t)blockIdx.x * 256 + threadIdx.x;  // over BS_*FF_/8
    int row = (int)(idx >> 9);
    int j8 = (int)(idx & 511) * 8;
    const __hip_bfloat16* pr = proj + (size_t)row * PROJN_;
    bf16x8 fv = *reinterpret_cast<const bf16x8*>(pr + 3072 + j8);
    bf16x8 gv = *reinterpret_cast<const bf16x8*>(pr + 7168 + j8);
    bf16x8 o;
#pragma unroll
    for (int d = 0; d < 8; ++d) o[d] = f2b(b2f(fv[d]) * gelu_tanh(b2f(gv[d])));
    *reinterpret_cast<bf16x8*>(reinterpret_cast<short*>(ffg) + (size_t)row * FF_ + j8) = o;
}

extern "C" void kernel_launch(void* const* d_in, const int* in_sizes, int n_in,
                              void* d_out, int out_size, void* d_ws, size_t ws_size,
                              hipStream_t stream) {
    const float* inputs = (const float*)d_in[0];
    const float* time = (const float*)d_in[1];
    const float* in_W = (const float*)d_in[2];
    const float* in_b = (const float*)d_in[3];
    const float* out_W = (const float*)d_in[4];
    const float* out_b = (const float*)d_in[5];
    const float* t_W1 = (const float*)d_in[6];
    const float* t_b1 = (const float*)d_in[7];
    const float* t_W2 = (const float*)d_in[8];
    const float* t_b2 = (const float*)d_in[9];
    const float* ln_scale = (const float*)d_in[10];
    const float* ln_bias = (const float*)d_in[11];
    const float* proj_W = (const float*)d_in[12];
    const float* attn_W = (const float*)d_in[13];
    const float* ff_W = (const float*)d_in[14];
    float* out = (float*)d_out;

    float* ws = (float*)d_ws;
    size_t off = 0;
    float* temb0 = ws + off; off += 8 * 1024;
    float* tact = ws + off;  off += 8 * 4096;
    float* temb = ws + off;  off += 8 * 1024;
    float* pos = ws + off;   off += (size_t)S_ * D_;
    float* h = ws + off;     off += (size_t)BS_ * D_;
    __hip_bfloat16* u = (__hip_bfloat16*)(ws + off);      off += (size_t)BS_ * D_ / 2;
    __hip_bfloat16* a = (__hip_bfloat16*)(ws + off);      off += (size_t)BS_ * D_ / 2;
    __hip_bfloat16* ffg = (__hip_bfloat16*)(ws + off);    off += (size_t)BS_ * FF_ / 2;
    __hip_bfloat16* proj = (__hip_bfloat16*)(ws + off);   off += (size_t)BS_ * PROJN_ / 2;
    __hip_bfloat16* hb = (__hip_bfloat16*)(ws + off);     off += (size_t)BS_ * D_ / 2;
    __hip_bfloat16* inbf = (__hip_bfloat16*)(ws + off);   off += (size_t)BS_ * (2 * E_) / 2;
    __hip_bfloat16* in_Wt = (__hip_bfloat16*)(ws + off);  off += (size_t)(2 * E_) * D_ / 2;
    __hip_bfloat16* out_Wt = (__hip_bfloat16*)(ws + off); off += (size_t)D_ * E_ / 2;
    __hip_bfloat16* Wpt = (__hip_bfloat16*)(ws + off);    off += (size_t)D_ * PROJN_ / 2;
    __hip_bfloat16* Wat = (__hip_bfloat16*)(ws + off);    off += (size_t)D_ * D_ / 2;
    __hip_bfloat16* Wft = (__hip_bfloat16*)(ws + off);    off += (size_t)FF_ * D_ / 2;

    dim3 blk(256);

    temb0_kernel<<<B_, 512, 0, stream>>>(time, temb0);
    tmlp_kernel<<<TDIM_ / 16, blk, 0, stream>>>(temb0, t_W1, t_b1, tact, D_, TDIM_);
    tmlp_kernel<<<D_ / 16, blk, 0, stream>>>(tact, t_W2, t_b2, temb, TDIM_, D_);
    pos_kernel<<<S_, 512, 0, stream>>>(pos);
    f2b4_kernel<<<(BS_ * 2 * E_) / 1024, blk, 0, stream>>>(inputs, inbf);
    convT_kernel<<<dim3(D_ / 64, (2 * E_) / 64), blk, 0, stream>>>(in_W, in_Wt, 2 * E_, D_);
    convT_kernel<<<dim3(E_ / 64, D_ / 64), blk, 0, stream>>>(out_W, out_Wt, D_, E_);
    mfma_gemm<0, 1><<<dim3(D_ / 128, BS_ / 128), blk, 0, stream>>>(
        inbf, in_Wt, in_b, h, nullptr, BS_, D_, 2 * E_);
    addpe_kernel<<<(BS_ * D_) / 256, blk, 0, stream>>>(h, pos, temb);

    for (int l = 0; l < L_; ++l) {
        const float* Wp = proj_W + (size_t)l * D_ * PROJN_;
        const float* Wa = attn_W + (size_t)l * (H_ * DH_) * D_;
        const float* Wf = ff_W + (size_t)l * FF_ * D_;
        convT_kernel<<<dim3(PROJN_ / 64, D_ / 64), blk, 0, stream>>>(Wp, Wpt, D_, PROJN_);
        convT_kernel<<<dim3(D_ / 64, D_ / 64), blk, 0, stream>>>(Wa, Wat, D_, D_);
        convT_kernel<<<dim3(D_ / 64, FF_ / 64), blk, 0, stream>>>(Wf, Wft, FF_, D_);
        ln_kernel<<<BS_, blk, 0, stream>>>(h, ln_scale + l * D_, ln_bias + l * D_, u);
        mfma_gemm<1, 0><<<dim3(PROJN_ / 128, BS_ / 128), blk, 0, stream>>>(
            u, Wpt, nullptr, nullptr, proj, BS_, PROJN_, D_);
        attn_kernel<<<dim3(S_ / 64, H_, B_), blk, 0, stream>>>(proj, a);
        mfma_gemm<2, 0><<<dim3(D_ / 128, BS_ / 128), blk, 0, stream>>>(
            a, Wat, nullptr, h, nullptr, BS_, D_, H_ * DH_);
        ffg_kernel<<<(BS_ * (FF_ / 8)) / 256, blk, 0, stream>>>(proj, ffg);
        mfma_gemm<2, 0><<<dim3(D_ / 128, BS_ / 128), blk, 0, stream>>>(
            ffg, Wft, nullptr, h, nullptr, BS_, D_, FF_);
    }
    f2b4_kernel<<<(BS_ * D_) / 1024, blk, 0, stream>>>(h, hb);
    mfma_gemm<0, 1><<<dim3(E_ / 128, BS_ / 128), blk, 0, stream>>>(
        hb, out_Wt, out_b, out, nullptr, BS_, E_, D_);
}

// Round 5
// 6691.103 us; speedup vs baseline: 12.8986x; 1.0550x over previous
//
#include <hip/hip_runtime.h>
#include <hip/hip_bf16.h>
#include <math.h>

// Problem constants
static constexpr int B_ = 8, S_ = 1024, E_ = 256, D_ = 1024, H_ = 16, DH_ = 64,
                     FF_ = 4096, L_ = 12, TDIM_ = 4096;
static constexpr int BS_ = B_ * S_;                    // 8192 rows
static constexpr int PROJN_ = 3 * H_ * DH_ + 2 * FF_;  // 11264

typedef __attribute__((ext_vector_type(8))) short bf16x8;
typedef __attribute__((ext_vector_type(4))) short bf16x4;
typedef __attribute__((ext_vector_type(4))) float f32x4;

__device__ __forceinline__ float b2f(short b) {
    return __uint_as_float(((unsigned)(unsigned short)b) << 16);
}
__device__ __forceinline__ short f2b(float f) {
    __hip_bfloat16 h = __float2bfloat16(f);
    return *reinterpret_cast<short*>(&h);
}
__device__ __forceinline__ float gelu_exact(float x) {
    return 0.5f * x * (1.f + erff(x * 0.70710678118654752440f));
}
__device__ __forceinline__ float gelu_tanh(float x) {
    float x3 = x * x * x;
    return 0.5f * x * (1.f + tanhf(0.79788456080286535588f * (x + 0.044715f * x3)));
}

#define GLOAD16(g, l)                                                     \
    __builtin_amdgcn_global_load_lds(                                     \
        (const __attribute__((address_space(1))) void*)(g),               \
        (__attribute__((address_space(3))) void*)(l), 16, 0, 0)

// ---------------- time embedding base: temb0[b] = [sin(ts), cos(ts)] -----------
__global__ void temb0_kernel(const float* __restrict__ time, float* __restrict__ temb0) {
    int b = blockIdx.x;
    int i = threadIdx.x;  // 0..511
    float inv_ts = expf((float)i * (-logf(10000.f) / 511.f));  // half-1 = 511
    float ts = time[b] * inv_ts;
    temb0[b * D_ + i] = sinf(ts);
    temb0[b * D_ + 512 + i] = cosf(ts);
}

// ---------------- fixed positional embedding ----------------------------------
__global__ void pos_kernel(float* __restrict__ pos) {
    int s = blockIdx.x;
    int j = threadIdx.x;  // 0..511
    float inv_freq = expf((float)j * (-logf(10000.f) / 512.f));  // 2j/D = j/512
    float arg = (float)s * inv_freq;
    pos[s * D_ + j] = sinf(arg);
    pos[s * D_ + 512 + j] = cosf(arg);
}

// ---------------- tiny-M GEMM + exact GELU: C[8][N] = gelu(A[8][K]@B + bias) ---
// grid N/16 blocks, 256 threads: col = t&15 (16 cols), ks = t>>4 (16 K-slices).
__global__ void tmlp_kernel(const float* __restrict__ A, const float* __restrict__ Bw,
                            const float* __restrict__ bias, float* __restrict__ C,
                            int K, int N) {
    __shared__ float Ast[8][256];
    __shared__ float red2[16][16][9];  // [ks][col][b], padded to break banks
    int t = threadIdx.x;
    int col = t & 15, ks = t >> 4;
    int n = blockIdx.x * 16 + col;
    float acc[8];
#pragma unroll
    for (int b = 0; b < 8; ++b) acc[b] = 0.f;
    for (int c0 = 0; c0 < K; c0 += 256) {
#pragma unroll
        for (int i = 0; i < 8; ++i) {
            int idx = t + i * 256;
            Ast[idx >> 8][idx & 255] = A[(idx >> 8) * K + c0 + (idx & 255)];
        }
        __syncthreads();
#pragma unroll
        for (int i = 0; i < 16; ++i) {
            int k = ks * 16 + i;
            float w = Bw[(size_t)(c0 + k) * N + n];
#pragma unroll
            for (int b = 0; b < 8; ++b) acc[b] = fmaf(Ast[b][k], w, acc[b]);
        }
        __syncthreads();
    }
#pragma unroll
    for (int b = 0; b < 8; ++b) red2[ks][col][b] = acc[b];
    __syncthreads();
    if (t < 128) {
        int c2 = t >> 3, b = t & 7;
        float s = 0.f;
#pragma unroll
        for (int k2 = 0; k2 < 16; ++k2) s += red2[k2][c2][b];
        int nn = blockIdx.x * 16 + c2;
        C[(size_t)b * N + nn] = gelu_exact(s + bias[nn]);
    }
}

// ---------------- h += pos[s] + temb[b] ---------------------------------------
__global__ void addpe_kernel(float* __restrict__ h, const float* __restrict__ pos,
                             const float* __restrict__ temb) {
    size_t idx = (size_t)blockIdx.x * 256 + threadIdx.x;  // over BS_*D_
    int d = (int)(idx & 1023);
    int s = (int)((idx >> 10) & 1023);
    int b = (int)(idx >> 20);
    h[idx] += pos[s * D_ + d] + temb[b * D_ + d];
}

// ---------------- fp32 -> bf16 elementwise (n multiple of 1024) ---------------
__global__ void f2b4_kernel(const float* __restrict__ in, __hip_bfloat16* __restrict__ out) {
    size_t i = ((size_t)blockIdx.x * 256 + threadIdx.x) * 4;
    float4 v = *reinterpret_cast<const float4*>(in + i);
    bf16x4 o;
    o[0] = f2b(v.x); o[1] = f2b(v.y); o[2] = f2b(v.z); o[3] = f2b(v.w);
    *reinterpret_cast<bf16x4*>(reinterpret_cast<short*>(out) + i) = o;
}

// ---------------- transpose + convert: W[K][N] fp32 -> Wt[N][K] bf16 ----------
// 64x64 tile, float4 coalesced loads, bf16x4 coalesced stores. grid (N/64, K/64).
__global__ void convT_kernel(const float* __restrict__ W, __hip_bfloat16* __restrict__ Wt,
                             int K, int N) {
    __shared__ float tile[64][65];
    int t = threadIdx.x;
    int n0 = blockIdx.x * 64, k0 = blockIdx.y * 64;
#pragma unroll
    for (int i = 0; i < 4; ++i) {
        int idx = t + i * 256;  // 1024 float4 slots = 64x64
        int row = idx >> 4, c4 = (idx & 15) * 4;
        float4 v = *reinterpret_cast<const float4*>(W + (size_t)(k0 + row) * N + n0 + c4);
        tile[row][c4 + 0] = v.x; tile[row][c4 + 1] = v.y;
        tile[row][c4 + 2] = v.z; tile[row][c4 + 3] = v.w;
    }
    __syncthreads();
#pragma unroll
    for (int i = 0; i < 4; ++i) {
        int idx = t + i * 256;
        int n = idx >> 4, k4 = (idx & 15) * 4;
        bf16x4 o;
#pragma unroll
        for (int j = 0; j < 4; ++j) o[j] = f2b(tile[k4 + j][n]);
        *reinterpret_cast<bf16x4*>(reinterpret_cast<short*>(Wt) + (size_t)(n0 + n) * K + k0 + k4) = o;
    }
}

// ---------------- LayerNorm: u = bf16((h-m)*rsqrt(v+eps)*g + b) ---------------
__global__ void ln_kernel(const float* __restrict__ h, const float* __restrict__ g,
                          const float* __restrict__ bb, __hip_bfloat16* __restrict__ u) {
    int row = blockIdx.x;
    int t = threadIdx.x;  // 256 threads, 4 elems each
    const float4 v = reinterpret_cast<const float4*>(h + (size_t)row * D_)[t];
    __shared__ float red[8];
    float s = v.x + v.y + v.z + v.w;
    for (int m8 = 1; m8 < 64; m8 <<= 1) s += __shfl_xor(s, m8, 64);
    if ((t & 63) == 0) red[t >> 6] = s;
    __syncthreads();
    float mean = (red[0] + red[1] + red[2] + red[3]) * (1.f / 1024.f);
    float dx = v.x - mean, dy = v.y - mean, dz = v.z - mean, dw = v.w - mean;
    float sq = dx * dx + dy * dy + dz * dz + dw * dw;
    for (int m8 = 1; m8 < 64; m8 <<= 1) sq += __shfl_xor(sq, m8, 64);
    if ((t & 63) == 0) red[4 + (t >> 6)] = sq;
    __syncthreads();
    float var = (red[4] + red[5] + red[6] + red[7]) * (1.f / 1024.f);
    float inv = rsqrtf(var + 1e-5f);
    int c = t * 4;
    bf16x4 o;
    o[0] = f2b(dx * inv * g[c + 0] + bb[c + 0]);
    o[1] = f2b(dy * inv * g[c + 1] + bb[c + 1]);
    o[2] = f2b(dz * inv * g[c + 2] + bb[c + 2]);
    o[3] = f2b(dw * inv * g[c + 3] + bb[c + 3]);
    *reinterpret_cast<bf16x4*>(reinterpret_cast<short*>(u) + (size_t)row * D_ + c) = o;
}

// ---------------- MFMA bf16 GEMM, m97 structure (kept for small-N GEMMs) ------
// C[M][N] = A[M][K] @ Bt[N][K]^T.  128x128 tile, BK=32, 256 thr (4 waves 2x2).
template <int MODE, int BIAS>
__global__ __launch_bounds__(256) void mfma_gemm(
    const __hip_bfloat16* __restrict__ A, const __hip_bfloat16* __restrict__ Bt,
    const float* __restrict__ bias, float* __restrict__ Cf,
    __hip_bfloat16* __restrict__ Cb, int M, int N, int K) {
    __shared__ __align__(16) char As[128 * 64];  // [128 rows][32 bf16]
    __shared__ __align__(16) char Bs[128 * 64];
    int t = threadIdx.x;
    int lane = t & 63, wid = t >> 6;
    int m0 = blockIdx.y * 128, n0 = blockIdx.x * 128;
    size_t rowb = (size_t)K * 2;
    int srow = wid * 32 + (lane >> 2);
    int scol = (lane & 3) * 16;
    const char* ag0 = (const char*)A + (size_t)(m0 + srow) * rowb + scol;
    const char* ag1 = (const char*)A + (size_t)(m0 + srow + 16) * rowb + scol;
    const char* bg0 = (const char*)Bt + (size_t)(n0 + srow) * rowb + scol;
    const char* bg1 = (const char*)Bt + (size_t)(n0 + srow + 16) * rowb + scol;
    int lb0 = wid * 32 * 64;
    int lb1 = lb0 + 16 * 64;
    int wr = (wid >> 1) * 64, wc = (wid & 1) * 64;
    int lr = lane & 15;
    int a_base = (wr + lr) * 64 + (lane >> 4) * 16;
    int b_base = (wc + lr) * 64 + (lane >> 4) * 16;
    f32x4 acc[4][4] = {};
    int nkt = K >> 5;
    for (int kt = 0; kt < nkt; ++kt) {
        GLOAD16(ag0, As + lb0);
        GLOAD16(ag1, As + lb1);
        GLOAD16(bg0, Bs + lb0);
        GLOAD16(bg1, Bs + lb1);
        ag0 += 64; ag1 += 64; bg0 += 64; bg1 += 64;
        __syncthreads();
        bf16x8 af[4], bf[4];
#pragma unroll
        for (int f = 0; f < 4; ++f) {
            af[f] = *reinterpret_cast<const bf16x8*>(As + a_base + f * 1024);
            bf[f] = *reinterpret_cast<const bf16x8*>(Bs + b_base + f * 1024);
        }
        __builtin_amdgcn_s_setprio(1);
#pragma unroll
        for (int i = 0; i < 4; ++i)
#pragma unroll
            for (int j = 0; j < 4; ++j)
                acc[i][j] = __builtin_amdgcn_mfma_f32_16x16x32_bf16(af[i], bf[j], acc[i][j], 0, 0, 0);
        __builtin_amdgcn_s_setprio(0);
        __syncthreads();
    }
    int crow0 = m0 + wr + (lane >> 4) * 4;
    int ccol0 = n0 + wc + lr;
#pragma unroll
    for (int i = 0; i < 4; ++i) {
#pragma unroll
        for (int j = 0; j < 4; ++j) {
            int col = ccol0 + j * 16;
            float bv = BIAS ? bias[col] : 0.f;
            f32x4 v = acc[i][j];
#pragma unroll
            for (int r = 0; r < 4; ++r) {
                size_t o = (size_t)(crow0 + i * 16 + r) * N + col;
                float val = v[r] + bv;
                if (MODE == 0) Cf[o] = val;
                else if (MODE == 1) Cb[o] = __float2bfloat16(val);
                else Cf[o] += val;
            }
        }
    }
}

// ---------------- 8-phase 256x256 MFMA GEMM (T2+T3+T4+T5), for proj -----------
// C[M][N] = A[M][K] @ Bt[N][K]^T. BK=64 (2 kk-panels of 32), 512 thr = 8 waves
// (2Mx4N), per-wave output 128x64 spread as rows m*32+wr*16, cols n*64+wc*16.
// LDS 128 KiB: [mat][parity][kk][256 rows][64B], st_16x32 swizzle (bit5^=bit9
// within each 1024B subtile) applied on BOTH sides: pre-swizzled global source
// lane (lane&3)^((lane>>5)<<1) for global_load_lds, and swizzled ds_read group
// g^((lr>>3)<<1). Per K-tile 4 phases; staging A1(kt+1)/A0(kt+2)/B0(kt+2)/
// B1(kt+2) so each slot is overwritten >=1 barrier after its last ds_read;
// vmcnt(6) once per K-tile (counted, never 0 until the NT-2 tail).
template <int MODE>
__global__ __launch_bounds__(512, 2) void gemm256(
    const __hip_bfloat16* __restrict__ A, const __hip_bfloat16* __restrict__ Bt,
    float* __restrict__ Cf, __hip_bfloat16* __restrict__ Cb, int M, int N, int K) {
    __shared__ __align__(16) char lds[131072];
    const int t = threadIdx.x;
    const int lane = t & 63, wid = t >> 6;
    const int lr = lane & 15, g = lane >> 4;
    const int wr = wid >> 2, wc = wid & 3;
    const int m0 = blockIdx.y * 256, n0 = blockIdx.x * 256;
    const size_t rowb = (size_t)K * 2;
    const int NT = K >> 6;
    const int srow = lane >> 2;
    const int scol = ((lane & 3) ^ (((lane >> 5) & 1) << 1)) * 16;  // src-side swizzle
    const int ga = (g ^ (((lr >> 3) & 1) << 1)) * 16;               // read-side swizzle
    const int arow = wr * 16 + lr;
    const int brow = wc * 16 + lr;
    const char* Ab = (const char*)A;
    const char* Bb = (const char*)Bt;

    auto stage = [&](int mat, int kt, int hh) {
        if (kt >= NT) return;
        int rbase = (mat ? n0 : m0) + hh * 128 + wid * 16 + srow;
        const char* src = (mat ? Bb : Ab) + (size_t)rbase * rowb + (size_t)kt * 128 + scol;
        char* dst = lds + mat * 65536 + (kt & 1) * 32768 + (hh * 128 + wid * 16) * 64;
        GLOAD16(src, dst);            // kk=0 panel
        GLOAD16(src + 64, dst + 16384);  // kk=1 panel
    };

    f32x4 acc[8][4] = {};
    bf16x8 af[4][2], bfr[4][2];

    // prologue: kt0 fully + kt1 {A0,B0,B1}; wait own kt0 loads (8 oldest)
    stage(0, 0, 0); stage(0, 0, 1); stage(1, 0, 0); stage(1, 0, 1);
    stage(0, 1, 0); stage(1, 1, 0); stage(1, 1, 1);
    asm volatile("s_waitcnt vmcnt(6)" ::: "memory");
    __builtin_amdgcn_s_barrier();

    for (int kt = 0; kt < NT; ++kt) {
        const int p = kt & 1;
        const char* la = lds + p * 32768;
        const char* lb = lds + 65536 + p * 32768;
        // ---- phase 1: read A(mq0)+B(n0,1); stage A1(kt+1); MFMA (mq0,nq0) ----
#pragma unroll
        for (int mi = 0; mi < 4; ++mi)
#pragma unroll
            for (int kk = 0; kk < 2; ++kk)
                af[mi][kk] = *reinterpret_cast<const bf16x8*>(
                    la + kk * 16384 + (mi * 32 + arow) * 64 + ga);
#pragma unroll
        for (int n = 0; n < 2; ++n)
#pragma unroll
            for (int kk = 0; kk < 2; ++kk)
                bfr[n][kk] = *reinterpret_cast<const bf16x8*>(
                    lb + kk * 16384 + (n * 64 + brow) * 64 + ga);
        stage(0, kt + 1, 1);
        __builtin_amdgcn_s_barrier();
        asm volatile("s_waitcnt lgkmcnt(0)" ::: "memory");
        __builtin_amdgcn_sched_barrier(0);
        __builtin_amdgcn_s_setprio(1);
#pragma unroll
        for (int mi = 0; mi < 4; ++mi)
#pragma unroll
            for (int n = 0; n < 2; ++n)
#pragma unroll
                for (int kk = 0; kk < 2; ++kk)
                    acc[mi][n] = __builtin_amdgcn_mfma_f32_16x16x32_bf16(
                        af[mi][kk], bfr[n][kk], acc[mi][n], 0, 0, 0);
        __builtin_amdgcn_s_setprio(0);
        __builtin_amdgcn_s_barrier();
        // ---- phase 2: read B(n2,3); stage A0(kt+2); MFMA (mq0,nq1) ----
#pragma unroll
        for (int n = 2; n < 4; ++n)
#pragma unroll
            for (int kk = 0; kk < 2; ++kk)
                bfr[n][kk] = *reinterpret_cast<const bf16x8*>(
                    lb + kk * 16384 + (n * 64 + brow) * 64 + ga);
        stage(0, kt + 2, 0);
        __builtin_amdgcn_s_barrier();
        asm volatile("s_waitcnt lgkmcnt(0)" ::: "memory");
        __builtin_amdgcn_sched_barrier(0);
        __builtin_amdgcn_s_setprio(1);
#pragma unroll
        for (int mi = 0; mi < 4; ++mi)
#pragma unroll
            for (int n = 2; n < 4; ++n)
#pragma unroll
                for (int kk = 0; kk < 2; ++kk)
                    acc[mi][n] = __builtin_amdgcn_mfma_f32_16x16x32_bf16(
                        af[mi][kk], bfr[n][kk], acc[mi][n], 0, 0, 0);
        __builtin_amdgcn_s_setprio(0);
        __builtin_amdgcn_s_barrier();
        // ---- phase 3: read A(mq1); stage B0(kt+2); MFMA (mq1,nq1) ----
#pragma unroll
        for (int mi = 0; mi < 4; ++mi)
#pragma unroll
            for (int kk = 0; kk < 2; ++kk)
                af[mi][kk] = *reinterpret_cast<const bf16x8*>(
                    la + kk * 16384 + ((mi + 4) * 32 + arow) * 64 + ga);
        stage(1, kt + 2, 0);
        __builtin_amdgcn_s_barrier();
        asm volatile("s_waitcnt lgkmcnt(0)" ::: "memory");
        __builtin_amdgcn_sched_barrier(0);
        __builtin_amdgcn_s_setprio(1);
#pragma unroll
        for (int mi = 0; mi < 4; ++mi)
#pragma unroll
            for (int n = 2; n < 4; ++n)
#pragma unroll
                for (int kk = 0; kk < 2; ++kk)
                    acc[mi + 4][n] = __builtin_amdgcn_mfma_f32_16x16x32_bf16(
                        af[mi][kk], bfr[n][kk], acc[mi + 4][n], 0, 0, 0);
        __builtin_amdgcn_s_setprio(0);
        __builtin_amdgcn_s_barrier();
        // ---- phase 4: stage B1(kt+2); counted vmcnt; MFMA (mq1,nq0) ----
        stage(1, kt + 2, 1);
        if (kt < NT - 2) {
            asm volatile("s_waitcnt vmcnt(6)" ::: "memory");
        } else {
            asm volatile("s_waitcnt vmcnt(0)" ::: "memory");
        }
        __builtin_amdgcn_s_barrier();
        __builtin_amdgcn_s_setprio(1);
#pragma unroll
        for (int mi = 0; mi < 4; ++mi)
#pragma unroll
            for (int n = 0; n < 2; ++n)
#pragma unroll
                for (int kk = 0; kk < 2; ++kk)
                    acc[mi + 4][n] = __builtin_amdgcn_mfma_f32_16x16x32_bf16(
                        af[mi][kk], bfr[n][kk], acc[mi + 4][n], 0, 0, 0);
        __builtin_amdgcn_s_setprio(0);
        __builtin_amdgcn_s_barrier();
    }
    // epilogue: C/D map col=lane&15, row=(lane>>4)*4+reg
#pragma unroll
    for (int m = 0; m < 8; ++m) {
        int crow = m0 + m * 32 + wr * 16 + g * 4;
#pragma unroll
        for (int n = 0; n < 4; ++n) {
            int col = n0 + n * 64 + wc * 16 + lr;
            f32x4 v = acc[m][n];
#pragma unroll
            for (int r = 0; r < 4; ++r) {
                size_t o = (size_t)(crow + r) * N + col;
                if (MODE == 0) Cf[o] = v[r];
                else if (MODE == 1) Cb[o] = __float2bfloat16(v[r]);
                else Cf[o] += v[r];
            }
        }
    }
}

// ---------------- MFMA flash attention ----------------------------------------
// grid (S/64, H, B), 256 thr = 4 waves; wave w owns q rows q0+w*16..+15.
__global__ __launch_bounds__(256, 2) void attn_kernel(
    const __hip_bfloat16* __restrict__ proj, __hip_bfloat16* __restrict__ a) {
    __shared__ __align__(16) char ksm[64 * 128];       // K [kv][64 bf16], swizzled cols
    __shared__ __align__(16) char vsm[64 * 128];       // V^T [d][kv], swizzled cols
    __shared__ __align__(16) char psm[4 * 16 * 128];   // per-wave P [q][kv]
    int qt = blockIdx.x, head = blockIdx.y, b = blockIdx.z;
    int t = threadIdx.x;
    int lane = t & 63, w = t >> 6;
    int r = lane & 15, g = lane >> 4;
    int r7s = (r & 7) << 4;  // read-side swizzle for rows r, byte units
    int q0 = qt * 64;
    int qcol = head * 64;
    const __hip_bfloat16* pb = proj + (size_t)b * S_ * PROJN_;
    bf16x8 qf[2];
#pragma unroll
    for (int kk = 0; kk < 2; ++kk)
        qf[kk] = *reinterpret_cast<const bf16x8*>(
            pb + (size_t)(q0 + w * 16 + r) * PROJN_ + qcol + kk * 32 + g * 8);
    int krow = lane >> 3;
    int kcolswz = ((lane & 7) ^ krow) * 8;  // element offset in row
    int vdg = lane & 7;
    float m = -1e30f, l = 0.f;
    f32x4 o_acc[4] = {};
    char* pw = psm + w * 2048;
    for (int kt = 0; kt < 16; ++kt) {
        int k0 = kt * 64;
#pragma unroll
        for (int c = 0; c < 2; ++c) {
            const __hip_bfloat16* src =
                pb + (size_t)(k0 + w * 16 + c * 8 + krow) * PROJN_ + 1024 + qcol + kcolswz;
            GLOAD16(src, ksm + (w * 16 + c * 8) * 128);
        }
#pragma unroll
        for (int it = 0; it < 2; ++it) {
            int kv = it * 32 + w * 8 + krow;
            bf16x8 vv = *reinterpret_cast<const bf16x8*>(
                pb + (size_t)(k0 + kv) * PROJN_ + 2048 + qcol + vdg * 8);
            int kv2 = kv * 2;
#pragma unroll
            for (int i = 0; i < 8; ++i) {
                int j = (i + vdg) & 7;
                int d = vdg * 8 + j;
                *reinterpret_cast<short*>(vsm + d * 128 + (kv2 ^ ((d & 7) << 4))) = vv[j];
            }
        }
        __syncthreads();
        // ---- QK^T -> S^T tile [64 kv][16 q] ----
        f32x4 st[4] = {};
        __builtin_amdgcn_s_setprio(1);
#pragma unroll
        for (int j = 0; j < 4; ++j) {
#pragma unroll
            for (int kk = 0; kk < 2; ++kk) {
                bf16x8 kf = *reinterpret_cast<const bf16x8*>(
                    ksm + (j * 16 + r) * 128 + ((((kk * 4 + g) << 4) ^ r7s)));
                st[j] = __builtin_amdgcn_mfma_f32_16x16x32_bf16(kf, qf[kk], st[j], 0, 0, 0);
            }
        }
        __builtin_amdgcn_s_setprio(0);
        // ---- online softmax: lane owns q = w*16 + r, kv = j*16 + g*4 + rr ----
        float tmax = -1e30f;
#pragma unroll
        for (int j = 0; j < 4; ++j)
#pragma unroll
            for (int rr = 0; rr < 4; ++rr) {
                st[j][rr] *= 0.125f;
                tmax = fmaxf(tmax, st[j][rr]);
            }
        tmax = fmaxf(tmax, __shfl_xor(tmax, 16, 64));
        tmax = fmaxf(tmax, __shfl_xor(tmax, 32, 64));
        float mnew = fmaxf(m, tmax);
        float rsum = 0.f;
#pragma unroll
        for (int j = 0; j < 4; ++j)
#pragma unroll
            for (int rr = 0; rr < 4; ++rr) {
                float p = __expf(st[j][rr] - mnew);
                st[j][rr] = p;
                rsum += p;
            }
        rsum += __shfl_xor(rsum, 16, 64);
        rsum += __shfl_xor(rsum, 32, 64);
        float alpha = __expf(m - mnew);
        l = l * alpha + rsum;
        m = mnew;
#pragma unroll
        for (int j = 0; j < 4; ++j)
#pragma unroll
            for (int rr = 0; rr < 4; ++rr) {
                int kv2 = j * 32 + g * 8 + rr * 2;
                *reinterpret_cast<short*>(pw + r * 128 + (kv2 ^ r7s)) = f2b(st[j][rr]);
            }
        asm volatile("s_waitcnt lgkmcnt(0)" ::: "memory");
        __builtin_amdgcn_sched_barrier(0);
        float ar[4];
#pragma unroll
        for (int rr = 0; rr < 4; ++rr) ar[rr] = __shfl(alpha, g * 4 + rr, 64);
#pragma unroll
        for (int dt = 0; dt < 4; ++dt)
#pragma unroll
            for (int rr = 0; rr < 4; ++rr) o_acc[dt][rr] *= ar[rr];
        // ---- PV: O[q][d] += P[q][kv] V^T[d][kv] ----
        __builtin_amdgcn_s_setprio(1);
#pragma unroll
        for (int kk = 0; kk < 2; ++kk) {
            bf16x8 pf = *reinterpret_cast<const bf16x8*>(
                pw + r * 128 + ((((kk * 4 + g) << 4) ^ r7s)));
#pragma unroll
            for (int dt = 0; dt < 4; ++dt) {
                bf16x8 vf = *reinterpret_cast<const bf16x8*>(
                    vsm + (dt * 16 + r) * 128 + ((((kk * 4 + g) << 4) ^ r7s)));
                o_acc[dt] = __builtin_amdgcn_mfma_f32_16x16x32_bf16(pf, vf, o_acc[dt], 0, 0, 0);
            }
        }
        __builtin_amdgcn_s_setprio(0);
        __syncthreads();
    }
    float linv = 1.f / l;
    float lr4[4];
#pragma unroll
    for (int rr = 0; rr < 4; ++rr) lr4[rr] = __shfl(linv, g * 4 + rr, 64);
    short* ap = reinterpret_cast<short*>(a);
#pragma unroll
    for (int dt = 0; dt < 4; ++dt)
#pragma unroll
        for (int rr = 0; rr < 4; ++rr) {
            size_t o = ((size_t)b * S_ + q0 + w * 16 + g * 4 + rr) * (size_t)(H_ * DH_) +
                       qcol + dt * 16 + r;
            ap[o] = f2b(o_acc[dt][rr] * lr4[rr]);
        }
}

// ---------------- ffg = bf16(ff * gelu_tanh(gate)) ----------------------------
__global__ void ffg_kernel(const __hip_bfloat16* __restrict__ proj,
                           __hip_bfloat16* __restrict__ ffg) {
    size_t idx = (size_t)blockIdx.x * 256 + threadIdx.x;  // over BS_*FF_/8
    int row = (int)(idx >> 9);
    int j8 = (int)(idx & 511) * 8;
    const __hip_bfloat16* pr = proj + (size_t)row * PROJN_;
    bf16x8 fv = *reinterpret_cast<const bf16x8*>(pr + 3072 + j8);
    bf16x8 gv = *reinterpret_cast<const bf16x8*>(pr + 7168 + j8);
    bf16x8 o;
#pragma unroll
    for (int d = 0; d < 8; ++d) o[d] = f2b(b2f(fv[d]) * gelu_tanh(b2f(gv[d])));
    *reinterpret_cast<bf16x8*>(reinterpret_cast<short*>(ffg) + (size_t)row * FF_ + j8) = o;
}

extern "C" void kernel_launch(void* const* d_in, const int* in_sizes, int n_in,
                              void* d_out, int out_size, void* d_ws, size_t ws_size,
                              hipStream_t stream) {
    const float* inputs = (const float*)d_in[0];
    const float* time = (const float*)d_in[1];
    const float* in_W = (const float*)d_in[2];
    const float* in_b = (const float*)d_in[3];
    const float* out_W = (const float*)d_in[4];
    const float* out_b = (const float*)d_in[5];
    const float* t_W1 = (const float*)d_in[6];
    const float* t_b1 = (const float*)d_in[7];
    const float* t_W2 = (const float*)d_in[8];
    const float* t_b2 = (const float*)d_in[9];
    const float* ln_scale = (const float*)d_in[10];
    const float* ln_bias = (const float*)d_in[11];
    const float* proj_W = (const float*)d_in[12];
    const float* attn_W = (const float*)d_in[13];
    const float* ff_W = (const float*)d_in[14];
    float* out = (float*)d_out;

    float* ws = (float*)d_ws;
    size_t off = 0;
    float* temb0 = ws + off; off += 8 * 1024;
    float* tact = ws + off;  off += 8 * 4096;
    float* temb = ws + off;  off += 8 * 1024;
    float* pos = ws + off;   off += (size_t)S_ * D_;
    float* h = ws + off;     off += (size_t)BS_ * D_;
    __hip_bfloat16* u = (__hip_bfloat16*)(ws + off);      off += (size_t)BS_ * D_ / 2;
    __hip_bfloat16* a = (__hip_bfloat16*)(ws + off);      off += (size_t)BS_ * D_ / 2;
    __hip_bfloat16* ffg = (__hip_bfloat16*)(ws + off);    off += (size_t)BS_ * FF_ / 2;
    __hip_bfloat16* proj = (__hip_bfloat16*)(ws + off);   off += (size_t)BS_ * PROJN_ / 2;
    __hip_bfloat16* hb = (__hip_bfloat16*)(ws + off);     off += (size_t)BS_ * D_ / 2;
    __hip_bfloat16* inbf = (__hip_bfloat16*)(ws + off);   off += (size_t)BS_ * (2 * E_) / 2;
    __hip_bfloat16* in_Wt = (__hip_bfloat16*)(ws + off);  off += (size_t)(2 * E_) * D_ / 2;
    __hip_bfloat16* out_Wt = (__hip_bfloat16*)(ws + off); off += (size_t)D_ * E_ / 2;
    __hip_bfloat16* Wpt = (__hip_bfloat16*)(ws + off);    off += (size_t)D_ * PROJN_ / 2;
    __hip_bfloat16* Wat = (__hip_bfloat16*)(ws + off);    off += (size_t)D_ * D_ / 2;
    __hip_bfloat16* Wft = (__hip_bfloat16*)(ws + off);    off += (size_t)FF_ * D_ / 2;

    dim3 blk(256);

    temb0_kernel<<<B_, 512, 0, stream>>>(time, temb0);
    tmlp_kernel<<<TDIM_ / 16, blk, 0, stream>>>(temb0, t_W1, t_b1, tact, D_, TDIM_);
    tmlp_kernel<<<D_ / 16, blk, 0, stream>>>(tact, t_W2, t_b2, temb, TDIM_, D_);
    pos_kernel<<<S_, 512, 0, stream>>>(pos);
    f2b4_kernel<<<(BS_ * 2 * E_) / 1024, blk, 0, stream>>>(inputs, inbf);
    convT_kernel<<<dim3(D_ / 64, (2 * E_) / 64), blk, 0, stream>>>(in_W, in_Wt, 2 * E_, D_);
    convT_kernel<<<dim3(E_ / 64, D_ / 64), blk, 0, stream>>>(out_W, out_Wt, D_, E_);
    mfma_gemm<0, 1><<<dim3(D_ / 128, BS_ / 128), blk, 0, stream>>>(
        inbf, in_Wt, in_b, h, nullptr, BS_, D_, 2 * E_);
    addpe_kernel<<<(BS_ * D_) / 256, blk, 0, stream>>>(h, pos, temb);

    for (int l = 0; l < L_; ++l) {
        const float* Wp = proj_W + (size_t)l * D_ * PROJN_;
        const float* Wa = attn_W + (size_t)l * (H_ * DH_) * D_;
        const float* Wf = ff_W + (size_t)l * FF_ * D_;
        convT_kernel<<<dim3(PROJN_ / 64, D_ / 64), blk, 0, stream>>>(Wp, Wpt, D_, PROJN_);
        convT_kernel<<<dim3(D_ / 64, D_ / 64), blk, 0, stream>>>(Wa, Wat, D_, D_);
        convT_kernel<<<dim3(D_ / 64, FF_ / 64), blk, 0, stream>>>(Wf, Wft, FF_, D_);
        ln_kernel<<<BS_, blk, 0, stream>>>(h, ln_scale + l * D_, ln_bias + l * D_, u);
        gemm256<1><<<dim3(PROJN_ / 256, BS_ / 256), dim3(512), 0, stream>>>(
            u, Wpt, nullptr, proj, BS_, PROJN_, D_);
        attn_kernel<<<dim3(S_ / 64, H_, B_), blk, 0, stream>>>(proj, a);
        mfma_gemm<2, 0><<<dim3(D_ / 128, BS_ / 128), blk, 0, stream>>>(
            a, Wat, nullptr, h, nullptr, BS_, D_, H_ * DH_);
        ffg_kernel<<<(BS_ * (FF_ / 8)) / 256, blk, 0, stream>>>(proj, ffg);
        mfma_gemm<2, 0><<<dim3(D_ / 128, BS_ / 128), blk, 0, stream>>>(
            ffg, Wft, nullptr, h, nullptr, BS_, D_, FF_);
    }
    f2b4_kernel<<<(BS_ * D_) / 1024, blk, 0, stream>>>(h, hb);
    mfma_gemm<0, 1><<<dim3(E_ / 128, BS_ / 128), blk, 0, stream>>>(
        hb, out_Wt, out_b, out, nullptr, BS_, E_, D_);
}

// Round 6
// 5588.815 us; speedup vs baseline: 15.4426x; 1.1972x over previous
//
#include <hip/hip_runtime.h>
#include <hip/hip_bf16.h>
#include <math.h>

// Problem constants
static constexpr int B_ = 8, S_ = 1024, E_ = 256, D_ = 1024, H_ = 16, DH_ = 64,
                     FF_ = 4096, L_ = 12, TDIM_ = 4096;
static constexpr int BS_ = B_ * S_;                    // 8192 rows
static constexpr int PROJN_ = 3 * H_ * DH_ + 2 * FF_;  // 11264
static constexpr int PROJ3_ = 3 * H_ * DH_;            // 3072 (qkv only)
static constexpr int AOW_ = H_ * DH_ + FF_;            // 5120 (attn | ffg)

typedef __attribute__((ext_vector_type(8))) short bf16x8;
typedef __attribute__((ext_vector_type(4))) short bf16x4;
typedef __attribute__((ext_vector_type(4))) float f32x4;

__device__ __forceinline__ float b2f(short b) {
    return __uint_as_float(((unsigned)(unsigned short)b) << 16);
}
__device__ __forceinline__ short f2b(float f) {
    __hip_bfloat16 h = __float2bfloat16(f);
    return *reinterpret_cast<short*>(&h);
}
__device__ __forceinline__ float gelu_exact(float x) {
    return 0.5f * x * (1.f + erff(x * 0.70710678118654752440f));
}
__device__ __forceinline__ float gelu_tanh(float x) {
    // x*0.5*(1+tanh(u)) == x*sigmoid(2u), u = 0.79788456*(x + 0.044715 x^3)
    float u2 = 1.59576912160573070f * (x + 0.044715f * x * x * x);
    return x / (1.f + __expf(-u2));
}

#define GLOAD16(g, l)                                                     \
    __builtin_amdgcn_global_load_lds(                                     \
        (const __attribute__((address_space(1))) void*)(g),               \
        (__attribute__((address_space(3))) void*)(l), 16, 0, 0)

// ---------------- time embedding base: temb0[b] = [sin(ts), cos(ts)] -----------
__global__ void temb0_kernel(const float* __restrict__ time, float* __restrict__ temb0) {
    int b = blockIdx.x;
    int i = threadIdx.x;  // 0..511
    float inv_ts = expf((float)i * (-logf(10000.f) / 511.f));  // half-1 = 511
    float ts = time[b] * inv_ts;
    temb0[b * D_ + i] = sinf(ts);
    temb0[b * D_ + 512 + i] = cosf(ts);
}

// ---------------- fixed positional embedding ----------------------------------
__global__ void pos_kernel(float* __restrict__ pos) {
    int s = blockIdx.x;
    int j = threadIdx.x;  // 0..511
    float inv_freq = expf((float)j * (-logf(10000.f) / 512.f));  // 2j/D = j/512
    float arg = (float)s * inv_freq;
    pos[s * D_ + j] = sinf(arg);
    pos[s * D_ + 512 + j] = cosf(arg);
}

// ---------------- tiny-M GEMM + exact GELU: C[8][N] = gelu(A[8][K]@B + bias) ---
__global__ void tmlp_kernel(const float* __restrict__ A, const float* __restrict__ Bw,
                            const float* __restrict__ bias, float* __restrict__ C,
                            int K, int N) {
    __shared__ float Ast[8][256];
    __shared__ float red2[16][16][9];
    int t = threadIdx.x;
    int col = t & 15, ks = t >> 4;
    int n = blockIdx.x * 16 + col;
    float acc[8];
#pragma unroll
    for (int b = 0; b < 8; ++b) acc[b] = 0.f;
    for (int c0 = 0; c0 < K; c0 += 256) {
#pragma unroll
        for (int i = 0; i < 8; ++i) {
            int idx = t + i * 256;
            Ast[idx >> 8][idx & 255] = A[(idx >> 8) * K + c0 + (idx & 255)];
        }
        __syncthreads();
#pragma unroll
        for (int i = 0; i < 16; ++i) {
            int k = ks * 16 + i;
            float w = Bw[(size_t)(c0 + k) * N + n];
#pragma unroll
            for (int b = 0; b < 8; ++b) acc[b] = fmaf(Ast[b][k], w, acc[b]);
        }
        __syncthreads();
    }
#pragma unroll
    for (int b = 0; b < 8; ++b) red2[ks][col][b] = acc[b];
    __syncthreads();
    if (t < 128) {
        int c2 = t >> 3, b = t & 7;
        float s = 0.f;
#pragma unroll
        for (int k2 = 0; k2 < 16; ++k2) s += red2[k2][c2][b];
        int nn = blockIdx.x * 16 + c2;
        C[(size_t)b * N + nn] = gelu_exact(s + bias[nn]);
    }
}

// ---------------- h += pos[s] + temb[b] ---------------------------------------
__global__ void addpe_kernel(float* __restrict__ h, const float* __restrict__ pos,
                             const float* __restrict__ temb) {
    size_t idx = (size_t)blockIdx.x * 256 + threadIdx.x;  // over BS_*D_
    int d = (int)(idx & 1023);
    int s = (int)((idx >> 10) & 1023);
    int b = (int)(idx >> 20);
    h[idx] += pos[s * D_ + d] + temb[b * D_ + d];
}

// ---------------- fp32 -> bf16 elementwise (n multiple of 1024) ---------------
__global__ void f2b4_kernel(const float* __restrict__ in, __hip_bfloat16* __restrict__ out) {
    size_t i = ((size_t)blockIdx.x * 256 + threadIdx.x) * 4;
    float4 v = *reinterpret_cast<const float4*>(in + i);
    bf16x4 o;
    o[0] = f2b(v.x); o[1] = f2b(v.y); o[2] = f2b(v.z); o[3] = f2b(v.w);
    *reinterpret_cast<bf16x4*>(reinterpret_cast<short*>(out) + i) = o;
}

// ---------------- transpose + convert: W[K][N] fp32 -> Wt[row'(n)][k] bf16 ----
// 64x64 tile. PERM=1: ff/gate column interleave for the fused proj epilogue:
//   n<3072: row'=n; ff j=n-3072: row'=3072+(j>>7)*256+(j&127);
//   gate j=n-7168: row'=3072+(j>>7)*256+128+(j&127).
template <int PERM>
__global__ void convT_kernel(const float* __restrict__ W, __hip_bfloat16* __restrict__ Wt,
                             int K, int N, int outStride, int colOff) {
    __shared__ float tile[64][65];
    int t = threadIdx.x;
    int n0 = blockIdx.x * 64, k0 = blockIdx.y * 64;
#pragma unroll
    for (int i = 0; i < 4; ++i) {
        int idx = t + i * 256;
        int row = idx >> 4, c4 = (idx & 15) * 4;
        float4 v = *reinterpret_cast<const float4*>(W + (size_t)(k0 + row) * N + n0 + c4);
        tile[row][c4 + 0] = v.x; tile[row][c4 + 1] = v.y;
        tile[row][c4 + 2] = v.z; tile[row][c4 + 3] = v.w;
    }
    __syncthreads();
#pragma unroll
    for (int i = 0; i < 4; ++i) {
        int idx = t + i * 256;
        int n = idx >> 4, k4 = (idx & 15) * 4;
        int ng = n0 + n;
        size_t orow;
        if (PERM) {
            if (ng < 3072) orow = ng;
            else if (ng < 7168) { int j = ng - 3072; orow = 3072 + (j >> 7) * 256 + (j & 127); }
            else { int j = ng - 7168; orow = 3072 + (j >> 7) * 256 + 128 + (j & 127); }
        } else {
            orow = ng;
        }
        bf16x4 o;
#pragma unroll
        for (int j = 0; j < 4; ++j) o[j] = f2b(tile[k4 + j][n]);
        *reinterpret_cast<bf16x4*>(reinterpret_cast<short*>(Wt) + orow * outStride + colOff + k0 + k4) = o;
    }
}

// ---------------- LayerNorm: u = bf16((h-m)*rsqrt(v+eps)*g + b) ---------------
__global__ void ln_kernel(const float* __restrict__ h, const float* __restrict__ g,
                          const float* __restrict__ bb, __hip_bfloat16* __restrict__ u) {
    int row = blockIdx.x;
    int t = threadIdx.x;
    const float4 v = reinterpret_cast<const float4*>(h + (size_t)row * D_)[t];
    __shared__ float red[8];
    float s = v.x + v.y + v.z + v.w;
    for (int m8 = 1; m8 < 64; m8 <<= 1) s += __shfl_xor(s, m8, 64);
    if ((t & 63) == 0) red[t >> 6] = s;
    __syncthreads();
    float mean = (red[0] + red[1] + red[2] + red[3]) * (1.f / 1024.f);
    float dx = v.x - mean, dy = v.y - mean, dz = v.z - mean, dw = v.w - mean;
    float sq = dx * dx + dy * dy + dz * dz + dw * dw;
    for (int m8 = 1; m8 < 64; m8 <<= 1) sq += __shfl_xor(sq, m8, 64);
    if ((t & 63) == 0) red[4 + (t >> 6)] = sq;
    __syncthreads();
    float var = (red[4] + red[5] + red[6] + red[7]) * (1.f / 1024.f);
    float inv = rsqrtf(var + 1e-5f);
    int c = t * 4;
    bf16x4 o;
    o[0] = f2b(dx * inv * g[c + 0] + bb[c + 0]);
    o[1] = f2b(dy * inv * g[c + 1] + bb[c + 1]);
    o[2] = f2b(dz * inv * g[c + 2] + bb[c + 2]);
    o[3] = f2b(dw * inv * g[c + 3] + bb[c + 3]);
    *reinterpret_cast<bf16x4*>(reinterpret_cast<short*>(u) + (size_t)row * D_ + c) = o;
}

// ---------------- MFMA bf16 GEMM, m97 structure (generic) ---------------------
// C[M][N] = A[M][K] @ Bt[N][K]^T.  128x128 tile, BK=32, 256 thr (4 waves 2x2).
template <int MODE, int BIAS>
__global__ __launch_bounds__(256) void mfma_gemm(
    const __hip_bfloat16* __restrict__ A, const __hip_bfloat16* __restrict__ Bt,
    const float* __restrict__ bias, float* __restrict__ Cf,
    __hip_bfloat16* __restrict__ Cb, int M, int N, int K) {
    __shared__ __align__(16) char As[128 * 64];
    __shared__ __align__(16) char Bs[128 * 64];
    int t = threadIdx.x;
    int lane = t & 63, wid = t >> 6;
    int m0 = blockIdx.y * 128, n0 = blockIdx.x * 128;
    size_t rowb = (size_t)K * 2;
    int srow = wid * 32 + (lane >> 2);
    int scol = (lane & 3) * 16;
    const char* ag0 = (const char*)A + (size_t)(m0 + srow) * rowb + scol;
    const char* ag1 = (const char*)A + (size_t)(m0 + srow + 16) * rowb + scol;
    const char* bg0 = (const char*)Bt + (size_t)(n0 + srow) * rowb + scol;
    const char* bg1 = (const char*)Bt + (size_t)(n0 + srow + 16) * rowb + scol;
    int lb0 = wid * 32 * 64;
    int lb1 = lb0 + 16 * 64;
    int wr = (wid >> 1) * 64, wc = (wid & 1) * 64;
    int lr = lane & 15;
    int a_base = (wr + lr) * 64 + (lane >> 4) * 16;
    int b_base = (wc + lr) * 64 + (lane >> 4) * 16;
    f32x4 acc[4][4] = {};
    int nkt = K >> 5;
    for (int kt = 0; kt < nkt; ++kt) {
        GLOAD16(ag0, As + lb0);
        GLOAD16(ag1, As + lb1);
        GLOAD16(bg0, Bs + lb0);
        GLOAD16(bg1, Bs + lb1);
        ag0 += 64; ag1 += 64; bg0 += 64; bg1 += 64;
        __syncthreads();
        bf16x8 af[4], bf[4];
#pragma unroll
        for (int f = 0; f < 4; ++f) {
            af[f] = *reinterpret_cast<const bf16x8*>(As + a_base + f * 1024);
            bf[f] = *reinterpret_cast<const bf16x8*>(Bs + b_base + f * 1024);
        }
        __builtin_amdgcn_s_setprio(1);
#pragma unroll
        for (int i = 0; i < 4; ++i)
#pragma unroll
            for (int j = 0; j < 4; ++j)
                acc[i][j] = __builtin_amdgcn_mfma_f32_16x16x32_bf16(af[i], bf[j], acc[i][j], 0, 0, 0);
        __builtin_amdgcn_s_setprio(0);
        __syncthreads();
    }
    int crow0 = m0 + wr + (lane >> 4) * 4;
    int ccol0 = n0 + wc + lr;
#pragma unroll
    for (int i = 0; i < 4; ++i) {
#pragma unroll
        for (int j = 0; j < 4; ++j) {
            int col = ccol0 + j * 16;
            float bv = BIAS ? bias[col] : 0.f;
            f32x4 v = acc[i][j];
#pragma unroll
            for (int r = 0; r < 4; ++r) {
                size_t o = (size_t)(crow0 + i * 16 + r) * N + col;
                float val = v[r] + bv;
                if (MODE == 0) Cf[o] = val;
                else if (MODE == 1) Cb[o] = __float2bfloat16(val);
                else Cf[o] += val;
            }
        }
    }
}

// ---------------- 8-phase 256x256 MFMA GEMM; MODE 3 = fused proj+ffg ----------
// A[M][K] @ Bt[N][K]^T with Bt rows permuted (convT PERM): tiles 0..11 -> qkv
// bf16 into proj (stride 3072); tiles 12..43: cols 0..127 = ff, 128..255 = the
// paired gate -> write ff*gelu(gate) into Fb (= ao+1024, stride 5120).
template <int MODE>
__global__ __launch_bounds__(512, 2) void gemm256(
    const __hip_bfloat16* __restrict__ A, const __hip_bfloat16* __restrict__ Bt,
    float* __restrict__ Cf, __hip_bfloat16* __restrict__ Cb,
    __hip_bfloat16* __restrict__ Fb, int M, int N, int K) {
    __shared__ __align__(16) char lds[131072];
    const int t = threadIdx.x;
    const int lane = t & 63, wid = t >> 6;
    const int lr = lane & 15, g = lane >> 4;
    const int wr = wid >> 2, wc = wid & 3;
    const int m0 = blockIdx.y * 256, n0 = blockIdx.x * 256;
    const size_t rowb = (size_t)K * 2;
    const int NT = K >> 6;
    const int srow = lane >> 2;
    const int scol = ((lane & 3) ^ (((lane >> 5) & 1) << 1)) * 16;  // src-side swizzle
    const int ga = (g ^ (((lr >> 3) & 1) << 1)) * 16;               // read-side swizzle
    const int arow = wr * 16 + lr;
    const int brow = wc * 16 + lr;
    const char* Ab = (const char*)A;
    const char* Bb = (const char*)Bt;

    auto stage = [&](int mat, int kt, int hh) {
        if (kt >= NT) return;
        int rbase = (mat ? n0 : m0) + hh * 128 + wid * 16 + srow;
        const char* src = (mat ? Bb : Ab) + (size_t)rbase * rowb + (size_t)kt * 128 + scol;
        char* dst = lds + mat * 65536 + (kt & 1) * 32768 + (hh * 128 + wid * 16) * 64;
        GLOAD16(src, dst);
        GLOAD16(src + 64, dst + 16384);
    };

    f32x4 acc[8][4] = {};
    bf16x8 af[4][2], bfr[4][2];

    stage(0, 0, 0); stage(0, 0, 1); stage(1, 0, 0); stage(1, 0, 1);
    stage(0, 1, 0); stage(1, 1, 0); stage(1, 1, 1);
    asm volatile("s_waitcnt vmcnt(6)" ::: "memory");
    __builtin_amdgcn_s_barrier();

    for (int kt = 0; kt < NT; ++kt) {
        const int p = kt & 1;
        const char* la = lds + p * 32768;
        const char* lb = lds + 65536 + p * 32768;
        // phase 1: read A(mq0)+B(n0,1); stage A1(kt+1); MFMA (mq0,nq0)
#pragma unroll
        for (int mi = 0; mi < 4; ++mi)
#pragma unroll
            for (int kk = 0; kk < 2; ++kk)
                af[mi][kk] = *reinterpret_cast<const bf16x8*>(
                    la + kk * 16384 + (mi * 32 + arow) * 64 + ga);
#pragma unroll
        for (int n = 0; n < 2; ++n)
#pragma unroll
            for (int kk = 0; kk < 2; ++kk)
                bfr[n][kk] = *reinterpret_cast<const bf16x8*>(
                    lb + kk * 16384 + (n * 64 + brow) * 64 + ga);
        stage(0, kt + 1, 1);
        __builtin_amdgcn_s_barrier();
        asm volatile("s_waitcnt lgkmcnt(0)" ::: "memory");
        __builtin_amdgcn_sched_barrier(0);
        __builtin_amdgcn_s_setprio(1);
#pragma unroll
        for (int mi = 0; mi < 4; ++mi)
#pragma unroll
            for (int n = 0; n < 2; ++n)
#pragma unroll
                for (int kk = 0; kk < 2; ++kk)
                    acc[mi][n] = __builtin_amdgcn_mfma_f32_16x16x32_bf16(
                        af[mi][kk], bfr[n][kk], acc[mi][n], 0, 0, 0);
        __builtin_amdgcn_s_setprio(0);
        __builtin_amdgcn_s_barrier();
        // phase 2: read B(n2,3); stage A0(kt+2); MFMA (mq0,nq1)
#pragma unroll
        for (int n = 2; n < 4; ++n)
#pragma unroll
            for (int kk = 0; kk < 2; ++kk)
                bfr[n][kk] = *reinterpret_cast<const bf16x8*>(
                    lb + kk * 16384 + (n * 64 + brow) * 64 + ga);
        stage(0, kt + 2, 0);
        __builtin_amdgcn_s_barrier();
        asm volatile("s_waitcnt lgkmcnt(0)" ::: "memory");
        __builtin_amdgcn_sched_barrier(0);
        __builtin_amdgcn_s_setprio(1);
#pragma unroll
        for (int mi = 0; mi < 4; ++mi)
#pragma unroll
            for (int n = 2; n < 4; ++n)
#pragma unroll
                for (int kk = 0; kk < 2; ++kk)
                    acc[mi][n] = __builtin_amdgcn_mfma_f32_16x16x32_bf16(
                        af[mi][kk], bfr[n][kk], acc[mi][n], 0, 0, 0);
        __builtin_amdgcn_s_setprio(0);
        __builtin_amdgcn_s_barrier();
        // phase 3: read A(mq1); stage B0(kt+2); MFMA (mq1,nq1)
#pragma unroll
        for (int mi = 0; mi < 4; ++mi)
#pragma unroll
            for (int kk = 0; kk < 2; ++kk)
                af[mi][kk] = *reinterpret_cast<const bf16x8*>(
                    la + kk * 16384 + ((mi + 4) * 32 + arow) * 64 + ga);
        stage(1, kt + 2, 0);
        __builtin_amdgcn_s_barrier();
        asm volatile("s_waitcnt lgkmcnt(0)" ::: "memory");
        __builtin_amdgcn_sched_barrier(0);
        __builtin_amdgcn_s_setprio(1);
#pragma unroll
        for (int mi = 0; mi < 4; ++mi)
#pragma unroll
            for (int n = 2; n < 4; ++n)
#pragma unroll
                for (int kk = 0; kk < 2; ++kk)
                    acc[mi + 4][n] = __builtin_amdgcn_mfma_f32_16x16x32_bf16(
                        af[mi][kk], bfr[n][kk], acc[mi + 4][n], 0, 0, 0);
        __builtin_amdgcn_s_setprio(0);
        __builtin_amdgcn_s_barrier();
        // phase 4: stage B1(kt+2); counted vmcnt; MFMA (mq1,nq0)
        stage(1, kt + 2, 1);
        if (kt < NT - 2) {
            asm volatile("s_waitcnt vmcnt(6)" ::: "memory");
        } else {
            asm volatile("s_waitcnt vmcnt(0)" ::: "memory");
        }
        __builtin_amdgcn_s_barrier();
        __builtin_amdgcn_s_setprio(1);
#pragma unroll
        for (int mi = 0; mi < 4; ++mi)
#pragma unroll
            for (int n = 0; n < 2; ++n)
#pragma unroll
                for (int kk = 0; kk < 2; ++kk)
                    acc[mi + 4][n] = __builtin_amdgcn_mfma_f32_16x16x32_bf16(
                        af[mi][kk], bfr[n][kk], acc[mi + 4][n], 0, 0, 0);
        __builtin_amdgcn_s_setprio(0);
        __builtin_amdgcn_s_barrier();
    }
    // epilogue: C/D map col=lane&15, row=(lane>>4)*4+reg
    if (MODE == 3 && blockIdx.x >= 12) {
        int jb = ((int)blockIdx.x - 12) * 128;
#pragma unroll
        for (int m = 0; m < 8; ++m) {
            int crow = m0 + m * 32 + wr * 16 + g * 4;
#pragma unroll
            for (int n = 0; n < 2; ++n) {
                int ffcol = jb + n * 64 + wc * 16 + lr;
                f32x4 fv = acc[m][n];
                f32x4 gv = acc[m][n + 2];
#pragma unroll
                for (int r = 0; r < 4; ++r) {
                    float val = fv[r] * gelu_tanh(gv[r]);
                    Fb[(size_t)(crow + r) * AOW_ + ffcol] = __float2bfloat16(val);
                }
            }
        }
        return;
    }
#pragma unroll
    for (int m = 0; m < 8; ++m) {
        int crow = m0 + m * 32 + wr * 16 + g * 4;
#pragma unroll
        for (int n = 0; n < 4; ++n) {
            int col = n0 + n * 64 + wc * 16 + lr;
            f32x4 v = acc[m][n];
#pragma unroll
            for (int r = 0; r < 4; ++r) {
                if (MODE == 3) Cb[(size_t)(crow + r) * PROJ3_ + col] = __float2bfloat16(v[r]);
                else if (MODE == 0) Cf[(size_t)(crow + r) * N + col] = v[r];
                else if (MODE == 1) Cb[(size_t)(crow + r) * N + col] = __float2bfloat16(v[r]);
                else Cf[(size_t)(crow + r) * N + col] += v[r];
            }
        }
    }
}

// ---------------- MFMA flash attention ----------------------------------------
// 1-D grid 2048, XCD-grouped: all 16 qt-blocks of one (head,b) on one XCD.
// proj stride 3072 (qkv); output into ao cols 0..1023 (stride 5120).
__global__ __launch_bounds__(256, 2) void attn_kernel(
    const __hip_bfloat16* __restrict__ proj, __hip_bfloat16* __restrict__ ao) {
    __shared__ __align__(16) char ksm[64 * 128];
    __shared__ __align__(16) char vsm[64 * 128];
    __shared__ __align__(16) char psm[4 * 16 * 128];
    int wgid = blockIdx.x;
    int xcd = wgid & 7, slot = wgid >> 3;
    int group = xcd * 16 + (slot >> 4);
    int qt = slot & 15;
    int head = group & 15, b = group >> 4;
    int t = threadIdx.x;
    int lane = t & 63, w = t >> 6;
    int r = lane & 15, g = lane >> 4;
    int r7s = (r & 7) << 4;
    int q0 = qt * 64;
    int qcol = head * 64;
    const __hip_bfloat16* pb = proj + (size_t)b * S_ * PROJ3_;
    bf16x8 qf[2];
#pragma unroll
    for (int kk = 0; kk < 2; ++kk)
        qf[kk] = *reinterpret_cast<const bf16x8*>(
            pb + (size_t)(q0 + w * 16 + r) * PROJ3_ + qcol + kk * 32 + g * 8);
    int krow = lane >> 3;
    int kcolswz = ((lane & 7) ^ krow) * 8;
    int vdg = lane & 7;
    float m = -1e30f, l = 0.f;
    f32x4 o_acc[4] = {};
    char* pw = psm + w * 2048;
    for (int kt = 0; kt < 16; ++kt) {
        int k0 = kt * 64;
#pragma unroll
        for (int c = 0; c < 2; ++c) {
            const __hip_bfloat16* src =
                pb + (size_t)(k0 + w * 16 + c * 8 + krow) * PROJ3_ + 1024 + qcol + kcolswz;
            GLOAD16(src, ksm + (w * 16 + c * 8) * 128);
        }
#pragma unroll
        for (int it = 0; it < 2; ++it) {
            int kv = it * 32 + w * 8 + krow;
            bf16x8 vv = *reinterpret_cast<const bf16x8*>(
                pb + (size_t)(k0 + kv) * PROJ3_ + 2048 + qcol + vdg * 8);
            int kv2 = kv * 2;
#pragma unroll
            for (int i = 0; i < 8; ++i) {
                int j = (i + vdg) & 7;
                int d = vdg * 8 + j;
                *reinterpret_cast<short*>(vsm + d * 128 + (kv2 ^ ((d & 7) << 4))) = vv[j];
            }
        }
        __syncthreads();
        f32x4 st[4] = {};
        __builtin_amdgcn_s_setprio(1);
#pragma unroll
        for (int j = 0; j < 4; ++j) {
#pragma unroll
            for (int kk = 0; kk < 2; ++kk) {
                bf16x8 kf = *reinterpret_cast<const bf16x8*>(
                    ksm + (j * 16 + r) * 128 + ((((kk * 4 + g) << 4) ^ r7s)));
                st[j] = __builtin_amdgcn_mfma_f32_16x16x32_bf16(kf, qf[kk], st[j], 0, 0, 0);
            }
        }
        __builtin_amdgcn_s_setprio(0);
        float tmax = -1e30f;
#pragma unroll
        for (int j = 0; j < 4; ++j)
#pragma unroll
            for (int rr = 0; rr < 4; ++rr) {
                st[j][rr] *= 0.125f;
                tmax = fmaxf(tmax, st[j][rr]);
            }
        tmax = fmaxf(tmax, __shfl_xor(tmax, 16, 64));
        tmax = fmaxf(tmax, __shfl_xor(tmax, 32, 64));
        float mnew = fmaxf(m, tmax);
        float rsum = 0.f;
#pragma unroll
        for (int j = 0; j < 4; ++j)
#pragma unroll
            for (int rr = 0; rr < 4; ++rr) {
                float p = __expf(st[j][rr] - mnew);
                st[j][rr] = p;
                rsum += p;
            }
        rsum += __shfl_xor(rsum, 16, 64);
        rsum += __shfl_xor(rsum, 32, 64);
        float alpha = __expf(m - mnew);
        l = l * alpha + rsum;
        m = mnew;
#pragma unroll
        for (int j = 0; j < 4; ++j)
#pragma unroll
            for (int rr = 0; rr < 4; ++rr) {
                int kv2 = j * 32 + g * 8 + rr * 2;
                *reinterpret_cast<short*>(pw + r * 128 + (kv2 ^ r7s)) = f2b(st[j][rr]);
            }
        asm volatile("s_waitcnt lgkmcnt(0)" ::: "memory");
        __builtin_amdgcn_sched_barrier(0);
        float ar[4];
#pragma unroll
        for (int rr = 0; rr < 4; ++rr) ar[rr] = __shfl(alpha, g * 4 + rr, 64);
#pragma unroll
        for (int dt = 0; dt < 4; ++dt)
#pragma unroll
            for (int rr = 0; rr < 4; ++rr) o_acc[dt][rr] *= ar[rr];
        __builtin_amdgcn_s_setprio(1);
#pragma unroll
        for (int kk = 0; kk < 2; ++kk) {
            bf16x8 pf = *reinterpret_cast<const bf16x8*>(
                pw + r * 128 + ((((kk * 4 + g) << 4) ^ r7s)));
#pragma unroll
            for (int dt = 0; dt < 4; ++dt) {
                bf16x8 vf = *reinterpret_cast<const bf16x8*>(
                    vsm + (dt * 16 + r) * 128 + ((((kk * 4 + g) << 4) ^ r7s)));
                o_acc[dt] = __builtin_amdgcn_mfma_f32_16x16x32_bf16(pf, vf, o_acc[dt], 0, 0, 0);
            }
        }
        __builtin_amdgcn_s_setprio(0);
        __syncthreads();
    }
    float linv = 1.f / l;
    float lr4[4];
#pragma unroll
    for (int rr = 0; rr < 4; ++rr) lr4[rr] = __shfl(linv, g * 4 + rr, 64);
    short* ap = reinterpret_cast<short*>(ao);
#pragma unroll
    for (int dt = 0; dt < 4; ++dt)
#pragma unroll
        for (int rr = 0; rr < 4; ++rr) {
            size_t o = ((size_t)b * S_ + q0 + w * 16 + g * 4 + rr) * (size_t)AOW_ +
                       qcol + dt * 16 + r;
            ap[o] = f2b(o_acc[dt][rr] * lr4[rr]);
        }
}

extern "C" void kernel_launch(void* const* d_in, const int* in_sizes, int n_in,
                              void* d_out, int out_size, void* d_ws, size_t ws_size,
                              hipStream_t stream) {
    const float* inputs = (const float*)d_in[0];
    const float* time = (const float*)d_in[1];
    const float* in_W = (const float*)d_in[2];
    const float* in_b = (const float*)d_in[3];
    const float* out_W = (const float*)d_in[4];
    const float* out_b = (const float*)d_in[5];
    const float* t_W1 = (const float*)d_in[6];
    const float* t_b1 = (const float*)d_in[7];
    const float* t_W2 = (const float*)d_in[8];
    const float* t_b2 = (const float*)d_in[9];
    const float* ln_scale = (const float*)d_in[10];
    const float* ln_bias = (const float*)d_in[11];
    const float* proj_W = (const float*)d_in[12];
    const float* attn_W = (const float*)d_in[13];
    const float* ff_W = (const float*)d_in[14];
    float* out = (float*)d_out;

    float* ws = (float*)d_ws;
    size_t off = 0;
    float* temb0 = ws + off; off += 8 * 1024;
    float* tact = ws + off;  off += 8 * 4096;
    float* temb = ws + off;  off += 8 * 1024;
    float* pos = ws + off;   off += (size_t)S_ * D_;
    float* h = ws + off;     off += (size_t)BS_ * D_;
    __hip_bfloat16* u = (__hip_bfloat16*)(ws + off);      off += (size_t)BS_ * D_ / 2;
    __hip_bfloat16* proj = (__hip_bfloat16*)(ws + off);   off += (size_t)BS_ * PROJ3_ / 2;
    __hip_bfloat16* ao = (__hip_bfloat16*)(ws + off);     off += (size_t)BS_ * AOW_ / 2;
    __hip_bfloat16* hb = (__hip_bfloat16*)(ws + off);     off += (size_t)BS_ * D_ / 2;
    __hip_bfloat16* inbf = (__hip_bfloat16*)(ws + off);   off += (size_t)BS_ * (2 * E_) / 2;
    __hip_bfloat16* in_Wt = (__hip_bfloat16*)(ws + off);  off += (size_t)(2 * E_) * D_ / 2;
    __hip_bfloat16* out_Wt = (__hip_bfloat16*)(ws + off); off += (size_t)D_ * E_ / 2;
    __hip_bfloat16* Wpt = (__hip_bfloat16*)(ws + off);    off += (size_t)D_ * PROJN_ / 2;
    __hip_bfloat16* Waft = (__hip_bfloat16*)(ws + off);   off += (size_t)D_ * AOW_ / 2;

    dim3 blk(256);

    temb0_kernel<<<B_, 512, 0, stream>>>(time, temb0);
    tmlp_kernel<<<TDIM_ / 16, blk, 0, stream>>>(temb0, t_W1, t_b1, tact, D_, TDIM_);
    tmlp_kernel<<<D_ / 16, blk, 0, stream>>>(tact, t_W2, t_b2, temb, TDIM_, D_);
    pos_kernel<<<S_, 512, 0, stream>>>(pos);
    f2b4_kernel<<<(BS_ * 2 * E_) / 1024, blk, 0, stream>>>(inputs, inbf);
    convT_kernel<0><<<dim3(D_ / 64, (2 * E_) / 64), blk, 0, stream>>>(
        in_W, in_Wt, 2 * E_, D_, 2 * E_, 0);
    convT_kernel<0><<<dim3(E_ / 64, D_ / 64), blk, 0, stream>>>(
        out_W, out_Wt, D_, E_, D_, 0);
    mfma_gemm<0, 1><<<dim3(D_ / 128, BS_ / 128), blk, 0, stream>>>(
        inbf, in_Wt, in_b, h, nullptr, BS_, D_, 2 * E_);
    addpe_kernel<<<(BS_ * D_) / 256, blk, 0, stream>>>(h, pos, temb);

    for (int l = 0; l < L_; ++l) {
        const float* Wp = proj_W + (size_t)l * D_ * PROJN_;
        const float* Wa = attn_W + (size_t)l * (H_ * DH_) * D_;
        const float* Wf = ff_W + (size_t)l * FF_ * D_;
        convT_kernel<1><<<dim3(PROJN_ / 64, D_ / 64), blk, 0, stream>>>(
            Wp, Wpt, D_, PROJN_, D_, 0);
        convT_kernel<0><<<dim3(D_ / 64, D_ / 64), blk, 0, stream>>>(
            Wa, Waft, D_, D_, AOW_, 0);
        convT_kernel<0><<<dim3(D_ / 64, FF_ / 64), blk, 0, stream>>>(
            Wf, Waft, FF_, D_, AOW_, D_);
        ln_kernel<<<BS_, blk, 0, stream>>>(h, ln_scale + l * D_, ln_bias + l * D_, u);
        gemm256<3><<<dim3(PROJN_ / 256, BS_ / 256), dim3(512), 0, stream>>>(
            u, Wpt, nullptr, proj, ao + D_, BS_, PROJN_, D_);
        attn_kernel<<<dim3(2048), blk, 0, stream>>>(proj, ao);
        mfma_gemm<2, 0><<<dim3(D_ / 128, BS_ / 128), blk, 0, stream>>>(
            ao, Waft, nullptr, h, nullptr, BS_, D_, AOW_);  // h += [a|ffg] @ [Wa;Wf]
    }
    f2b4_kernel<<<(BS_ * D_) / 1024, blk, 0, stream>>>(h, hb);
    mfma_gemm<0, 1><<<dim3(E_ / 128, BS_ / 128), blk, 0, stream>>>(
        hb, out_Wt, out_b, out, nullptr, BS_, E_, D_);
}

// Round 7
// 5391.640 us; speedup vs baseline: 16.0074x; 1.0366x over previous
//
#include <hip/hip_runtime.h>
#include <hip/hip_bf16.h>
#include <math.h>

// Problem constants
static constexpr int B_ = 8, S_ = 1024, E_ = 256, D_ = 1024, H_ = 16, DH_ = 64,
                     FF_ = 4096, L_ = 12, TDIM_ = 4096;
static constexpr int BS_ = B_ * S_;                    // 8192 rows
static constexpr int PROJN_ = 3 * H_ * DH_ + 2 * FF_;  // 11264
static constexpr int PROJK_ = 2 * H_ * DH_;            // 2048 (q,k only in proj buf)
static constexpr int AOW_ = H_ * DH_ + FF_;            // 5120 (attn | ffg)

typedef __attribute__((ext_vector_type(8))) short bf16x8;
typedef __attribute__((ext_vector_type(4))) short bf16x4;
typedef __attribute__((ext_vector_type(4))) float f32x4;

__device__ __forceinline__ float b2f(short b) {
    return __uint_as_float(((unsigned)(unsigned short)b) << 16);
}
__device__ __forceinline__ short f2b(float f) {
    __hip_bfloat16 h = __float2bfloat16(f);
    return *reinterpret_cast<short*>(&h);
}
__device__ __forceinline__ float gelu_exact(float x) {
    return 0.5f * x * (1.f + erff(x * 0.70710678118654752440f));
}
__device__ __forceinline__ float gelu_tanh(float x) {
    // x*0.5*(1+tanh(u)) == x*sigmoid(2u), u = 0.79788456*(x + 0.044715 x^3)
    float u2 = 1.59576912160573070f * (x + 0.044715f * x * x * x);
    return x / (1.f + __expf(-u2));
}

#define GLOAD16(g, l)                                                     \
    __builtin_amdgcn_global_load_lds(                                     \
        (const __attribute__((address_space(1))) void*)(g),               \
        (__attribute__((address_space(3))) void*)(l), 16, 0, 0)

// ---------------- time embedding base: temb0[b] = [sin(ts), cos(ts)] -----------
__global__ void temb0_kernel(const float* __restrict__ time, float* __restrict__ temb0) {
    int b = blockIdx.x;
    int i = threadIdx.x;  // 0..511
    float inv_ts = expf((float)i * (-logf(10000.f) / 511.f));  // half-1 = 511
    float ts = time[b] * inv_ts;
    temb0[b * D_ + i] = sinf(ts);
    temb0[b * D_ + 512 + i] = cosf(ts);
}

// ---------------- fixed positional embedding ----------------------------------
__global__ void pos_kernel(float* __restrict__ pos) {
    int s = blockIdx.x;
    int j = threadIdx.x;  // 0..511
    float inv_freq = expf((float)j * (-logf(10000.f) / 512.f));  // 2j/D = j/512
    float arg = (float)s * inv_freq;
    pos[s * D_ + j] = sinf(arg);
    pos[s * D_ + 512 + j] = cosf(arg);
}

// ---------------- tiny-M GEMM + exact GELU: C[8][N] = gelu(A[8][K]@B + bias) ---
__global__ void tmlp_kernel(const float* __restrict__ A, const float* __restrict__ Bw,
                            const float* __restrict__ bias, float* __restrict__ C,
                            int K, int N) {
    __shared__ float Ast[8][256];
    __shared__ float red2[16][16][9];
    int t = threadIdx.x;
    int col = t & 15, ks = t >> 4;
    int n = blockIdx.x * 16 + col;
    float acc[8];
#pragma unroll
    for (int b = 0; b < 8; ++b) acc[b] = 0.f;
    for (int c0 = 0; c0 < K; c0 += 256) {
#pragma unroll
        for (int i = 0; i < 8; ++i) {
            int idx = t + i * 256;
            Ast[idx >> 8][idx & 255] = A[(idx >> 8) * K + c0 + (idx & 255)];
        }
        __syncthreads();
#pragma unroll
        for (int i = 0; i < 16; ++i) {
            int k = ks * 16 + i;
            float w = Bw[(size_t)(c0 + k) * N + n];
#pragma unroll
            for (int b = 0; b < 8; ++b) acc[b] = fmaf(Ast[b][k], w, acc[b]);
        }
        __syncthreads();
    }
#pragma unroll
    for (int b = 0; b < 8; ++b) red2[ks][col][b] = acc[b];
    __syncthreads();
    if (t < 128) {
        int c2 = t >> 3, b = t & 7;
        float s = 0.f;
#pragma unroll
        for (int k2 = 0; k2 < 16; ++k2) s += red2[k2][c2][b];
        int nn = blockIdx.x * 16 + c2;
        C[(size_t)b * N + nn] = gelu_exact(s + bias[nn]);
    }
}

// ---------------- fp32 -> bf16 elementwise (n multiple of 1024) ---------------
__global__ void f2b4_kernel(const float* __restrict__ in, __hip_bfloat16* __restrict__ out) {
    size_t i = ((size_t)blockIdx.x * 256 + threadIdx.x) * 4;
    float4 v = *reinterpret_cast<const float4*>(in + i);
    bf16x4 o;
    o[0] = f2b(v.x); o[1] = f2b(v.y); o[2] = f2b(v.z); o[3] = f2b(v.w);
    *reinterpret_cast<bf16x4*>(reinterpret_cast<short*>(out) + i) = o;
}

// ---------------- transpose+convert body: W[K][N] fp32 -> Wt[row'(n)][k] bf16 --
__device__ __forceinline__ void convT_body(const float* __restrict__ W,
                                           __hip_bfloat16* __restrict__ Wt,
                                           int K, int N, int outStride, int colOff,
                                           int perm, int bx, int by) {
    __shared__ float tile[64][65];
    int t = threadIdx.x;
    int n0 = bx * 64, k0 = by * 64;
#pragma unroll
    for (int i = 0; i < 4; ++i) {
        int idx = t + i * 256;
        int row = idx >> 4, c4 = (idx & 15) * 4;
        float4 v = *reinterpret_cast<const float4*>(W + (size_t)(k0 + row) * N + n0 + c4);
        tile[row][c4 + 0] = v.x; tile[row][c4 + 1] = v.y;
        tile[row][c4 + 2] = v.z; tile[row][c4 + 3] = v.w;
    }
    __syncthreads();
#pragma unroll
    for (int i = 0; i < 4; ++i) {
        int idx = t + i * 256;
        int n = idx >> 4, k4 = (idx & 15) * 4;
        int ng = n0 + n;
        size_t orow;
        if (perm) {
            // ff/gate interleave for fused proj epilogue
            if (ng < 3072) orow = ng;
            else if (ng < 7168) { int j = ng - 3072; orow = 3072 + (j >> 7) * 256 + (j & 127); }
            else { int j = ng - 7168; orow = 3072 + (j >> 7) * 256 + 128 + (j & 127); }
        } else {
            orow = ng;
        }
        bf16x4 o;
#pragma unroll
        for (int j = 0; j < 4; ++j) o[j] = f2b(tile[k4 + j][n]);
        *reinterpret_cast<bf16x4*>(reinterpret_cast<short*>(Wt) + orow * outStride + colOff + k0 + k4) = o;
    }
}

__global__ void convT_kernel(const float* __restrict__ W, __hip_bfloat16* __restrict__ Wt,
                             int K, int N, int outStride, int colOff) {
    convT_body(W, Wt, K, N, outStride, colOff, 0, blockIdx.x, blockIdx.y);
}

// ---------------- batched per-layer weight conversion (Wp perm + Wa + Wf) -----
// 1-D grid 4096: [0,2816) Wp (176x16), [2816,3072) Wa (16x16), [3072,4096) Wf (16x64)
__global__ void convT3_kernel(const float* __restrict__ Wp, const float* __restrict__ Wa,
                              const float* __restrict__ Wf, __hip_bfloat16* __restrict__ Wpt,
                              __hip_bfloat16* __restrict__ Waft) {
    int bid = blockIdx.x;
    if (bid < 2816) {
        convT_body(Wp, Wpt, D_, PROJN_, D_, 0, 1, bid % 176, bid / 176);
    } else if (bid < 3072) {
        int i2 = bid - 2816;
        convT_body(Wa, Waft, D_, D_, AOW_, 0, 0, i2 & 15, i2 >> 4);
    } else {
        int i2 = bid - 3072;
        convT_body(Wf, Waft, FF_, D_, AOW_, D_, 0, i2 & 15, i2 >> 4);
    }
}

// ---------------- LayerNorm: u = bf16((h-m)*rsqrt(v+eps)*g + b) ---------------
__global__ void ln_kernel(const float* __restrict__ h, const float* __restrict__ g,
                          const float* __restrict__ bb, __hip_bfloat16* __restrict__ u) {
    int row = blockIdx.x;
    int t = threadIdx.x;
    const float4 v = reinterpret_cast<const float4*>(h + (size_t)row * D_)[t];
    __shared__ float red[8];
    float s = v.x + v.y + v.z + v.w;
    for (int m8 = 1; m8 < 64; m8 <<= 1) s += __shfl_xor(s, m8, 64);
    if ((t & 63) == 0) red[t >> 6] = s;
    __syncthreads();
    float mean = (red[0] + red[1] + red[2] + red[3]) * (1.f / 1024.f);
    float dx = v.x - mean, dy = v.y - mean, dz = v.z - mean, dw = v.w - mean;
    float sq = dx * dx + dy * dy + dz * dz + dw * dw;
    for (int m8 = 1; m8 < 64; m8 <<= 1) sq += __shfl_xor(sq, m8, 64);
    if ((t & 63) == 0) red[4 + (t >> 6)] = sq;
    __syncthreads();
    float var = (red[4] + red[5] + red[6] + red[7]) * (1.f / 1024.f);
    float inv = rsqrtf(var + 1e-5f);
    int c = t * 4;
    bf16x4 o;
    o[0] = f2b(dx * inv * g[c + 0] + bb[c + 0]);
    o[1] = f2b(dy * inv * g[c + 1] + bb[c + 1]);
    o[2] = f2b(dz * inv * g[c + 2] + bb[c + 2]);
    o[3] = f2b(dw * inv * g[c + 3] + bb[c + 3]);
    *reinterpret_cast<bf16x4*>(reinterpret_cast<short*>(u) + (size_t)row * D_ + c) = o;
}

// ---------------- MFMA bf16 GEMM, m97 structure (generic) ---------------------
// C[M][N] = A[M][K] @ Bt[N][K]^T.  128x128 tile, BK=32, 256 thr (4 waves 2x2).
// ADDPE: epilogue adds pos[s][col] + temb[b][col] (input GEMM fusion).
template <int MODE, int BIAS, int ADDPE>
__global__ __launch_bounds__(256) void mfma_gemm(
    const __hip_bfloat16* __restrict__ A, const __hip_bfloat16* __restrict__ Bt,
    const float* __restrict__ bias, float* __restrict__ Cf,
    __hip_bfloat16* __restrict__ Cb, const float* __restrict__ pe_pos,
    const float* __restrict__ pe_temb, int M, int N, int K) {
    __shared__ __align__(16) char As[128 * 64];
    __shared__ __align__(16) char Bs[128 * 64];
    int t = threadIdx.x;
    int lane = t & 63, wid = t >> 6;
    int m0 = blockIdx.y * 128, n0 = blockIdx.x * 128;
    size_t rowb = (size_t)K * 2;
    int srow = wid * 32 + (lane >> 2);
    int scol = (lane & 3) * 16;
    const char* ag0 = (const char*)A + (size_t)(m0 + srow) * rowb + scol;
    const char* ag1 = (const char*)A + (size_t)(m0 + srow + 16) * rowb + scol;
    const char* bg0 = (const char*)Bt + (size_t)(n0 + srow) * rowb + scol;
    const char* bg1 = (const char*)Bt + (size_t)(n0 + srow + 16) * rowb + scol;
    int lb0 = wid * 32 * 64;
    int lb1 = lb0 + 16 * 64;
    int wr = (wid >> 1) * 64, wc = (wid & 1) * 64;
    int lr = lane & 15;
    int a_base = (wr + lr) * 64 + (lane >> 4) * 16;
    int b_base = (wc + lr) * 64 + (lane >> 4) * 16;
    f32x4 acc[4][4] = {};
    int nkt = K >> 5;
    for (int kt = 0; kt < nkt; ++kt) {
        GLOAD16(ag0, As + lb0);
        GLOAD16(ag1, As + lb1);
        GLOAD16(bg0, Bs + lb0);
        GLOAD16(bg1, Bs + lb1);
        ag0 += 64; ag1 += 64; bg0 += 64; bg1 += 64;
        __syncthreads();
        bf16x8 af[4], bf[4];
#pragma unroll
        for (int f = 0; f < 4; ++f) {
            af[f] = *reinterpret_cast<const bf16x8*>(As + a_base + f * 1024);
            bf[f] = *reinterpret_cast<const bf16x8*>(Bs + b_base + f * 1024);
        }
        __builtin_amdgcn_s_setprio(1);
#pragma unroll
        for (int i = 0; i < 4; ++i)
#pragma unroll
            for (int j = 0; j < 4; ++j)
                acc[i][j] = __builtin_amdgcn_mfma_f32_16x16x32_bf16(af[i], bf[j], acc[i][j], 0, 0, 0);
        __builtin_amdgcn_s_setprio(0);
        __syncthreads();
    }
    int crow0 = m0 + wr + (lane >> 4) * 4;
    int ccol0 = n0 + wc + lr;
#pragma unroll
    for (int i = 0; i < 4; ++i) {
#pragma unroll
        for (int j = 0; j < 4; ++j) {
            int col = ccol0 + j * 16;
            float bv = BIAS ? bias[col] : 0.f;
            f32x4 v = acc[i][j];
#pragma unroll
            for (int r = 0; r < 4; ++r) {
                int row = crow0 + i * 16 + r;
                size_t o = (size_t)row * N + col;
                float val = v[r] + bv;
                if (ADDPE)
                    val += pe_pos[(size_t)(row & 1023) * D_ + col] +
                           pe_temb[(size_t)(row >> 10) * D_ + col];
                if (MODE == 0) Cf[o] = val;
                else if (MODE == 1) Cb[o] = __float2bfloat16(val);
                else Cf[o] += val;
            }
        }
    }
}

// ---------------- 8-phase 256x256 MFMA GEMM; MODE 3 = fused proj+ffg ----------
// A[M][K] @ Bt[N][K]^T with Bt rows permuted (convT perm). Block tiles (bx):
//   0..7:  q,k -> proj bf16 (stride 2048)
//   8..11: v   -> vt bf16 TRANSPOSED: vt[(b*16+head)*64+d][s]
//   12..43: cols 0..127 = ff, 128..255 = paired gate -> ff*gelu(gate) into Fb
// XCD-swizzled block order (nwg % 8 == 0).
template <int MODE>
__global__ __launch_bounds__(512, 2) void gemm256(
    const __hip_bfloat16* __restrict__ A, const __hip_bfloat16* __restrict__ Bt,
    float* __restrict__ Cf, __hip_bfloat16* __restrict__ Cb,
    __hip_bfloat16* __restrict__ Fb, __hip_bfloat16* __restrict__ Vt,
    int M, int N, int K) {
    __shared__ __align__(16) char lds[131072];
    const int t = threadIdx.x;
    const int lane = t & 63, wid = t >> 6;
    const int lr = lane & 15, g = lane >> 4;
    const int wr = wid >> 2, wc = wid & 3;
    // XCD-aware bijective swizzle (consecutive hw blocks on one XCD get
    // contiguous tile ids -> shared A-panels resident in that XCD's L2)
    const int nbx = gridDim.x;
    const int nwg = nbx * gridDim.y;
    const int bid = blockIdx.y * nbx + blockIdx.x;
    const int swz = (bid & 7) * (nwg >> 3) + (bid >> 3);
    const int bx = swz % nbx, by = swz / nbx;
    const int m0 = by * 256, n0 = bx * 256;
    const size_t rowb = (size_t)K * 2;
    const int NT = K >> 6;
    const int srow = lane >> 2;
    const int scol = ((lane & 3) ^ (((lane >> 5) & 1) << 1)) * 16;  // src-side swizzle
    const int ga = (g ^ (((lr >> 3) & 1) << 1)) * 16;               // read-side swizzle
    const int arow = wr * 16 + lr;
    const int brow = wc * 16 + lr;
    const char* Ab = (const char*)A;
    const char* Bb = (const char*)Bt;

    auto stage = [&](int mat, int kt, int hh) {
        if (kt >= NT) return;
        int rbase = (mat ? n0 : m0) + hh * 128 + wid * 16 + srow;
        const char* src = (mat ? Bb : Ab) + (size_t)rbase * rowb + (size_t)kt * 128 + scol;
        char* dst = lds + mat * 65536 + (kt & 1) * 32768 + (hh * 128 + wid * 16) * 64;
        GLOAD16(src, dst);
        GLOAD16(src + 64, dst + 16384);
    };

    f32x4 acc[8][4] = {};
    bf16x8 af[4][2], bfr[4][2];

    stage(0, 0, 0); stage(0, 0, 1); stage(1, 0, 0); stage(1, 0, 1);
    stage(0, 1, 0); stage(1, 1, 0); stage(1, 1, 1);
    asm volatile("s_waitcnt vmcnt(6)" ::: "memory");
    __builtin_amdgcn_s_barrier();

    for (int kt = 0; kt < NT; ++kt) {
        const int p = kt & 1;
        const char* la = lds + p * 32768;
        const char* lb = lds + 65536 + p * 32768;
        // phase 1: read A(mq0)+B(n0,1); stage A1(kt+1); MFMA (mq0,nq0)
#pragma unroll
        for (int mi = 0; mi < 4; ++mi)
#pragma unroll
            for (int kk = 0; kk < 2; ++kk)
                af[mi][kk] = *reinterpret_cast<const bf16x8*>(
                    la + kk * 16384 + (mi * 32 + arow) * 64 + ga);
#pragma unroll
        for (int n = 0; n < 2; ++n)
#pragma unroll
            for (int kk = 0; kk < 2; ++kk)
                bfr[n][kk] = *reinterpret_cast<const bf16x8*>(
                    lb + kk * 16384 + (n * 64 + brow) * 64 + ga);
        stage(0, kt + 1, 1);
        __builtin_amdgcn_s_barrier();
        asm volatile("s_waitcnt lgkmcnt(0)" ::: "memory");
        __builtin_amdgcn_sched_barrier(0);
        __builtin_amdgcn_s_setprio(1);
#pragma unroll
        for (int mi = 0; mi < 4; ++mi)
#pragma unroll
            for (int n = 0; n < 2; ++n)
#pragma unroll
                for (int kk = 0; kk < 2; ++kk)
                    acc[mi][n] = __builtin_amdgcn_mfma_f32_16x16x32_bf16(
                        af[mi][kk], bfr[n][kk], acc[mi][n], 0, 0, 0);
        __builtin_amdgcn_s_setprio(0);
        __builtin_amdgcn_s_barrier();
        // phase 2: read B(n2,3); stage A0(kt+2); MFMA (mq0,nq1)
#pragma unroll
        for (int n = 2; n < 4; ++n)
#pragma unroll
            for (int kk = 0; kk < 2; ++kk)
                bfr[n][kk] = *reinterpret_cast<const bf16x8*>(
                    lb + kk * 16384 + (n * 64 + brow) * 64 + ga);
        stage(0, kt + 2, 0);
        __builtin_amdgcn_s_barrier();
        asm volatile("s_waitcnt lgkmcnt(0)" ::: "memory");
        __builtin_amdgcn_sched_barrier(0);
        __builtin_amdgcn_s_setprio(1);
#pragma unroll
        for (int mi = 0; mi < 4; ++mi)
#pragma unroll
            for (int n = 2; n < 4; ++n)
#pragma unroll
                for (int kk = 0; kk < 2; ++kk)
                    acc[mi][n] = __builtin_amdgcn_mfma_f32_16x16x32_bf16(
                        af[mi][kk], bfr[n][kk], acc[mi][n], 0, 0, 0);
        __builtin_amdgcn_s_setprio(0);
        __builtin_amdgcn_s_barrier();
        // phase 3: read A(mq1); stage B0(kt+2); MFMA (mq1,nq1)
#pragma unroll
        for (int mi = 0; mi < 4; ++mi)
#pragma unroll
            for (int kk = 0; kk < 2; ++kk)
                af[mi][kk] = *reinterpret_cast<const bf16x8*>(
                    la + kk * 16384 + ((mi + 4) * 32 + arow) * 64 + ga);
        stage(1, kt + 2, 0);
        __builtin_amdgcn_s_barrier();
        asm volatile("s_waitcnt lgkmcnt(0)" ::: "memory");
        __builtin_amdgcn_sched_barrier(0);
        __builtin_amdgcn_s_setprio(1);
#pragma unroll
        for (int mi = 0; mi < 4; ++mi)
#pragma unroll
            for (int n = 2; n < 4; ++n)
#pragma unroll
                for (int kk = 0; kk < 2; ++kk)
                    acc[mi + 4][n] = __builtin_amdgcn_mfma_f32_16x16x32_bf16(
                        af[mi][kk], bfr[n][kk], acc[mi + 4][n], 0, 0, 0);
        __builtin_amdgcn_s_setprio(0);
        __builtin_amdgcn_s_barrier();
        // phase 4: stage B1(kt+2); counted vmcnt; MFMA (mq1,nq0)
        stage(1, kt + 2, 1);
        if (kt < NT - 2) {
            asm volatile("s_waitcnt vmcnt(6)" ::: "memory");
        } else {
            asm volatile("s_waitcnt vmcnt(0)" ::: "memory");
        }
        __builtin_amdgcn_s_barrier();
        __builtin_amdgcn_s_setprio(1);
#pragma unroll
        for (int mi = 0; mi < 4; ++mi)
#pragma unroll
            for (int n = 0; n < 2; ++n)
#pragma unroll
                for (int kk = 0; kk < 2; ++kk)
                    acc[mi + 4][n] = __builtin_amdgcn_mfma_f32_16x16x32_bf16(
                        af[mi][kk], bfr[n][kk], acc[mi + 4][n], 0, 0, 0);
        __builtin_amdgcn_s_setprio(0);
        __builtin_amdgcn_s_barrier();
    }
    // epilogue: C/D map col=lane&15, row=(lane>>4)*4+reg
    if (MODE == 3 && bx >= 12) {
        int jb = (bx - 12) * 128;
#pragma unroll
        for (int m = 0; m < 8; ++m) {
            int crow = m0 + m * 32 + wr * 16 + g * 4;
#pragma unroll
            for (int n = 0; n < 2; ++n) {
                int ffcol = jb + n * 64 + wc * 16 + lr;
                f32x4 fv = acc[m][n];
                f32x4 gv = acc[m][n + 2];
#pragma unroll
                for (int r = 0; r < 4; ++r) {
                    float val = fv[r] * gelu_tanh(gv[r]);
                    Fb[(size_t)(crow + r) * AOW_ + ffcol] = __float2bfloat16(val);
                }
            }
        }
        return;
    }
    if (MODE == 3 && bx >= 8) {
        // V region: write transposed into vt[(b*16+head)*64+d][s]
#pragma unroll
        for (int m = 0; m < 8; ++m) {
            int crow = m0 + m * 32 + wr * 16 + g * 4;
            int b = crow >> 10, s = crow & 1023;
#pragma unroll
            for (int n = 0; n < 4; ++n) {
                int col = n0 + n * 64 + wc * 16 + lr;  // 2048..3071
                int head = (col - 2048) >> 6, d = col & 63;
                f32x4 v = acc[m][n];
                bf16x4 o;
#pragma unroll
                for (int r = 0; r < 4; ++r) o[r] = f2b(v[r]);
                *reinterpret_cast<bf16x4*>(
                    reinterpret_cast<short*>(Vt) +
                    ((size_t)(b * 16 + head) * 64 + d) * 1024 + s) = o;
            }
        }
        return;
    }
#pragma unroll
    for (int m = 0; m < 8; ++m) {
        int crow = m0 + m * 32 + wr * 16 + g * 4;
#pragma unroll
        for (int n = 0; n < 4; ++n) {
            int col = n0 + n * 64 + wc * 16 + lr;
            f32x4 v = acc[m][n];
#pragma unroll
            for (int r = 0; r < 4; ++r) {
                if (MODE == 3) Cb[(size_t)(crow + r) * PROJK_ + col] = __float2bfloat16(v[r]);
                else if (MODE == 0) Cf[(size_t)(crow + r) * N + col] = v[r];
                else if (MODE == 1) Cb[(size_t)(crow + r) * N + col] = __float2bfloat16(v[r]);
                else Cf[(size_t)(crow + r) * N + col] += v[r];
            }
        }
    }
}

// ---------------- MFMA flash attention ----------------------------------------
// 1-D grid 2048, XCD-grouped. Q,K from proj (stride 2048); V^T staged directly
// from vt (pre-transposed by gemm256). Output into ao cols 0..1023 (stride 5120).
__global__ __launch_bounds__(256, 2) void attn_kernel(
    const __hip_bfloat16* __restrict__ proj, const __hip_bfloat16* __restrict__ vt,
    __hip_bfloat16* __restrict__ ao) {
    __shared__ __align__(16) char ksm[64 * 128];
    __shared__ __align__(16) char vsm[64 * 128];
    __shared__ __align__(16) char psm[4 * 16 * 128];
    int wgid = blockIdx.x;
    int xcd = wgid & 7, slot = wgid >> 3;
    int group = xcd * 16 + (slot >> 4);
    int qt = slot & 15;
    int head = group & 15, b = group >> 4;
    int t = threadIdx.x;
    int lane = t & 63, w = t >> 6;
    int r = lane & 15, g = lane >> 4;
    int r7s = (r & 7) << 4;
    int q0 = qt * 64;
    int qcol = head * 64;
    const __hip_bfloat16* pb = proj + (size_t)b * S_ * PROJK_;
    const char* vtb = (const char*)(vt + ((size_t)(b * 16 + head) * 64) * 1024);
    bf16x8 qf[2];
#pragma unroll
    for (int kk = 0; kk < 2; ++kk)
        qf[kk] = *reinterpret_cast<const bf16x8*>(
            pb + (size_t)(q0 + w * 16 + r) * PROJK_ + qcol + kk * 32 + g * 8);
    int srow8 = lane >> 3;              // row within an 8-row staging chunk
    int sgrp = lane & 7;                // 16B group
    float m = -1e30f, l = 0.f;
    f32x4 o_acc[4] = {};
    char* pw = psm + w * 2048;
    for (int kt = 0; kt < 16; ++kt) {
        int k0 = kt * 64;
        // ---- stage K rows (swizzled src, linear LDS) ----
#pragma unroll
        for (int c = 0; c < 2; ++c) {
            int krow = w * 16 + c * 8 + srow8;
            const __hip_bfloat16* src =
                pb + (size_t)(k0 + krow) * PROJK_ + 1024 + qcol + ((sgrp ^ (krow & 7)) << 3);
            GLOAD16(src, ksm + (w * 16 + c * 8) * 128);
        }
        // ---- stage V^T rows d from vt (swizzled src, linear LDS) ----
#pragma unroll
        for (int c = 0; c < 2; ++c) {
            int drow = w * 16 + c * 8 + srow8;
            const char* src = vtb + (size_t)drow * 2048 + k0 * 2 + ((sgrp ^ (drow & 7)) << 4);
            GLOAD16(src, vsm + (w * 16 + c * 8) * 128);
        }
        __syncthreads();
        f32x4 st[4] = {};
        __builtin_amdgcn_s_setprio(1);
#pragma unroll
        for (int j = 0; j < 4; ++j) {
#pragma unroll
            for (int kk = 0; kk < 2; ++kk) {
                bf16x8 kf = *reinterpret_cast<const bf16x8*>(
                    ksm + (j * 16 + r) * 128 + ((((kk * 4 + g) << 4) ^ r7s)));
                st[j] = __builtin_amdgcn_mfma_f32_16x16x32_bf16(kf, qf[kk], st[j], 0, 0, 0);
            }
        }
        __builtin_amdgcn_s_setprio(0);
        float tmax = -1e30f;
#pragma unroll
        for (int j = 0; j < 4; ++j)
#pragma unroll
            for (int rr = 0; rr < 4; ++rr) {
                st[j][rr] *= 0.125f;
                tmax = fmaxf(tmax, st[j][rr]);
            }
        tmax = fmaxf(tmax, __shfl_xor(tmax, 16, 64));
        tmax = fmaxf(tmax, __shfl_xor(tmax, 32, 64));
        float mnew = fmaxf(m, tmax);
        float rsum = 0.f;
#pragma unroll
        for (int j = 0; j < 4; ++j)
#pragma unroll
            for (int rr = 0; rr < 4; ++rr) {
                float p = __expf(st[j][rr] - mnew);
                st[j][rr] = p;
                rsum += p;
            }
        rsum += __shfl_xor(rsum, 16, 64);
        rsum += __shfl_xor(rsum, 32, 64);
        float alpha = __expf(m - mnew);
        l = l * alpha + rsum;
        m = mnew;
#pragma unroll
        for (int j = 0; j < 4; ++j)
#pragma unroll
            for (int rr = 0; rr < 4; ++rr) {
                int kv2 = j * 32 + g * 8 + rr * 2;
                *reinterpret_cast<short*>(pw + r * 128 + (kv2 ^ r7s)) = f2b(st[j][rr]);
            }
        asm volatile("s_waitcnt lgkmcnt(0)" ::: "memory");
        __builtin_amdgcn_sched_barrier(0);
        float ar[4];
#pragma unroll
        for (int rr = 0; rr < 4; ++rr) ar[rr] = __shfl(alpha, g * 4 + rr, 64);
#pragma unroll
        for (int dt = 0; dt < 4; ++dt)
#pragma unroll
            for (int rr = 0; rr < 4; ++rr) o_acc[dt][rr] *= ar[rr];
        __builtin_amdgcn_s_setprio(1);
#pragma unroll
        for (int kk = 0; kk < 2; ++kk) {
            bf16x8 pf = *reinterpret_cast<const bf16x8*>(
                pw + r * 128 + ((((kk * 4 + g) << 4) ^ r7s)));
#pragma unroll
            for (int dt = 0; dt < 4; ++dt) {
                bf16x8 vf = *reinterpret_cast<const bf16x8*>(
                    vsm + (dt * 16 + r) * 128 + ((((kk * 4 + g) << 4) ^ r7s)));
                o_acc[dt] = __builtin_amdgcn_mfma_f32_16x16x32_bf16(pf, vf, o_acc[dt], 0, 0, 0);
            }
        }
        __builtin_amdgcn_s_setprio(0);
        __syncthreads();
    }
    float linv = 1.f / l;
    float lr4[4];
#pragma unroll
    for (int rr = 0; rr < 4; ++rr) lr4[rr] = __shfl(linv, g * 4 + rr, 64);
    short* ap = reinterpret_cast<short*>(ao);
#pragma unroll
    for (int dt = 0; dt < 4; ++dt)
#pragma unroll
        for (int rr = 0; rr < 4; ++rr) {
            size_t o = ((size_t)b * S_ + q0 + w * 16 + g * 4 + rr) * (size_t)AOW_ +
                       qcol + dt * 16 + r;
            ap[o] = f2b(o_acc[dt][rr] * lr4[rr]);
        }
}

extern "C" void kernel_launch(void* const* d_in, const int* in_sizes, int n_in,
                              void* d_out, int out_size, void* d_ws, size_t ws_size,
                              hipStream_t stream) {
    const float* inputs = (const float*)d_in[0];
    const float* time = (const float*)d_in[1];
    const float* in_W = (const float*)d_in[2];
    const float* in_b = (const float*)d_in[3];
    const float* out_W = (const float*)d_in[4];
    const float* out_b = (const float*)d_in[5];
    const float* t_W1 = (const float*)d_in[6];
    const float* t_b1 = (const float*)d_in[7];
    const float* t_W2 = (const float*)d_in[8];
    const float* t_b2 = (const float*)d_in[9];
    const float* ln_scale = (const float*)d_in[10];
    const float* ln_bias = (const float*)d_in[11];
    const float* proj_W = (const float*)d_in[12];
    const float* attn_W = (const float*)d_in[13];
    const float* ff_W = (const float*)d_in[14];
    float* out = (float*)d_out;

    float* ws = (float*)d_ws;
    size_t off = 0;
    float* temb0 = ws + off; off += 8 * 1024;
    float* tact = ws + off;  off += 8 * 4096;
    float* temb = ws + off;  off += 8 * 1024;
    float* pos = ws + off;   off += (size_t)S_ * D_;
    float* h = ws + off;     off += (size_t)BS_ * D_;
    __hip_bfloat16* u = (__hip_bfloat16*)(ws + off);      off += (size_t)BS_ * D_ / 2;
    __hip_bfloat16* proj = (__hip_bfloat16*)(ws + off);   off += (size_t)BS_ * PROJK_ / 2;
    __hip_bfloat16* vt = (__hip_bfloat16*)(ws + off);     off += (size_t)BS_ * D_ / 2;
    __hip_bfloat16* ao = (__hip_bfloat16*)(ws + off);     off += (size_t)BS_ * AOW_ / 2;
    __hip_bfloat16* hb = (__hip_bfloat16*)(ws + off);     off += (size_t)BS_ * D_ / 2;
    __hip_bfloat16* inbf = (__hip_bfloat16*)(ws + off);   off += (size_t)BS_ * (2 * E_) / 2;
    __hip_bfloat16* in_Wt = (__hip_bfloat16*)(ws + off);  off += (size_t)(2 * E_) * D_ / 2;
    __hip_bfloat16* out_Wt = (__hip_bfloat16*)(ws + off); off += (size_t)D_ * E_ / 2;
    __hip_bfloat16* Wpt = (__hip_bfloat16*)(ws + off);    off += (size_t)D_ * PROJN_ / 2;
    __hip_bfloat16* Waft = (__hip_bfloat16*)(ws + off);   off += (size_t)D_ * AOW_ / 2;

    dim3 blk(256);

    temb0_kernel<<<B_, 512, 0, stream>>>(time, temb0);
    tmlp_kernel<<<TDIM_ / 16, blk, 0, stream>>>(temb0, t_W1, t_b1, tact, D_, TDIM_);
    tmlp_kernel<<<D_ / 16, blk, 0, stream>>>(tact, t_W2, t_b2, temb, TDIM_, D_);
    pos_kernel<<<S_, 512, 0, stream>>>(pos);
    f2b4_kernel<<<(BS_ * 2 * E_) / 1024, blk, 0, stream>>>(inputs, inbf);
    convT_kernel<<<dim3(D_ / 64, (2 * E_) / 64), blk, 0, stream>>>(
        in_W, in_Wt, 2 * E_, D_, 2 * E_, 0);
    convT_kernel<<<dim3(E_ / 64, D_ / 64), blk, 0, stream>>>(
        out_W, out_Wt, D_, E_, D_, 0);
    // input projection + bias + pos + temb fused
    mfma_gemm<0, 1, 1><<<dim3(D_ / 128, BS_ / 128), blk, 0, stream>>>(
        inbf, in_Wt, in_b, h, nullptr, pos, temb, BS_, D_, 2 * E_);

    for (int l = 0; l < L_; ++l) {
        const float* Wp = proj_W + (size_t)l * D_ * PROJN_;
        const float* Wa = attn_W + (size_t)l * (H_ * DH_) * D_;
        const float* Wf = ff_W + (size_t)l * FF_ * D_;
        convT3_kernel<<<dim3(4096), blk, 0, stream>>>(Wp, Wa, Wf, Wpt, Waft);
        ln_kernel<<<BS_, blk, 0, stream>>>(h, ln_scale + l * D_, ln_bias + l * D_, u);
        gemm256<3><<<dim3(PROJN_ / 256, BS_ / 256), dim3(512), 0, stream>>>(
            u, Wpt, nullptr, proj, ao + D_, vt, BS_, PROJN_, D_);
        attn_kernel<<<dim3(2048), blk, 0, stream>>>(proj, vt, ao);
        mfma_gemm<2, 0, 0><<<dim3(D_ / 128, BS_ / 128), blk, 0, stream>>>(
            ao, Waft, nullptr, h, nullptr, nullptr, nullptr, BS_, D_, AOW_);
    }
    f2b4_kernel<<<(BS_ * D_) / 1024, blk, 0, stream>>>(h, hb);
    mfma_gemm<0, 1, 0><<<dim3(E_ / 128, BS_ / 128), blk, 0, stream>>>(
        hb, out_Wt, out_b, out, nullptr, nullptr, nullptr, BS_, E_, D_);
}

// Round 9
// 4891.046 us; speedup vs baseline: 17.6457x; 1.1023x over previous
//
#include <hip/hip_runtime.h>
#include <hip/hip_bf16.h>
#include <math.h>

// Problem constants
static constexpr int B_ = 8, S_ = 1024, E_ = 256, D_ = 1024, H_ = 16, DH_ = 64,
                     FF_ = 4096, L_ = 12, TDIM_ = 4096;
static constexpr int BS_ = B_ * S_;                    // 8192 rows
static constexpr int PROJN_ = 3 * H_ * DH_ + 2 * FF_;  // 11264
static constexpr int PROJK_ = 2 * H_ * DH_;            // 2048 (q,k only in proj buf)
static constexpr int AOW_ = H_ * DH_ + FF_;            // 5120 (attn | ffg)

typedef __attribute__((ext_vector_type(8))) short bf16x8;
typedef __attribute__((ext_vector_type(4))) short bf16x4;
typedef __attribute__((ext_vector_type(4))) float f32x4;

__device__ __forceinline__ float b2f(short b) {
    return __uint_as_float(((unsigned)(unsigned short)b) << 16);
}
__device__ __forceinline__ short f2b(float f) {
    __hip_bfloat16 h = __float2bfloat16(f);
    return *reinterpret_cast<short*>(&h);
}
__device__ __forceinline__ float gelu_exact(float x) {
    return 0.5f * x * (1.f + erff(x * 0.70710678118654752440f));
}
__device__ __forceinline__ float gelu_tanh(float x) {
    // x*0.5*(1+tanh(u)) == x*sigmoid(2u), u = 0.79788456*(x + 0.044715 x^3)
    float u2 = 1.59576912160573070f * (x + 0.044715f * x * x * x);
    return x / (1.f + __expf(-u2));
}

#define GLOAD16(g, l)                                                     \
    __builtin_amdgcn_global_load_lds(                                     \
        (const __attribute__((address_space(1))) void*)(g),               \
        (__attribute__((address_space(3))) void*)(l), 16, 0, 0)

// ---------------- time embedding base: temb0[b] = [sin(ts), cos(ts)] -----------
__global__ void temb0_kernel(const float* __restrict__ time, float* __restrict__ temb0) {
    int b = blockIdx.x;
    int i = threadIdx.x;  // 0..511
    float inv_ts = expf((float)i * (-logf(10000.f) / 511.f));  // half-1 = 511
    float ts = time[b] * inv_ts;
    temb0[b * D_ + i] = sinf(ts);
    temb0[b * D_ + 512 + i] = cosf(ts);
}

// ---------------- fixed positional embedding ----------------------------------
__global__ void pos_kernel(float* __restrict__ pos) {
    int s = blockIdx.x;
    int j = threadIdx.x;  // 0..511
    float inv_freq = expf((float)j * (-logf(10000.f) / 512.f));  // 2j/D = j/512
    float arg = (float)s * inv_freq;
    pos[s * D_ + j] = sinf(arg);
    pos[s * D_ + 512 + j] = cosf(arg);
}

// ---------------- tiny-M GEMM + exact GELU: C[8][N] = gelu(A[8][K]@B + bias) ---
__global__ void tmlp_kernel(const float* __restrict__ A, const float* __restrict__ Bw,
                            const float* __restrict__ bias, float* __restrict__ C,
                            int K, int N) {
    __shared__ float Ast[8][256];
    __shared__ float red2[16][16][9];
    int t = threadIdx.x;
    int col = t & 15, ks = t >> 4;
    int n = blockIdx.x * 16 + col;
    float acc[8];
#pragma unroll
    for (int b = 0; b < 8; ++b) acc[b] = 0.f;
    for (int c0 = 0; c0 < K; c0 += 256) {
#pragma unroll
        for (int i = 0; i < 8; ++i) {
            int idx = t + i * 256;
            Ast[idx >> 8][idx & 255] = A[(idx >> 8) * K + c0 + (idx & 255)];
        }
        __syncthreads();
#pragma unroll
        for (int i = 0; i < 16; ++i) {
            int k = ks * 16 + i;
            float w = Bw[(size_t)(c0 + k) * N + n];
#pragma unroll
            for (int b = 0; b < 8; ++b) acc[b] = fmaf(Ast[b][k], w, acc[b]);
        }
        __syncthreads();
    }
#pragma unroll
    for (int b = 0; b < 8; ++b) red2[ks][col][b] = acc[b];
    __syncthreads();
    if (t < 128) {
        int c2 = t >> 3, b = t & 7;
        float s = 0.f;
#pragma unroll
        for (int k2 = 0; k2 < 16; ++k2) s += red2[k2][c2][b];
        int nn = blockIdx.x * 16 + c2;
        C[(size_t)b * N + nn] = gelu_exact(s + bias[nn]);
    }
}

// ---------------- fp32 -> bf16 elementwise (n multiple of 1024) ---------------
__global__ void f2b4_kernel(const float* __restrict__ in, __hip_bfloat16* __restrict__ out) {
    size_t i = ((size_t)blockIdx.x * 256 + threadIdx.x) * 4;
    float4 v = *reinterpret_cast<const float4*>(in + i);
    bf16x4 o;
    o[0] = f2b(v.x); o[1] = f2b(v.y); o[2] = f2b(v.z); o[3] = f2b(v.w);
    *reinterpret_cast<bf16x4*>(reinterpret_cast<short*>(out) + i) = o;
}

// ---------------- transpose+convert body: W[K][N] fp32 -> Wt[row'(n)][k] bf16 --
__device__ __forceinline__ void convT_body(const float* __restrict__ W,
                                           __hip_bfloat16* __restrict__ Wt,
                                           int K, int N, int outStride, int colOff,
                                           int perm, int bx, int by) {
    __shared__ float tile[64][65];
    int t = threadIdx.x;
    int n0 = bx * 64, k0 = by * 64;
#pragma unroll
    for (int i = 0; i < 4; ++i) {
        int idx = t + i * 256;
        int row = idx >> 4, c4 = (idx & 15) * 4;
        float4 v = *reinterpret_cast<const float4*>(W + (size_t)(k0 + row) * N + n0 + c4);
        tile[row][c4 + 0] = v.x; tile[row][c4 + 1] = v.y;
        tile[row][c4 + 2] = v.z; tile[row][c4 + 3] = v.w;
    }
    __syncthreads();
#pragma unroll
    for (int i = 0; i < 4; ++i) {
        int idx = t + i * 256;
        int n = idx >> 4, k4 = (idx & 15) * 4;
        int ng = n0 + n;
        size_t orow;
        if (perm) {
            // ff/gate interleave for fused proj epilogue
            if (ng < 3072) orow = ng;
            else if (ng < 7168) { int j = ng - 3072; orow = 3072 + (j >> 7) * 256 + (j & 127); }
            else { int j = ng - 7168; orow = 3072 + (j >> 7) * 256 + 128 + (j & 127); }
        } else {
            orow = ng;
        }
        bf16x4 o;
#pragma unroll
        for (int j = 0; j < 4; ++j) o[j] = f2b(tile[k4 + j][n]);
        *reinterpret_cast<bf16x4*>(reinterpret_cast<short*>(Wt) + orow * outStride + colOff + k0 + k4) = o;
    }
}

__global__ void convT_kernel(const float* __restrict__ W, __hip_bfloat16* __restrict__ Wt,
                             int K, int N, int outStride, int colOff) {
    convT_body(W, Wt, K, N, outStride, colOff, 0, blockIdx.x, blockIdx.y);
}

// ---------------- batched per-layer weight conversion (Wp perm + Wa + Wf) -----
// 1-D grid 4096: [0,2816) Wp (176x16), [2816,3072) Wa (16x16), [3072,4096) Wf (16x64)
__global__ void convT3_kernel(const float* __restrict__ Wp, const float* __restrict__ Wa,
                              const float* __restrict__ Wf, __hip_bfloat16* __restrict__ Wpt,
                              __hip_bfloat16* __restrict__ Waft) {
    int bid = blockIdx.x;
    if (bid < 2816) {
        convT_body(Wp, Wpt, D_, PROJN_, D_, 0, 1, bid % 176, bid / 176);
    } else if (bid < 3072) {
        int i2 = bid - 2816;
        convT_body(Wa, Waft, D_, D_, AOW_, 0, 0, i2 & 15, i2 >> 4);
    } else {
        int i2 = bid - 3072;
        convT_body(Wf, Waft, FF_, D_, AOW_, D_, 0, i2 & 15, i2 >> 4);
    }
}

// ---------------- LayerNorm: u = bf16((h-m)*rsqrt(v+eps)*g + b) ---------------
__global__ void ln_kernel(const float* __restrict__ h, const float* __restrict__ g,
                          const float* __restrict__ bb, __hip_bfloat16* __restrict__ u) {
    int row = blockIdx.x;
    int t = threadIdx.x;
    const float4 v = reinterpret_cast<const float4*>(h + (size_t)row * D_)[t];
    __shared__ float red[8];
    float s = v.x + v.y + v.z + v.w;
    for (int m8 = 1; m8 < 64; m8 <<= 1) s += __shfl_xor(s, m8, 64);
    if ((t & 63) == 0) red[t >> 6] = s;
    __syncthreads();
    float mean = (red[0] + red[1] + red[2] + red[3]) * (1.f / 1024.f);
    float dx = v.x - mean, dy = v.y - mean, dz = v.z - mean, dw = v.w - mean;
    float sq = dx * dx + dy * dy + dz * dz + dw * dw;
    for (int m8 = 1; m8 < 64; m8 <<= 1) sq += __shfl_xor(sq, m8, 64);
    if ((t & 63) == 0) red[4 + (t >> 6)] = sq;
    __syncthreads();
    float var = (red[4] + red[5] + red[6] + red[7]) * (1.f / 1024.f);
    float inv = rsqrtf(var + 1e-5f);
    int c = t * 4;
    bf16x4 o;
    o[0] = f2b(dx * inv * g[c + 0] + bb[c + 0]);
    o[1] = f2b(dy * inv * g[c + 1] + bb[c + 1]);
    o[2] = f2b(dz * inv * g[c + 2] + bb[c + 2]);
    o[3] = f2b(dw * inv * g[c + 3] + bb[c + 3]);
    *reinterpret_cast<bf16x4*>(reinterpret_cast<short*>(u) + (size_t)row * D_ + c) = o;
}

// ---------------- MFMA bf16 GEMM, m97 structure (generic) ---------------------
// C[M][N] = A[M][K] @ Bt[N][K]^T.  128x128 tile, BK=32, 256 thr (4 waves 2x2).
// ADDPE: epilogue adds pos[s][col] + temb[b][col] (input GEMM fusion).
template <int MODE, int BIAS, int ADDPE>
__global__ __launch_bounds__(256) void mfma_gemm(
    const __hip_bfloat16* __restrict__ A, const __hip_bfloat16* __restrict__ Bt,
    const float* __restrict__ bias, float* __restrict__ Cf,
    __hip_bfloat16* __restrict__ Cb, const float* __restrict__ pe_pos,
    const float* __restrict__ pe_temb, int M, int N, int K) {
    __shared__ __align__(16) char As[128 * 64];
    __shared__ __align__(16) char Bs[128 * 64];
    int t = threadIdx.x;
    int lane = t & 63, wid = t >> 6;
    int m0 = blockIdx.y * 128, n0 = blockIdx.x * 128;
    size_t rowb = (size_t)K * 2;
    int srow = wid * 32 + (lane >> 2);
    int scol = (lane & 3) * 16;
    const char* ag0 = (const char*)A + (size_t)(m0 + srow) * rowb + scol;
    const char* ag1 = (const char*)A + (size_t)(m0 + srow + 16) * rowb + scol;
    const char* bg0 = (const char*)Bt + (size_t)(n0 + srow) * rowb + scol;
    const char* bg1 = (const char*)Bt + (size_t)(n0 + srow + 16) * rowb + scol;
    int lb0 = wid * 32 * 64;
    int lb1 = lb0 + 16 * 64;
    int wr = (wid >> 1) * 64, wc = (wid & 1) * 64;
    int lr = lane & 15;
    int a_base = (wr + lr) * 64 + (lane >> 4) * 16;
    int b_base = (wc + lr) * 64 + (lane >> 4) * 16;
    f32x4 acc[4][4] = {};
    int nkt = K >> 5;
    for (int kt = 0; kt < nkt; ++kt) {
        GLOAD16(ag0, As + lb0);
        GLOAD16(ag1, As + lb1);
        GLOAD16(bg0, Bs + lb0);
        GLOAD16(bg1, Bs + lb1);
        ag0 += 64; ag1 += 64; bg0 += 64; bg1 += 64;
        __syncthreads();
        bf16x8 af[4], bf[4];
#pragma unroll
        for (int f = 0; f < 4; ++f) {
            af[f] = *reinterpret_cast<const bf16x8*>(As + a_base + f * 1024);
            bf[f] = *reinterpret_cast<const bf16x8*>(Bs + b_base + f * 1024);
        }
        __builtin_amdgcn_s_setprio(1);
#pragma unroll
        for (int i = 0; i < 4; ++i)
#pragma unroll
            for (int j = 0; j < 4; ++j)
                acc[i][j] = __builtin_amdgcn_mfma_f32_16x16x32_bf16(af[i], bf[j], acc[i][j], 0, 0, 0);
        __builtin_amdgcn_s_setprio(0);
        __syncthreads();
    }
    int crow0 = m0 + wr + (lane >> 4) * 4;
    int ccol0 = n0 + wc + lr;
#pragma unroll
    for (int i = 0; i < 4; ++i) {
#pragma unroll
        for (int j = 0; j < 4; ++j) {
            int col = ccol0 + j * 16;
            float bv = BIAS ? bias[col] : 0.f;
            f32x4 v = acc[i][j];
#pragma unroll
            for (int r = 0; r < 4; ++r) {
                int row = crow0 + i * 16 + r;
                size_t o = (size_t)row * N + col;
                float val = v[r] + bv;
                if (ADDPE)
                    val += pe_pos[(size_t)(row & 1023) * D_ + col] +
                           pe_temb[(size_t)(row >> 10) * D_ + col];
                if (MODE == 0) Cf[o] = val;
                else if (MODE == 1) Cb[o] = __float2bfloat16(val);
                else Cf[o] += val;
            }
        }
    }
}

// ---------------- 8-phase 256x256 MFMA GEMM; MODE 3 = fused proj+ffg ----------
// A[M][K] @ Bt[N][K]^T with Bt rows permuted (convT perm). Block tiles (bx):
//   0..7:  q,k -> proj bf16 (stride 2048)
//   8..11: v   -> vt bf16 TRANSPOSED: vt[(b*16+head)*64+d][s]
//   12..43: cols 0..127 = ff, 128..255 = paired gate -> ff*gelu(gate) into Fb
// XCD-swizzled block order (nwg % 8 == 0).
template <int MODE>
__global__ __launch_bounds__(512, 2) void gemm256(
    const __hip_bfloat16* __restrict__ A, const __hip_bfloat16* __restrict__ Bt,
    float* __restrict__ Cf, __hip_bfloat16* __restrict__ Cb,
    __hip_bfloat16* __restrict__ Fb, __hip_bfloat16* __restrict__ Vt,
    int M, int N, int K) {
    __shared__ __align__(16) char lds[131072];
    const int t = threadIdx.x;
    const int lane = t & 63, wid = t >> 6;
    const int lr = lane & 15, g = lane >> 4;
    const int wr = wid >> 2, wc = wid & 3;
    const int nbx = gridDim.x;
    const int nwg = nbx * gridDim.y;
    const int bid = blockIdx.y * nbx + blockIdx.x;
    const int swz = (bid & 7) * (nwg >> 3) + (bid >> 3);
    const int bx = swz % nbx, by = swz / nbx;
    const int m0 = by * 256, n0 = bx * 256;
    const size_t rowb = (size_t)K * 2;
    const int NT = K >> 6;
    const int srow = lane >> 2;
    const int scol = ((lane & 3) ^ (((lane >> 5) & 1) << 1)) * 16;  // src-side swizzle
    const int ga = (g ^ (((lr >> 3) & 1) << 1)) * 16;               // read-side swizzle
    const int arow = wr * 16 + lr;
    const int brow = wc * 16 + lr;
    const char* Ab = (const char*)A;
    const char* Bb = (const char*)Bt;

    auto stage = [&](int mat, int kt, int hh) {
        if (kt >= NT) return;
        int rbase = (mat ? n0 : m0) + hh * 128 + wid * 16 + srow;
        const char* src = (mat ? Bb : Ab) + (size_t)rbase * rowb + (size_t)kt * 128 + scol;
        char* dst = lds + mat * 65536 + (kt & 1) * 32768 + (hh * 128 + wid * 16) * 64;
        GLOAD16(src, dst);
        GLOAD16(src + 64, dst + 16384);
    };

    f32x4 acc[8][4] = {};
    bf16x8 af[4][2], bfr[4][2];

    stage(0, 0, 0); stage(0, 0, 1); stage(1, 0, 0); stage(1, 0, 1);
    stage(0, 1, 0); stage(1, 1, 0); stage(1, 1, 1);
    asm volatile("s_waitcnt vmcnt(6)" ::: "memory");
    __builtin_amdgcn_s_barrier();

    for (int kt = 0; kt < NT; ++kt) {
        const int p = kt & 1;
        const char* la = lds + p * 32768;
        const char* lb = lds + 65536 + p * 32768;
        // phase 1: read A(mq0, rows 0..127)+B(n0,1); stage A1(kt+1); MFMA (mq0,nq0)
#pragma unroll
        for (int mi = 0; mi < 4; ++mi)
#pragma unroll
            for (int kk = 0; kk < 2; ++kk)
                af[mi][kk] = *reinterpret_cast<const bf16x8*>(
                    la + kk * 16384 + (mi * 32 + arow) * 64 + ga);
#pragma unroll
        for (int n = 0; n < 2; ++n)
#pragma unroll
            for (int kk = 0; kk < 2; ++kk)
                bfr[n][kk] = *reinterpret_cast<const bf16x8*>(
                    lb + kk * 16384 + (n * 64 + brow) * 64 + ga);
        stage(0, kt + 1, 1);
        __builtin_amdgcn_s_barrier();
        asm volatile("s_waitcnt lgkmcnt(0)" ::: "memory");
        __builtin_amdgcn_sched_barrier(0);
        __builtin_amdgcn_s_setprio(1);
#pragma unroll
        for (int mi = 0; mi < 4; ++mi)
#pragma unroll
            for (int n = 0; n < 2; ++n)
#pragma unroll
                for (int kk = 0; kk < 2; ++kk)
                    acc[mi][n] = __builtin_amdgcn_mfma_f32_16x16x32_bf16(
                        af[mi][kk], bfr[n][kk], acc[mi][n], 0, 0, 0);
        __builtin_amdgcn_s_setprio(0);
        __builtin_amdgcn_s_barrier();
        // phase 2: read B(n2,3); stage A0(kt+2); MFMA (mq0,nq1)
#pragma unroll
        for (int n = 2; n < 4; ++n)
#pragma unroll
            for (int kk = 0; kk < 2; ++kk)
                bfr[n][kk] = *reinterpret_cast<const bf16x8*>(
                    lb + kk * 16384 + (n * 64 + brow) * 64 + ga);
        stage(0, kt + 2, 0);
        __builtin_amdgcn_s_barrier();
        asm volatile("s_waitcnt lgkmcnt(0)" ::: "memory");
        __builtin_amdgcn_sched_barrier(0);
        __builtin_amdgcn_s_setprio(1);
#pragma unroll
        for (int mi = 0; mi < 4; ++mi)
#pragma unroll
            for (int n = 2; n < 4; ++n)
#pragma unroll
                for (int kk = 0; kk < 2; ++kk)
                    acc[mi][n] = __builtin_amdgcn_mfma_f32_16x16x32_bf16(
                        af[mi][kk], bfr[n][kk], acc[mi][n], 0, 0, 0);
        __builtin_amdgcn_s_setprio(0);
        __builtin_amdgcn_s_barrier();
        // phase 3: read A(mq1, rows 128..255); stage B0(kt+2); MFMA (mq1,nq1)
#pragma unroll
        for (int mi = 0; mi < 4; ++mi)
#pragma unroll
            for (int kk = 0; kk < 2; ++kk)
                af[mi][kk] = *reinterpret_cast<const bf16x8*>(
                    la + kk * 16384 + ((mi + 4) * 32 + arow) * 64 + ga);
        stage(1, kt + 2, 0);
        __builtin_amdgcn_s_barrier();
        asm volatile("s_waitcnt lgkmcnt(0)" ::: "memory");
        __builtin_amdgcn_sched_barrier(0);
        __builtin_amdgcn_s_setprio(1);
#pragma unroll
        for (int mi = 0; mi < 4; ++mi)
#pragma unroll
            for (int n = 2; n < 4; ++n)
#pragma unroll
                for (int kk = 0; kk < 2; ++kk)
                    acc[mi + 4][n] = __builtin_amdgcn_mfma_f32_16x16x32_bf16(
                        af[mi][kk], bfr[n][kk], acc[mi + 4][n], 0, 0, 0);
        __builtin_amdgcn_s_setprio(0);
        __builtin_amdgcn_s_barrier();
        // phase 4: stage B1(kt+2); counted vmcnt; MFMA (mq1,nq0)
        stage(1, kt + 2, 1);
        if (kt < NT - 2) {
            asm volatile("s_waitcnt vmcnt(6)" ::: "memory");
        } else {
            asm volatile("s_waitcnt vmcnt(0)" ::: "memory");
        }
        __builtin_amdgcn_s_barrier();
        __builtin_amdgcn_s_setprio(1);
#pragma unroll
        for (int mi = 0; mi < 4; ++mi)
#pragma unroll
            for (int n = 0; n < 2; ++n)
#pragma unroll
                for (int kk = 0; kk < 2; ++kk)
                    acc[mi + 4][n] = __builtin_amdgcn_mfma_f32_16x16x32_bf16(
                        af[mi][kk], bfr[n][kk], acc[mi + 4][n], 0, 0, 0);
        __builtin_amdgcn_s_setprio(0);
        __builtin_amdgcn_s_barrier();
    }
    // epilogue: C/D map col=lane&15, row=(lane>>4)*4+reg
    if (MODE == 3 && bx >= 12) {
        int jb = (bx - 12) * 128;
#pragma unroll
        for (int m = 0; m < 8; ++m) {
            int crow = m0 + m * 32 + wr * 16 + g * 4;
#pragma unroll
            for (int n = 0; n < 2; ++n) {
                int ffcol = jb + n * 64 + wc * 16 + lr;
                f32x4 fv = acc[m][n];
                f32x4 gv = acc[m][n + 2];
#pragma unroll
                for (int r = 0; r < 4; ++r) {
                    float val = fv[r] * gelu_tanh(gv[r]);
                    Fb[(size_t)(crow + r) * AOW_ + ffcol] = __float2bfloat16(val);
                }
            }
        }
        return;
    }
    if (MODE == 3 && bx >= 8) {
        // V region: write transposed into vt[(b*16+head)*64+d][s]
#pragma unroll
        for (int m = 0; m < 8; ++m) {
            int crow = m0 + m * 32 + wr * 16 + g * 4;
            int b = crow >> 10, s = crow & 1023;
#pragma unroll
            for (int n = 0; n < 4; ++n) {
                int col = n0 + n * 64 + wc * 16 + lr;  // 2048..3071
                int head = (col - 2048) >> 6, d = col & 63;
                f32x4 v = acc[m][n];
                bf16x4 o;
#pragma unroll
                for (int r = 0; r < 4; ++r) o[r] = f2b(v[r]);
                *reinterpret_cast<bf16x4*>(
                    reinterpret_cast<short*>(Vt) +
                    ((size_t)(b * 16 + head) * 64 + d) * 1024 + s) = o;
            }
        }
        return;
    }
#pragma unroll
    for (int m = 0; m < 8; ++m) {
        int crow = m0 + m * 32 + wr * 16 + g * 4;
#pragma unroll
        for (int n = 0; n < 4; ++n) {
            int col = n0 + n * 64 + wc * 16 + lr;
            f32x4 v = acc[m][n];
#pragma unroll
            for (int r = 0; r < 4; ++r) {
                if (MODE == 3) Cb[(size_t)(crow + r) * PROJK_ + col] = __float2bfloat16(v[r]);
                else if (MODE == 0) Cf[(size_t)(crow + r) * N + col] = v[r];
                else if (MODE == 1) Cb[(size_t)(crow + r) * N + col] = __float2bfloat16(v[r]);
                else Cf[(size_t)(crow + r) * N + col] += v[r];
            }
        }
    }
}

// ---------------- 8-phase 256(M)x128(N) MFMA GEMM: Cf[M][N] += A@Bt^T ---------
// FIXED mapping (r8 bug): M-rows interleaved as mq*64 + wr*16 + lr so phase 1
// reads ONLY rows 0..127 (A0) and phase 3 ONLY 128..255 (A1) -> stage A0(kt+2)
// in phase 2 never collides with pending reads (gemm256 invariant restored).
// 512 thr = 8 waves (4M x 2N). LDS 96 KiB: A [par][kk][256][64B] (64K),
// B at +65536 [par][kk][128][64B] (32K). vmcnt(4) counted. XCD swizzle.
// EMITB: also write Cb = bf16(updated C) (final layer).
template <int EMITB>
__global__ __launch_bounds__(512, 1) void gemm256b(
    const __hip_bfloat16* __restrict__ A, const __hip_bfloat16* __restrict__ Bt,
    float* __restrict__ Cf, __hip_bfloat16* __restrict__ Cb, int M, int N, int K) {
    __shared__ __align__(16) char lds[98304];
    const int t = threadIdx.x;
    const int lane = t & 63, wid = t >> 6;
    const int lr = lane & 15, g = lane >> 4;
    const int wr = wid >> 1, wc = wid & 1;
    const int nbx = gridDim.x;
    const int nwg = nbx * gridDim.y;
    const int bid = blockIdx.y * nbx + blockIdx.x;
    const int swz = (bid & 7) * (nwg >> 3) + (bid >> 3);
    const int bx = swz % nbx, by = swz / nbx;
    const int m0 = by * 256, n0 = bx * 128;
    const size_t rowb = (size_t)K * 2;
    const int NT = K >> 6;
    const int srow = lane >> 2;
    const int scol = ((lane & 3) ^ (((lane >> 5) & 1) << 1)) * 16;  // src-side swizzle
    const int ga = (g ^ (((lr >> 3) & 1) << 1)) * 16;               // read-side swizzle

    auto stageA = [&](int kt, int hh) {
        if (kt >= NT) return;
        int rowg = hh * 128 + wid * 16 + srow;
        const char* src = (const char*)A + (size_t)(m0 + rowg) * rowb + (size_t)kt * 128 + scol;
        char* dst = lds + (kt & 1) * 32768 + (hh * 128 + wid * 16) * 64;  // wave-uniform
        GLOAD16(src, dst);               // kk0 panel
        GLOAD16(src + 64, dst + 16384);  // kk1 panel
    };
    auto stageB = [&](int kt) {
        if (kt >= NT) return;
        int rowg = wid * 16 + srow;  // 0..127
        const char* src = (const char*)Bt + (size_t)(n0 + rowg) * rowb + (size_t)kt * 128 + scol;
        char* dst = lds + 65536 + (kt & 1) * 16384 + (wid * 16) * 64;  // wave-uniform
        GLOAD16(src, dst);
        GLOAD16(src + 64, dst + 8192);
    };

    f32x4 acc[4][4] = {};
    bf16x8 af[2][2], bfr[4][2];

    // prologue: kt0 {A0,A1,B} + kt1 {A0,B}; confirm kt0 (6 oldest of 10)
    stageA(0, 0); stageA(0, 1); stageB(0);
    stageA(1, 0); stageB(1);
    asm volatile("s_waitcnt vmcnt(4)" ::: "memory");
    __builtin_amdgcn_s_barrier();

    for (int kt = 0; kt < NT; ++kt) {
        const int p = kt & 1;
        const char* la = lds + p * 32768;
        const char* lb = lds + 65536 + p * 16384;
        // phase 1: read A(mq0,1: rows 0..127)+B(nq0,1); stage A1(kt+1); MFMA
#pragma unroll
        for (int mi = 0; mi < 2; ++mi)
#pragma unroll
            for (int kk = 0; kk < 2; ++kk)
                af[mi][kk] = *reinterpret_cast<const bf16x8*>(
                    la + kk * 16384 + (mi * 64 + wr * 16 + lr) * 64 + ga);
#pragma unroll
        for (int n = 0; n < 2; ++n)
#pragma unroll
            for (int kk = 0; kk < 2; ++kk)
                bfr[n][kk] = *reinterpret_cast<const bf16x8*>(
                    lb + kk * 8192 + (wc * 64 + n * 16 + lr) * 64 + ga);
        stageA(kt + 1, 1);
        __builtin_amdgcn_s_barrier();
        asm volatile("s_waitcnt lgkmcnt(0)" ::: "memory");
        __builtin_amdgcn_sched_barrier(0);
        __builtin_amdgcn_s_setprio(1);
#pragma unroll
        for (int mi = 0; mi < 2; ++mi)
#pragma unroll
            for (int n = 0; n < 2; ++n)
#pragma unroll
                for (int kk = 0; kk < 2; ++kk)
                    acc[mi][n] = __builtin_amdgcn_mfma_f32_16x16x32_bf16(
                        af[mi][kk], bfr[n][kk], acc[mi][n], 0, 0, 0);
        __builtin_amdgcn_s_setprio(0);
        __builtin_amdgcn_s_barrier();
        // phase 2: read B(nq2,3); stage A0(kt+2); MFMA mq01 x nq23
#pragma unroll
        for (int n = 2; n < 4; ++n)
#pragma unroll
            for (int kk = 0; kk < 2; ++kk)
                bfr[n][kk] = *reinterpret_cast<const bf16x8*>(
                    lb + kk * 8192 + (wc * 64 + n * 16 + lr) * 64 + ga);
        stageA(kt + 2, 0);
        __builtin_amdgcn_s_barrier();
        asm volatile("s_waitcnt lgkmcnt(0)" ::: "memory");
        __builtin_amdgcn_sched_barrier(0);
        __builtin_amdgcn_s_setprio(1);
#pragma unroll
        for (int mi = 0; mi < 2; ++mi)
#pragma unroll
            for (int n = 2; n < 4; ++n)
#pragma unroll
                for (int kk = 0; kk < 2; ++kk)
                    acc[mi][n] = __builtin_amdgcn_mfma_f32_16x16x32_bf16(
                        af[mi][kk], bfr[n][kk], acc[mi][n], 0, 0, 0);
        __builtin_amdgcn_s_setprio(0);
        __builtin_amdgcn_s_barrier();
        // phase 3: read A(mq2,3: rows 128..255); stage B(kt+2); MFMA mq23 x nq23
#pragma unroll
        for (int mi = 0; mi < 2; ++mi)
#pragma unroll
            for (int kk = 0; kk < 2; ++kk)
                af[mi][kk] = *reinterpret_cast<const bf16x8*>(
                    la + kk * 16384 + ((mi + 2) * 64 + wr * 16 + lr) * 64 + ga);
        stageB(kt + 2);
        __builtin_amdgcn_s_barrier();
        asm volatile("s_waitcnt lgkmcnt(0)" ::: "memory");
        __builtin_amdgcn_sched_barrier(0);
        __builtin_amdgcn_s_setprio(1);
#pragma unroll
        for (int mi = 0; mi < 2; ++mi)
#pragma unroll
            for (int n = 2; n < 4; ++n)
#pragma unroll
                for (int kk = 0; kk < 2; ++kk)
                    acc[mi + 2][n] = __builtin_amdgcn_mfma_f32_16x16x32_bf16(
                        af[mi][kk], bfr[n][kk], acc[mi + 2][n], 0, 0, 0);
        __builtin_amdgcn_s_setprio(0);
        __builtin_amdgcn_s_barrier();
        // phase 4: counted vmcnt; MFMA mq23 x nq01
        if (kt < NT - 2) {
            asm volatile("s_waitcnt vmcnt(4)" ::: "memory");
        } else {
            asm volatile("s_waitcnt vmcnt(0)" ::: "memory");
        }
        __builtin_amdgcn_s_barrier();
        __builtin_amdgcn_s_setprio(1);
#pragma unroll
        for (int mi = 0; mi < 2; ++mi)
#pragma unroll
            for (int n = 0; n < 2; ++n)
#pragma unroll
                for (int kk = 0; kk < 2; ++kk)
                    acc[mi + 2][n] = __builtin_amdgcn_mfma_f32_16x16x32_bf16(
                        af[mi][kk], bfr[n][kk], acc[mi + 2][n], 0, 0, 0);
        __builtin_amdgcn_s_setprio(0);
        __builtin_amdgcn_s_barrier();
    }
    // epilogue: Cf += acc  (C/D map col=lane&15, row=(lane>>4)*4+reg)
#pragma unroll
    for (int mq = 0; mq < 4; ++mq) {
        int crow = m0 + mq * 64 + wr * 16 + g * 4;
#pragma unroll
        for (int nq = 0; nq < 4; ++nq) {
            int col = n0 + wc * 64 + nq * 16 + lr;
            f32x4 v = acc[mq][nq];
#pragma unroll
            for (int r = 0; r < 4; ++r) {
                size_t o = (size_t)(crow + r) * N + col;
                float nv = Cf[o] + v[r];
                Cf[o] = nv;
                if (EMITB) Cb[o] = __float2bfloat16(nv);
            }
        }
    }
}

// ---------------- MFMA flash attention (round-7 verified version) -------------
// 1-D grid 2048, XCD-grouped. Q,K from proj (stride 2048); V^T staged from vt.
__global__ __launch_bounds__(256, 2) void attn_kernel(
    const __hip_bfloat16* __restrict__ proj, const __hip_bfloat16* __restrict__ vt,
    __hip_bfloat16* __restrict__ ao) {
    __shared__ __align__(16) char ksm[64 * 128];
    __shared__ __align__(16) char vsm[64 * 128];
    __shared__ __align__(16) char psm[4 * 16 * 128];
    int wgid = blockIdx.x;
    int xcd = wgid & 7, slot = wgid >> 3;
    int group = xcd * 16 + (slot >> 4);
    int qt = slot & 15;
    int head = group & 15, b = group >> 4;
    int t = threadIdx.x;
    int lane = t & 63, w = t >> 6;
    int r = lane & 15, g = lane >> 4;
    int r7s = (r & 7) << 4;
    int q0 = qt * 64;
    int qcol = head * 64;
    const __hip_bfloat16* pb = proj + (size_t)b * S_ * PROJK_;
    const char* vtb = (const char*)(vt + ((size_t)(b * 16 + head) * 64) * 1024);
    bf16x8 qf[2];
#pragma unroll
    for (int kk = 0; kk < 2; ++kk)
        qf[kk] = *reinterpret_cast<const bf16x8*>(
            pb + (size_t)(q0 + w * 16 + r) * PROJK_ + qcol + kk * 32 + g * 8);
    int srow8 = lane >> 3;  // row within an 8-row staging chunk
    int sgrp = lane & 7;    // 16B group
    float m = -1e30f, l = 0.f;
    f32x4 o_acc[4] = {};
    char* pw = psm + w * 2048;
    for (int kt = 0; kt < 16; ++kt) {
        int k0 = kt * 64;
        // ---- stage K rows (swizzled src, linear LDS) ----
#pragma unroll
        for (int c = 0; c < 2; ++c) {
            int krow = w * 16 + c * 8 + srow8;
            const __hip_bfloat16* src =
                pb + (size_t)(k0 + krow) * PROJK_ + 1024 + qcol + ((sgrp ^ (krow & 7)) << 3);
            GLOAD16(src, ksm + (w * 16 + c * 8) * 128);
        }
        // ---- stage V^T rows d from vt (swizzled src, linear LDS) ----
#pragma unroll
        for (int c = 0; c < 2; ++c) {
            int drow = w * 16 + c * 8 + srow8;
            const char* src = vtb + (size_t)drow * 2048 + k0 * 2 + ((sgrp ^ (drow & 7)) << 4);
            GLOAD16(src, vsm + (w * 16 + c * 8) * 128);
        }
        __syncthreads();
        f32x4 st[4] = {};
        __builtin_amdgcn_s_setprio(1);
#pragma unroll
        for (int j = 0; j < 4; ++j) {
#pragma unroll
            for (int kk = 0; kk < 2; ++kk) {
                bf16x8 kf = *reinterpret_cast<const bf16x8*>(
                    ksm + (j * 16 + r) * 128 + ((((kk * 4 + g) << 4) ^ r7s)));
                st[j] = __builtin_amdgcn_mfma_f32_16x16x32_bf16(kf, qf[kk], st[j], 0, 0, 0);
            }
        }
        __builtin_amdgcn_s_setprio(0);
        float tmax = -1e30f;
#pragma unroll
        for (int j = 0; j < 4; ++j)
#pragma unroll
            for (int rr = 0; rr < 4; ++rr) {
                st[j][rr] *= 0.125f;
                tmax = fmaxf(tmax, st[j][rr]);
            }
        tmax = fmaxf(tmax, __shfl_xor(tmax, 16, 64));
        tmax = fmaxf(tmax, __shfl_xor(tmax, 32, 64));
        float mnew = fmaxf(m, tmax);
        float rsum = 0.f;
#pragma unroll
        for (int j = 0; j < 4; ++j)
#pragma unroll
            for (int rr = 0; rr < 4; ++rr) {
                float p = __expf(st[j][rr] - mnew);
                st[j][rr] = p;
                rsum += p;
            }
        rsum += __shfl_xor(rsum, 16, 64);
        rsum += __shfl_xor(rsum, 32, 64);
        float alpha = __expf(m - mnew);
        l = l * alpha + rsum;
        m = mnew;
#pragma unroll
        for (int j = 0; j < 4; ++j)
#pragma unroll
            for (int rr = 0; rr < 4; ++rr) {
                int kv2 = j * 32 + g * 8 + rr * 2;
                *reinterpret_cast<short*>(pw + r * 128 + (kv2 ^ r7s)) = f2b(st[j][rr]);
            }
        asm volatile("s_waitcnt lgkmcnt(0)" ::: "memory");
        __builtin_amdgcn_sched_barrier(0);
        float ar[4];
#pragma unroll
        for (int rr = 0; rr < 4; ++rr) ar[rr] = __shfl(alpha, g * 4 + rr, 64);
#pragma unroll
        for (int dt = 0; dt < 4; ++dt)
#pragma unroll
            for (int rr = 0; rr < 4; ++rr) o_acc[dt][rr] *= ar[rr];
        __builtin_amdgcn_s_setprio(1);
#pragma unroll
        for (int kk = 0; kk < 2; ++kk) {
            bf16x8 pf = *reinterpret_cast<const bf16x8*>(
                pw + r * 128 + ((((kk * 4 + g) << 4) ^ r7s)));
#pragma unroll
            for (int dt = 0; dt < 4; ++dt) {
                bf16x8 vf = *reinterpret_cast<const bf16x8*>(
                    vsm + (dt * 16 + r) * 128 + ((((kk * 4 + g) << 4) ^ r7s)));
                o_acc[dt] = __builtin_amdgcn_mfma_f32_16x16x32_bf16(pf, vf, o_acc[dt], 0, 0, 0);
            }
        }
        __builtin_amdgcn_s_setprio(0);
        __syncthreads();
    }
    float linv = 1.f / l;
    float lr4[4];
#pragma unroll
    for (int rr = 0; rr < 4; ++rr) lr4[rr] = __shfl(linv, g * 4 + rr, 64);
    short* ap = reinterpret_cast<short*>(ao);
#pragma unroll
    for (int dt = 0; dt < 4; ++dt)
#pragma unroll
        for (int rr = 0; rr < 4; ++rr) {
            size_t o = ((size_t)b * S_ + q0 + w * 16 + g * 4 + rr) * (size_t)AOW_ +
                       qcol + dt * 16 + r;
            ap[o] = f2b(o_acc[dt][rr] * lr4[rr]);
        }
}

extern "C" void kernel_launch(void* const* d_in, const int* in_sizes, int n_in,
                              void* d_out, int out_size, void* d_ws, size_t ws_size,
                              hipStream_t stream) {
    const float* inputs = (const float*)d_in[0];
    const float* time = (const float*)d_in[1];
    const float* in_W = (const float*)d_in[2];
    const float* in_b = (const float*)d_in[3];
    const float* out_W = (const float*)d_in[4];
    const float* out_b = (const float*)d_in[5];
    const float* t_W1 = (const float*)d_in[6];
    const float* t_b1 = (const float*)d_in[7];
    const float* t_W2 = (const float*)d_in[8];
    const float* t_b2 = (const float*)d_in[9];
    const float* ln_scale = (const float*)d_in[10];
    const float* ln_bias = (const float*)d_in[11];
    const float* proj_W = (const float*)d_in[12];
    const float* attn_W = (const float*)d_in[13];
    const float* ff_W = (const float*)d_in[14];
    float* out = (float*)d_out;

    float* ws = (float*)d_ws;
    size_t off = 0;
    float* temb0 = ws + off; off += 8 * 1024;
    float* tact = ws + off;  off += 8 * 4096;
    float* temb = ws + off;  off += 8 * 1024;
    float* pos = ws + off;   off += (size_t)S_ * D_;
    float* h = ws + off;     off += (size_t)BS_ * D_;
    __hip_bfloat16* u = (__hip_bfloat16*)(ws + off);      off += (size_t)BS_ * D_ / 2;
    __hip_bfloat16* proj = (__hip_bfloat16*)(ws + off);   off += (size_t)BS_ * PROJK_ / 2;
    __hip_bfloat16* vt = (__hip_bfloat16*)(ws + off);     off += (size_t)BS_ * D_ / 2;
    __hip_bfloat16* ao = (__hip_bfloat16*)(ws + off);     off += (size_t)BS_ * AOW_ / 2;
    __hip_bfloat16* hb = (__hip_bfloat16*)(ws + off);     off += (size_t)BS_ * D_ / 2;
    __hip_bfloat16* inbf = (__hip_bfloat16*)(ws + off);   off += (size_t)BS_ * (2 * E_) / 2;
    __hip_bfloat16* in_Wt = (__hip_bfloat16*)(ws + off);  off += (size_t)(2 * E_) * D_ / 2;
    __hip_bfloat16* out_Wt = (__hip_bfloat16*)(ws + off); off += (size_t)D_ * E_ / 2;
    __hip_bfloat16* Wpt = (__hip_bfloat16*)(ws + off);    off += (size_t)D_ * PROJN_ / 2;
    __hip_bfloat16* Waft = (__hip_bfloat16*)(ws + off);   off += (size_t)D_ * AOW_ / 2;

    dim3 blk(256);

    temb0_kernel<<<B_, 512, 0, stream>>>(time, temb0);
    tmlp_kernel<<<TDIM_ / 16, blk, 0, stream>>>(temb0, t_W1, t_b1, tact, D_, TDIM_);
    tmlp_kernel<<<D_ / 16, blk, 0, stream>>>(tact, t_W2, t_b2, temb, TDIM_, D_);
    pos_kernel<<<S_, 512, 0, stream>>>(pos);
    f2b4_kernel<<<(BS_ * 2 * E_) / 1024, blk, 0, stream>>>(inputs, inbf);
    convT_kernel<<<dim3(D_ / 64, (2 * E_) / 64), blk, 0, stream>>>(
        in_W, in_Wt, 2 * E_, D_, 2 * E_, 0);
    convT_kernel<<<dim3(E_ / 64, D_ / 64), blk, 0, stream>>>(
        out_W, out_Wt, D_, E_, D_, 0);
    // input projection + bias + pos + temb fused
    mfma_gemm<0, 1, 1><<<dim3(D_ / 128, BS_ / 128), blk, 0, stream>>>(
        inbf, in_Wt, in_b, h, nullptr, pos, temb, BS_, D_, 2 * E_);

    for (int l = 0; l < L_; ++l) {
        const float* Wp = proj_W + (size_t)l * D_ * PROJN_;
        const float* Wa = attn_W + (size_t)l * (H_ * DH_) * D_;
        const float* Wf = ff_W + (size_t)l * FF_ * D_;
        convT3_kernel<<<dim3(4096), blk, 0, stream>>>(Wp, Wa, Wf, Wpt, Waft);
        ln_kernel<<<BS_, blk, 0, stream>>>(h, ln_scale + l * D_, ln_bias + l * D_, u);
        gemm256<3><<<dim3(PROJN_ / 256, BS_ / 256), dim3(512), 0, stream>>>(
            u, Wpt, nullptr, proj, ao + D_, vt, BS_, PROJN_, D_);
        attn_kernel<<<dim3(2048), blk, 0, stream>>>(proj, vt, ao);
        if (l == L_ - 1)
            gemm256b<1><<<dim3(D_ / 128, BS_ / 256), dim3(512), 0, stream>>>(
                ao, Waft, h, hb, BS_, D_, AOW_);
        else
            gemm256b<0><<<dim3(D_ / 128, BS_ / 256), dim3(512), 0, stream>>>(
                ao, Waft, h, nullptr, BS_, D_, AOW_);
    }
    mfma_gemm<0, 1, 0><<<dim3(E_ / 128, BS_ / 128), blk, 0, stream>>>(
        hb, out_Wt, out_b, out, nullptr, nullptr, nullptr, BS_, E_, D_);
}